// Round 1
// baseline (1891.243 us; speedup 1.0000x reference)
//
#include <hip/hip_runtime.h>
#include <math.h>

namespace {

constexpr int kB   = 64;
constexpr int kN   = 196;
constexpr int kD   = 384;
constexpr int kS   = 4096;
constexpr int kTRI = 73920;
constexpr int kDD  = kD * kD;          // 147456
constexpr float kEPS   = 1e-5f;
constexpr float kBNEPS = 1e-5f;

// ---------------- small utility kernels ----------------

__global__ void k_zero64(float* p) { p[threadIdx.x] = 0.f; }

// deg[b,i] = sum_j graph[b,i,j]; inv_sqrt = 1/sqrt(max(deg, EPS))
__global__ void k_deg(const float* __restrict__ g, float* __restrict__ isq) {
  int i = blockIdx.x, b = blockIdx.y;
  const float* row = g + ((size_t)b * kN + i) * kN;
  float s = 0.f;
  for (int j = threadIdx.x; j < kN; j += 64) s += row[j];
#pragma unroll
  for (int off = 32; off; off >>= 1) s += __shfl_down(s, off);
  if (threadIdx.x == 0) {
    float dg = s < kEPS ? kEPS : s;
    isq[b * kN + i] = 1.0f / sqrtf(dg);
  }
}

// row_sum[b,i] = is[i] * sum_j g[i,j]*is[j] ; tr_w[b] += g[i,i]*is[i]^2
__global__ void k_rowsum(const float* __restrict__ g, const float* __restrict__ isq,
                         float* __restrict__ rs, float* __restrict__ trw) {
  int i = blockIdx.x, b = blockIdx.y;
  const float* row = g + ((size_t)b * kN + i) * kN;
  const float* is = isq + b * kN;
  float s = 0.f, diag = 0.f;
  for (int j = threadIdx.x; j < kN; j += 64) {
    float gv = row[j];
    s += gv * is[j];
    if (j == i) diag = gv;
  }
#pragma unroll
  for (int off = 32; off; off >>= 1) {
    s += __shfl_down(s, off);
    diag += __shfl_down(diag, off);
  }
  if (threadIdx.x == 0) {
    float isi = is[i];
    rs[b * kN + i] = isi * s;
    atomicAdd(&trw[b], diag * isi * isi);
  }
}

// mu[b,d] = sum_n tokens[b,n,d]*rs[n] / (tr+EPS);
// wc[b,d] = mu * (1 - sum_n rs[n]/(tr+EPS))     (algebraic identity)
__global__ void k_mu_wc(const float* __restrict__ tokens, const float* __restrict__ rs,
                        const float* __restrict__ trw, float* __restrict__ mu,
                        float* __restrict__ wc) {
  int b = blockIdx.x, d = threadIdx.x;  // blockDim = 384
  const float* r = rs + b * kN;
  const float* tb = tokens + (size_t)b * kN * kD + d;
  float T = 0.f, S = 0.f;
  for (int n = 0; n < kN; ++n) {
    float rv = r[n];
    T += tb[(size_t)n * kD] * rv;
    S += rv;
  }
  float invtr = 1.0f / (trw[b] + kEPS);
  float m = T * invtr;
  mu[b * kD + d] = m;
  wc[b * kD + d] = m * (1.0f - S * invtr);
}

__global__ void k_xc(const float* __restrict__ tokens, const float* __restrict__ mu,
                     float* __restrict__ xc) {
  size_t total = (size_t)kB * kN * kD;
  for (size_t i = (size_t)blockIdx.x * blockDim.x + threadIdx.x; i < total;
       i += (size_t)gridDim.x * blockDim.x) {
    int d = (int)(i % kD);
    int b = (int)(i / ((size_t)kN * kD));
    xc[i] = tokens[i] - mu[b * kD + d];
  }
}

// WX = W @ Xc with W computed on the fly: W[i,k] = g[i,k]*is[i]*is[k]
__global__ __launch_bounds__(256) void k_wx(const float* __restrict__ g,
                                            const float* __restrict__ isq,
                                            const float* __restrict__ xc,
                                            float* __restrict__ wx) {
  __shared__ float Gs[16][68];
  __shared__ float Bs[16][68];
  int b = blockIdx.z;
  int n0 = blockIdx.x * 64, i0 = blockIdx.y * 64;
  int tid = threadIdx.x, tx = tid & 15, ty = tid >> 4;
  const float* gb = g + (size_t)b * kN * kN;
  const float* is = isq + b * kN;
  const float* xb = xc + (size_t)b * kN * kD;
  float acc[4][4] = {};
  for (int kt = 0; kt < kN; kt += 16) {
#pragma unroll
    for (int l = 0; l < 4; ++l) {
      int idx = tid + 256 * l;
      int r = idx >> 4, k = idx & 15;
      int ii = i0 + r, kk = kt + k;
      float v = 0.f;
      if (ii < kN && kk < kN) v = gb[(size_t)ii * kN + kk] * is[ii] * is[kk];
      Gs[k][r] = v;
      int n = idx & 63, k2 = idx >> 6;
      int kk2 = kt + k2;
      float v2 = 0.f;
      if (kk2 < kN) v2 = xb[(size_t)kk2 * kD + n0 + n];
      Bs[k2][n] = v2;
    }
    __syncthreads();
#pragma unroll
    for (int k = 0; k < 16; ++k) {
      float a[4], bb[4];
#pragma unroll
      for (int i = 0; i < 4; ++i) a[i] = Gs[k][ty * 4 + i];
#pragma unroll
      for (int j = 0; j < 4; ++j) bb[j] = Bs[k][tx * 4 + j];
#pragma unroll
      for (int i = 0; i < 4; ++i)
#pragma unroll
        for (int j = 0; j < 4; ++j) acc[i][j] += a[i] * bb[j];
    }
    __syncthreads();
  }
  for (int i = 0; i < 4; ++i) {
    int row = i0 + ty * 4 + i;
    if (row < kN) {
      float4 v = make_float4(acc[i][0], acc[i][1], acc[i][2], acc[i][3]);
      *(float4*)&wx[(size_t)b * kN * kD + (size_t)row * kD + n0 + tx * 4] = v;
    }
  }
}

// M2[d,e] = sum_n Xc[n,d]*WX[n,e]
__global__ __launch_bounds__(256) void k_m2(const float* __restrict__ xc,
                                            const float* __restrict__ wx,
                                            float* __restrict__ m2) {
  __shared__ float As[16][68];
  __shared__ float Bs[16][68];
  int b = blockIdx.z;
  int e0 = blockIdx.x * 64, d0 = blockIdx.y * 64;
  int tid = threadIdx.x, tx = tid & 15, ty = tid >> 4;
  const float* xb = xc + (size_t)b * kN * kD;
  const float* wb = wx + (size_t)b * kN * kD;
  float acc[4][4] = {};
  for (int kt = 0; kt < kN; kt += 16) {
#pragma unroll
    for (int l = 0; l < 4; ++l) {
      int idx = tid + 256 * l;
      int m = idx & 63, k = idx >> 6;
      int kk = kt + k;
      float va = 0.f, vb = 0.f;
      if (kk < kN) {
        va = xb[(size_t)kk * kD + d0 + m];
        vb = wb[(size_t)kk * kD + e0 + m];
      }
      As[k][m] = va;
      Bs[k][m] = vb;
    }
    __syncthreads();
#pragma unroll
    for (int k = 0; k < 16; ++k) {
      float a[4], bb[4];
#pragma unroll
      for (int i = 0; i < 4; ++i) a[i] = As[k][ty * 4 + i];
#pragma unroll
      for (int j = 0; j < 4; ++j) bb[j] = Bs[k][tx * 4 + j];
#pragma unroll
      for (int i = 0; i < 4; ++i)
#pragma unroll
        for (int j = 0; j < 4; ++j) acc[i][j] += a[i] * bb[j];
    }
    __syncthreads();
  }
  for (int i = 0; i < 4; ++i) {
    int row = d0 + ty * 4 + i;
    float4 v = make_float4(acc[i][0], acc[i][1], acc[i][2], acc[i][3]);
    *(float4*)&m2[(size_t)b * kDD + (size_t)row * kD + e0 + tx * 4] = v;
  }
}

__global__ void k_trace(const float* __restrict__ m2, float* __restrict__ tinv,
                        float* __restrict__ tsc) {
  int b = blockIdx.x;
  const float* mb = m2 + (size_t)b * kDD;
  float s = 0.f;
  for (int d = threadIdx.x; d < kD; d += 64) s += mb[(size_t)d * kD + d];
#pragma unroll
  for (int off = 32; off; off >>= 1) s += __shfl_down(s, off);
  if (threadIdx.x == 0) {
    float t = s + kEPS;
    tinv[b] = 1.0f / t;
    tsc[b] = 1.0f / sqrtf(t);
  }
}

// A = M2/(tr+EPS) in place; Y1 = 1.5I - 0.5A  (first NS iteration is matmul-free)
__global__ void k_init_ns(float* __restrict__ m2, float* __restrict__ y,
                          const float* __restrict__ tinv) {
  size_t total = (size_t)kB * kDD;
  for (size_t i = (size_t)blockIdx.x * blockDim.x + threadIdx.x; i < total;
       i += (size_t)gridDim.x * blockDim.x) {
    int b = (int)(i / kDD);
    int rc = (int)(i % kDD);
    float a = m2[i] * tinv[b];
    m2[i] = a;
    y[i] = ((rc % (kD + 1)) == 0 ? 1.5f : 0.f) - 0.5f * a;
  }
}

// batched 384x384x384 fp32 GEMM: C = alpha*(A@B) + beta*D (D nullable)
__global__ __launch_bounds__(256) void k_gemm384(const float* __restrict__ A,
                                                 const float* __restrict__ Bm,
                                                 float* __restrict__ C,
                                                 const float* __restrict__ Dm,
                                                 float alpha, float beta) {
  __shared__ float As[16][132];
  __shared__ float Bs[16][132];
  size_t boff = (size_t)blockIdx.z * kDD;
  int m0 = blockIdx.y * 128, n0 = blockIdx.x * 128;
  int tid = threadIdx.x, tx = tid & 15, ty = tid >> 4;
  const float* Ab = A + boff;
  const float* Bb = Bm + boff;
  float acc[8][8] = {};
  for (int kt = 0; kt < kD; kt += 16) {
#pragma unroll
    for (int l = 0; l < 2; ++l) {
      int e = tid + 256 * l;
      int r = e >> 2, q = e & 3;
      float4 av = *(const float4*)&Ab[(size_t)(m0 + r) * kD + kt + q * 4];
      As[q * 4 + 0][r] = av.x;
      As[q * 4 + 1][r] = av.y;
      As[q * 4 + 2][r] = av.z;
      As[q * 4 + 3][r] = av.w;
      int k = e >> 5, nq = e & 31;
      float4 bv = *(const float4*)&Bb[(size_t)(kt + k) * kD + n0 + nq * 4];
      *(float4*)&Bs[k][nq * 4] = bv;
    }
    __syncthreads();
#pragma unroll
    for (int k = 0; k < 16; ++k) {
      float a[8], bb[8];
      *(float4*)&a[0] = *(const float4*)&As[k][ty * 4];
      *(float4*)&a[4] = *(const float4*)&As[k][64 + ty * 4];
      *(float4*)&bb[0] = *(const float4*)&Bs[k][tx * 4];
      *(float4*)&bb[4] = *(const float4*)&Bs[k][64 + tx * 4];
#pragma unroll
      for (int i = 0; i < 8; ++i)
#pragma unroll
        for (int j = 0; j < 8; ++j) acc[i][j] += a[i] * bb[j];
    }
    __syncthreads();
  }
  float* Cb = C + boff;
  const float* Db = Dm ? Dm + boff : nullptr;
  for (int ih = 0; ih < 2; ++ih)
    for (int i = 0; i < 4; ++i) {
      int m = m0 + ih * 64 + ty * 4 + i;
      for (int jh = 0; jh < 2; ++jh) {
        int n = n0 + jh * 64 + tx * 4;
        float4 v;
        v.x = alpha * acc[ih * 4 + i][jh * 4 + 0];
        v.y = alpha * acc[ih * 4 + i][jh * 4 + 1];
        v.z = alpha * acc[ih * 4 + i][jh * 4 + 2];
        v.w = alpha * acc[ih * 4 + i][jh * 4 + 3];
        if (Db) {
          float4 dv = *(const float4*)&Db[(size_t)m * kD + n];
          v.x += beta * dv.x;
          v.y += beta * dv.y;
          v.z += beta * dv.z;
          v.w += beta * dv.w;
        }
        *(float4*)&Cb[(size_t)m * kD + n] = v;
      }
    }
}

// M2_vec[b,t] = Yfinal[b, r(t), c(t)] * (1/sqrt(tr+EPS))
__global__ void k_trigather(const float* __restrict__ y, const float* __restrict__ tsc,
                            float* __restrict__ m2v) {
  size_t total = (size_t)kB * kTRI;
  for (size_t i = (size_t)blockIdx.x * blockDim.x + threadIdx.x; i < total;
       i += (size_t)gridDim.x * blockDim.x) {
    int b = (int)(i / kTRI);
    int t = (int)(i % kTRI);
    float disc = 591361.0f - 8.0f * (float)t;  // (2D+1)^2 - 8t, exact in fp32
    int r = (int)((769.0f - sqrtf(disc)) * 0.5f);
    if (r > kD - 1) r = kD - 1;
    if (r < 0) r = 0;
    while (r > 0 && (r * (769 - r)) / 2 > t) --r;
    while (r < kD - 1 && ((r + 1) * (769 - (r + 1))) / 2 <= t) ++r;
    int base = (r * (769 - r)) / 2;
    int c = r + (t - base);
    m2v[i] = y[(size_t)b * kDD + (size_t)r * kD + c] * tsc[b];
  }
}

__global__ void k_bias_init(float* __restrict__ dst, const float* __restrict__ bias,
                            int cols, int ldo) {
  int total = kB * cols;
  for (int i = blockIdx.x * blockDim.x + threadIdx.x; i < total;
       i += gridDim.x * blockDim.x) {
    int row = i / cols, col = i % cols;
    dst[(size_t)row * ldo + col] = bias[col];
  }
}

// skinny GEMM, M=64 fixed: C[64 x N] (+=, atomic) A[64 x K] @ B[K x N]
// grid: (N/64, ksplit); each block does `ktiles` k-tiles of 16 starting at
// blockIdx.y*ktiles*16. K chunking is exact (caller guarantees divisibility).
__global__ __launch_bounds__(256) void k_skinny(const float* __restrict__ A, int lda,
                                                const float* __restrict__ Bm, int ldb,
                                                float* __restrict__ C, int ldc,
                                                int ktiles) {
  __shared__ float As[16][68];
  __shared__ float Bs[16][68];
  int n0 = blockIdx.x * 64;
  int kt0 = blockIdx.y * ktiles * 16;
  int tid = threadIdx.x, tx = tid & 15, ty = tid >> 4;
  float acc[4][4] = {};
  for (int t = 0; t < ktiles; ++t) {
    int kt = kt0 + t * 16;
    int r = tid >> 2, q = tid & 3;
    float4 av = *(const float4*)&A[(size_t)r * lda + kt + q * 4];
    As[q * 4 + 0][r] = av.x;
    As[q * 4 + 1][r] = av.y;
    As[q * 4 + 2][r] = av.z;
    As[q * 4 + 3][r] = av.w;
    int kk = tid >> 4, nq = tid & 15;
    float4 bv = *(const float4*)&Bm[(size_t)(kt + kk) * ldb + n0 + nq * 4];
    *(float4*)&Bs[kk][nq * 4] = bv;
    __syncthreads();
#pragma unroll
    for (int k = 0; k < 16; ++k) {
      float a[4], bb[4];
#pragma unroll
      for (int i = 0; i < 4; ++i) a[i] = As[k][ty * 4 + i];
#pragma unroll
      for (int j = 0; j < 4; ++j) bb[j] = Bs[k][tx * 4 + j];
#pragma unroll
      for (int i = 0; i < 4; ++i)
#pragma unroll
        for (int j = 0; j < 4; ++j) acc[i][j] += a[i] * bb[j];
    }
    __syncthreads();
  }
  for (int i = 0; i < 4; ++i)
    for (int j = 0; j < 4; ++j)
      atomicAdd(&C[(size_t)(ty * 4 + i) * ldc + n0 + tx * 4 + j], acc[i][j]);
}

__global__ void k_bngelu(const float* __restrict__ h, const float* __restrict__ gamma,
                         const float* __restrict__ beta, const float* __restrict__ rm,
                         const float* __restrict__ rv, float* __restrict__ o, int cols) {
  int total = kB * cols;
  for (int i = blockIdx.x * blockDim.x + threadIdx.x; i < total;
       i += gridDim.x * blockDim.x) {
    int col = i % cols;
    float x = h[i];
    float xn = (x - rm[col]) / sqrtf(rv[col] + kBNEPS) * gamma[col] + beta[col];
    o[i] = xn * 0.5f * (1.0f + erff(xn * 0.70710678118654752f));
  }
}

__global__ void k_sketch(const float* __restrict__ wc, const int* __restrict__ h1,
                         const int* __restrict__ h2, const int* __restrict__ h3,
                         const float* __restrict__ s1, const float* __restrict__ s2,
                         const float* __restrict__ s3, float* __restrict__ sk) {
  __shared__ float L1[kS];
  __shared__ float L2[kS];
  __shared__ float L3[kS];
  int b = blockIdx.x;
  for (int i = threadIdx.x; i < kS; i += blockDim.x) {
    L1[i] = 0.f;
    L2[i] = 0.f;
    L3[i] = 0.f;
  }
  __syncthreads();
  for (int d = threadIdx.x; d < kD; d += blockDim.x) {
    float w = wc[b * kD + d];
    atomicAdd(&L1[h1[d]], w * s1[d]);
    atomicAdd(&L2[h2[d]], w * s2[d]);
    atomicAdd(&L3[h3[d]], w * s3[d]);
  }
  __syncthreads();
  for (int i = threadIdx.x; i < kS; i += blockDim.x)
    sk[(size_t)b * kS + i] = L1[i] * L2[i] * L3[i];
}

}  // namespace

extern "C" void kernel_launch(void* const* d_in, const int* in_sizes, int n_in,
                              void* d_out, int out_size, void* d_ws, size_t ws_size,
                              hipStream_t stream) {
  (void)in_sizes; (void)n_in; (void)out_size; (void)ws_size;
  const float* tokens = (const float*)d_in[0];
  const float* graph  = (const float*)d_in[1];
  const int*   hash1  = (const int*)d_in[2];
  const int*   hash2  = (const int*)d_in[3];
  const int*   hash3  = (const int*)d_in[4];
  const float* sign1  = (const float*)d_in[5];
  const float* sign2  = (const float*)d_in[6];
  const float* sign3  = (const float*)d_in[7];
  const float* w1_2   = (const float*)d_in[8];
  const float* b1_2   = (const float*)d_in[9];
  const float* gamma2 = (const float*)d_in[10];
  const float* beta2  = (const float*)d_in[11];
  const float* rm2    = (const float*)d_in[12];
  const float* rv2    = (const float*)d_in[13];
  const float* w2_2   = (const float*)d_in[14];
  const float* b2_2   = (const float*)d_in[15];
  const float* w1_3   = (const float*)d_in[16];
  const float* b1_3   = (const float*)d_in[17];
  const float* gamma3 = (const float*)d_in[18];
  const float* beta3  = (const float*)d_in[19];
  const float* rm3    = (const float*)d_in[20];
  const float* rv3    = (const float*)d_in[21];
  const float* w2_3   = (const float*)d_in[22];
  const float* b2_3   = (const float*)d_in[23];
  float* outp = (float*)d_out;

  float* p = (float*)d_ws;
  auto take = [&](size_t n) { float* q = p; p += n; return q; };
  float* isq = take((size_t)kB * kN);
  float* rs  = take((size_t)kB * kN);
  float* trw = take(64);
  float* tinv = take(64);
  float* tsc  = take(64);
  float* mu = take((size_t)kB * kD);
  float* wc = take((size_t)kB * kD);
  float* xc = take((size_t)kB * kN * kD);
  float* wx = take((size_t)kB * kN * kD);
  float* P0 = take((size_t)kB * kDD);
  float* P1 = take((size_t)kB * kDD);
  float* P2 = take((size_t)kB * kDD);
  float* P3 = take((size_t)kB * kDD);
  float* m2v = take((size_t)kB * kTRI);
  float* h1b = take((size_t)kB * 1024);
  float* h1g = take((size_t)kB * 1024);
  float* h3b = take((size_t)kB * 1024);
  float* h3g = take((size_t)kB * 1024);
  float* sk  = take((size_t)kB * kS);

  hipLaunchKernelGGL(k_zero64, dim3(1), dim3(64), 0, stream, trw);
  hipLaunchKernelGGL(k_deg, dim3(kN, kB), dim3(64), 0, stream, graph, isq);
  hipLaunchKernelGGL(k_rowsum, dim3(kN, kB), dim3(64), 0, stream, graph, isq, rs, trw);
  hipLaunchKernelGGL(k_mu_wc, dim3(kB), dim3(kD), 0, stream, tokens, rs, trw, mu, wc);
  hipLaunchKernelGGL(k_xc, dim3(8192), dim3(256), 0, stream, tokens, mu, xc);
  hipLaunchKernelGGL(k_wx, dim3(6, 4, kB), dim3(256), 0, stream, graph, isq, xc, wx);
  hipLaunchKernelGGL(k_m2, dim3(6, 6, kB), dim3(256), 0, stream, xc, wx, P0);
  hipLaunchKernelGGL(k_trace, dim3(kB), dim3(64), 0, stream, P0, tinv, tsc);
  hipLaunchKernelGGL(k_init_ns, dim3(8192), dim3(256), 0, stream, P0, P1, tinv);

  // Newton-Schulz, Y-only form: per iter T=Y@Y, U=A@T, Ynew=1.5Y-0.5*Y@U
  float* Y = P1;
  float* F1 = P2;
  float* F2 = P3;
  for (int it = 0; it < 4; ++it) {
    hipLaunchKernelGGL(k_gemm384, dim3(3, 3, kB), dim3(256), 0, stream,
                       Y, Y, F1, (const float*)nullptr, 1.f, 0.f);
    hipLaunchKernelGGL(k_gemm384, dim3(3, 3, kB), dim3(256), 0, stream,
                       P0, F1, F2, (const float*)nullptr, 1.f, 0.f);
    hipLaunchKernelGGL(k_gemm384, dim3(3, 3, kB), dim3(256), 0, stream,
                       Y, F2, F1, Y, -0.5f, 1.5f);
    float* newY = F1;
    F1 = Y;
    Y = newY;
  }

  hipLaunchKernelGGL(k_trigather, dim3(8192), dim3(256), 0, stream, Y, tsc, m2v);

  // second path MLP
  hipLaunchKernelGGL(k_bias_init, dim3(256), dim3(256), 0, stream, h1b, b1_2, 1024, 1024);
  hipLaunchKernelGGL(k_skinny, dim3(16, 30), dim3(256), 0, stream,
                     m2v, kTRI, w1_2, 1024, h1b, 1024, 154);  // 30*154*16 = 73920
  hipLaunchKernelGGL(k_bngelu, dim3(256), dim3(256), 0, stream,
                     h1b, gamma2, beta2, rm2, rv2, h1g, 1024);
  hipLaunchKernelGGL(k_bias_init, dim3(128), dim3(256), 0, stream, outp, b2_2, 512, 1024);
  hipLaunchKernelGGL(k_bias_init, dim3(128), dim3(256), 0, stream, outp + 512, b2_3, 512, 1024);
  hipLaunchKernelGGL(k_skinny, dim3(8, 4), dim3(256), 0, stream,
                     h1g, 1024, w2_2, 512, outp, 1024, 16);  // 4*16*16 = 1024

  // third path (count-sketch MLP)
  hipLaunchKernelGGL(k_sketch, dim3(kB), dim3(256), 0, stream,
                     wc, hash1, hash2, hash3, sign1, sign2, sign3, sk);
  hipLaunchKernelGGL(k_bias_init, dim3(256), dim3(256), 0, stream, h3b, b1_3, 1024, 1024);
  hipLaunchKernelGGL(k_skinny, dim3(16, 8), dim3(256), 0, stream,
                     sk, kS, w1_3, 1024, h3b, 1024, 32);  // 8*32*16 = 4096
  hipLaunchKernelGGL(k_bngelu, dim3(256), dim3(256), 0, stream,
                     h3b, gamma3, beta3, rm3, rv3, h3g, 1024);
  hipLaunchKernelGGL(k_skinny, dim3(8, 4), dim3(256), 0, stream,
                     h3g, 1024, w2_3, 512, outp + 512, 1024, 16);
}

// Round 2
// 1066.015 us; speedup vs baseline: 1.7741x; 1.7741x over previous
//
#include <hip/hip_runtime.h>
#include <math.h>

namespace {

constexpr int kB   = 64;
constexpr int kN   = 196;
constexpr int kD   = 384;
constexpr int kS   = 4096;
constexpr int kTRI = 73920;
constexpr int kDD  = kD * kD;          // 147456
constexpr float kEPS   = 1e-5f;
constexpr float kBNEPS = 1e-5f;

typedef __attribute__((ext_vector_type(8))) short s16x8;
typedef __attribute__((ext_vector_type(4))) float f32x4;
typedef __attribute__((ext_vector_type(4))) ushort u16x4;

__device__ inline float bf2f(ushort h) {
  union { uint u; float f; } v; v.u = (uint)h << 16; return v.f;
}
__device__ inline ushort f2bf(float f) {
  union { float f; uint u; } v; v.f = f;
  uint r = v.u + 0x7FFF + ((v.u >> 16) & 1);
  return (ushort)(r >> 16);
}

// ---------------- small utility kernels ----------------

__global__ void k_zero64(float* p) { p[threadIdx.x] = 0.f; }

__global__ void k_deg(const float* __restrict__ g, float* __restrict__ isq) {
  int i = blockIdx.x, b = blockIdx.y;
  const float* row = g + ((size_t)b * kN + i) * kN;
  float s = 0.f;
  for (int j = threadIdx.x; j < kN; j += 64) s += row[j];
#pragma unroll
  for (int off = 32; off; off >>= 1) s += __shfl_down(s, off);
  if (threadIdx.x == 0) {
    float dg = s < kEPS ? kEPS : s;
    isq[b * kN + i] = 1.0f / sqrtf(dg);
  }
}

__global__ void k_rowsum(const float* __restrict__ g, const float* __restrict__ isq,
                         float* __restrict__ rs, float* __restrict__ trw) {
  int i = blockIdx.x, b = blockIdx.y;
  const float* row = g + ((size_t)b * kN + i) * kN;
  const float* is = isq + b * kN;
  float s = 0.f, diag = 0.f;
  for (int j = threadIdx.x; j < kN; j += 64) {
    float gv = row[j];
    s += gv * is[j];
    if (j == i) diag = gv;
  }
#pragma unroll
  for (int off = 32; off; off >>= 1) {
    s += __shfl_down(s, off);
    diag += __shfl_down(diag, off);
  }
  if (threadIdx.x == 0) {
    float isi = is[i];
    rs[b * kN + i] = isi * s;
    atomicAdd(&trw[b], diag * isi * isi);
  }
}

__global__ void k_mu_wc(const float* __restrict__ tokens, const float* __restrict__ rs,
                        const float* __restrict__ trw, float* __restrict__ mu,
                        float* __restrict__ wc) {
  int b = blockIdx.x, d = threadIdx.x;  // blockDim = 384
  const float* r = rs + b * kN;
  const float* tb = tokens + (size_t)b * kN * kD + d;
  float T = 0.f, S = 0.f;
  for (int n = 0; n < kN; ++n) {
    float rv = r[n];
    T += tb[(size_t)n * kD] * rv;
    S += rv;
  }
  float invtr = 1.0f / (trw[b] + kEPS);
  float m = T * invtr;
  mu[b * kD + d] = m;
  wc[b * kD + d] = m * (1.0f - S * invtr);
}

__global__ void k_xc(const float* __restrict__ tokens, const float* __restrict__ mu,
                     float* __restrict__ xc) {
  size_t total = (size_t)kB * kN * kD;
  for (size_t i = (size_t)blockIdx.x * blockDim.x + threadIdx.x; i < total;
       i += (size_t)gridDim.x * blockDim.x) {
    int d = (int)(i % kD);
    int b = (int)(i / ((size_t)kN * kD));
    xc[i] = tokens[i] - mu[b * kD + d];
  }
}

__global__ __launch_bounds__(256) void k_wx(const float* __restrict__ g,
                                            const float* __restrict__ isq,
                                            const float* __restrict__ xc,
                                            float* __restrict__ wx) {
  __shared__ float Gs[16][68];
  __shared__ float Bs[16][68];
  int b = blockIdx.z;
  int n0 = blockIdx.x * 64, i0 = blockIdx.y * 64;
  int tid = threadIdx.x, tx = tid & 15, ty = tid >> 4;
  const float* gb = g + (size_t)b * kN * kN;
  const float* is = isq + b * kN;
  const float* xb = xc + (size_t)b * kN * kD;
  float acc[4][4] = {};
  for (int kt = 0; kt < kN; kt += 16) {
#pragma unroll
    for (int l = 0; l < 4; ++l) {
      int idx = tid + 256 * l;
      int r = idx >> 4, k = idx & 15;
      int ii = i0 + r, kk = kt + k;
      float v = 0.f;
      if (ii < kN && kk < kN) v = gb[(size_t)ii * kN + kk] * is[ii] * is[kk];
      Gs[k][r] = v;
      int n = idx & 63, k2 = idx >> 6;
      int kk2 = kt + k2;
      float v2 = 0.f;
      if (kk2 < kN) v2 = xb[(size_t)kk2 * kD + n0 + n];
      Bs[k2][n] = v2;
    }
    __syncthreads();
#pragma unroll
    for (int k = 0; k < 16; ++k) {
      float a[4], bb[4];
#pragma unroll
      for (int i = 0; i < 4; ++i) a[i] = Gs[k][ty * 4 + i];
#pragma unroll
      for (int j = 0; j < 4; ++j) bb[j] = Bs[k][tx * 4 + j];
#pragma unroll
      for (int i = 0; i < 4; ++i)
#pragma unroll
        for (int j = 0; j < 4; ++j) acc[i][j] += a[i] * bb[j];
    }
    __syncthreads();
  }
  for (int i = 0; i < 4; ++i) {
    int row = i0 + ty * 4 + i;
    if (row < kN) {
      float4 v = make_float4(acc[i][0], acc[i][1], acc[i][2], acc[i][3]);
      *(float4*)&wx[(size_t)b * kN * kD + (size_t)row * kD + n0 + tx * 4] = v;
    }
  }
}

__global__ __launch_bounds__(256) void k_m2(const float* __restrict__ xc,
                                            const float* __restrict__ wx,
                                            float* __restrict__ m2) {
  __shared__ float As[16][68];
  __shared__ float Bs[16][68];
  int b = blockIdx.z;
  int e0 = blockIdx.x * 64, d0 = blockIdx.y * 64;
  int tid = threadIdx.x, tx = tid & 15, ty = tid >> 4;
  const float* xb = xc + (size_t)b * kN * kD;
  const float* wb = wx + (size_t)b * kN * kD;
  float acc[4][4] = {};
  for (int kt = 0; kt < kN; kt += 16) {
#pragma unroll
    for (int l = 0; l < 4; ++l) {
      int idx = tid + 256 * l;
      int m = idx & 63, k = idx >> 6;
      int kk = kt + k;
      float va = 0.f, vb = 0.f;
      if (kk < kN) {
        va = xb[(size_t)kk * kD + d0 + m];
        vb = wb[(size_t)kk * kD + e0 + m];
      }
      As[k][m] = va;
      Bs[k][m] = vb;
    }
    __syncthreads();
#pragma unroll
    for (int k = 0; k < 16; ++k) {
      float a[4], bb[4];
#pragma unroll
      for (int i = 0; i < 4; ++i) a[i] = As[k][ty * 4 + i];
#pragma unroll
      for (int j = 0; j < 4; ++j) bb[j] = Bs[k][tx * 4 + j];
#pragma unroll
      for (int i = 0; i < 4; ++i)
#pragma unroll
        for (int j = 0; j < 4; ++j) acc[i][j] += a[i] * bb[j];
    }
    __syncthreads();
  }
  for (int i = 0; i < 4; ++i) {
    int row = d0 + ty * 4 + i;
    float4 v = make_float4(acc[i][0], acc[i][1], acc[i][2], acc[i][3]);
    *(float4*)&m2[(size_t)b * kDD + (size_t)row * kD + e0 + tx * 4] = v;
  }
}

__global__ void k_trace(const float* __restrict__ m2, float* __restrict__ tinv,
                        float* __restrict__ tsc) {
  int b = blockIdx.x;
  const float* mb = m2 + (size_t)b * kDD;
  float s = 0.f;
  for (int d = threadIdx.x; d < kD; d += 64) s += mb[(size_t)d * kD + d];
#pragma unroll
  for (int off = 32; off; off >>= 1) s += __shfl_down(s, off);
  if (threadIdx.x == 0) {
    float t = s + kEPS;
    tinv[b] = 1.0f / t;
    tsc[b] = 1.0f / sqrtf(t);
  }
}

// M2 fp32 -> Y1 (bf16 row-major), AT (bf16, =A^T), Y1T (bf16, =Y1^T)
// A = M2*tinv; Y1 = 1.5I - 0.5A.  64x64 tiles, LDS transpose.
__global__ __launch_bounds__(256) void k_init2(const float* __restrict__ M2,
                                               const float* __restrict__ tinv,
                                               ushort* __restrict__ Y1,
                                               ushort* __restrict__ AT,
                                               ushort* __restrict__ Y1T) {
  __shared__ ushort Ls[64][72];
  int b = blockIdx.z;
  int r0 = blockIdx.y * 64, c0 = blockIdx.x * 64;
  int tid = threadIdx.x;
  float ti = tinv[b];
  const float* Mb = M2 + (size_t)b * kDD;
  ushort* Yb = Y1 + (size_t)b * kDD;
#pragma unroll
  for (int h = 0; h < 4; ++h) {
    int id = tid + 256 * h;
    int r = id >> 4, c4 = id & 15;
    float4 m = *(const float4*)(Mb + (size_t)(r0 + r) * kD + c0 + c4 * 4);
    const float* mp = (const float*)&m;
    u16x4 y;
#pragma unroll
    for (int e = 0; e < 4; ++e) {
      float av = mp[e] * ti;
      Ls[r][c4 * 4 + e] = f2bf(av);
      float yv = ((r0 + r) == (c0 + c4 * 4 + e) ? 1.5f : 0.f) - 0.5f * av;
      y[e] = f2bf(yv);
    }
    *(u16x4*)(Yb + (size_t)(r0 + r) * kD + c0 + c4 * 4) = y;
  }
  __syncthreads();
  int oc = tid >> 2, och = tid & 3;
  ushort atv[16], ytv[16];
#pragma unroll
  for (int s = 0; s < 16; ++s) {
    int r = och * 16 + s;
    ushort a = Ls[r][oc];
    atv[s] = a;
    float av = bf2f(a);
    float yv = ((c0 + oc) == (r0 + r) ? 1.5f : 0.f) - 0.5f * av;
    ytv[s] = f2bf(yv);
  }
  size_t obase = (size_t)b * kDD + (size_t)(c0 + oc) * kD + r0 + och * 16;
  *(s16x8*)(AT + obase) = *(s16x8*)&atv[0];
  *(s16x8*)(AT + obase + 8) = *(s16x8*)&atv[8];
  *(s16x8*)(Y1T + obase) = *(s16x8*)&ytv[0];
  *(s16x8*)(Y1T + obase + 8) = *(s16x8*)&ytv[8];
}

// ---------------- batched bf16 MFMA GEMM 384x384x384 ----------------
// C = amul*(A @ Bt^T) + dadd*I   (Bt holds B^T row-major; both read identically)
// optional Ct = C^T.  Tile 128x128, BK=32, 4 waves (2x2), wave tile 64x64.

__device__ inline float4 ld_g4(const ushort* g, int row, int col) {
  return *(const float4*)(g + (size_t)row * kD + col);
}
__device__ inline void st_tile(ushort* base, int r, int kb, float4 v) {
  *(float4*)((char*)base + kb * 2048 + ((r ^ (kb << 2)) << 4)) = v;
}
__device__ inline s16x8 ld_frag(const ushort* base, int row, int kq) {
  return *(const s16x8*)((const char*)base + kq * 2048 + ((row ^ (kq << 2)) << 4));
}

__global__ __launch_bounds__(256) void k_mfma384(const ushort* __restrict__ A,
                                                 const ushort* __restrict__ Bt,
                                                 ushort* __restrict__ C,
                                                 ushort* __restrict__ Ct,
                                                 float amul, float dadd) {
  __shared__ ushort lds[16384];  // 32KB: 2 x (A 4096 + B 4096)
  int b = blockIdx.z;
  size_t boff = (size_t)b * kDD;
  int m0 = blockIdx.y * 128, n0 = blockIdx.x * 128;
  int tid = threadIdx.x;
  int lane = tid & 63, wid = tid >> 6;
  int wr = wid >> 1, wc = wid & 1;
  int l15 = lane & 15, kq = lane >> 4;
  const ushort* Ag = A + boff;
  const ushort* Bg = Bt + boff;
  int rs = tid >> 2, kb = tid & 3;

  f32x4 acc[4][4];
#pragma unroll
  for (int i = 0; i < 4; ++i)
#pragma unroll
    for (int j = 0; j < 4; ++j) acc[i][j] = (f32x4){0.f, 0.f, 0.f, 0.f};

  float4 sa0 = ld_g4(Ag, m0 + rs, kb * 8);
  float4 sa1 = ld_g4(Ag, m0 + rs + 64, kb * 8);
  float4 sb0 = ld_g4(Bg, n0 + rs, kb * 8);
  float4 sb1 = ld_g4(Bg, n0 + rs + 64, kb * 8);
  st_tile(lds, rs, kb, sa0);
  st_tile(lds, rs + 64, kb, sa1);
  st_tile(lds + 4096, rs, kb, sb0);
  st_tile(lds + 4096, rs + 64, kb, sb1);
  __syncthreads();

  for (int kt = 0; kt < 12; ++kt) {
    ushort* Lc = lds + (kt & 1) * 8192;
    if (kt < 11) {
      int kk = (kt + 1) * 32 + kb * 8;
      sa0 = ld_g4(Ag, m0 + rs, kk);
      sa1 = ld_g4(Ag, m0 + rs + 64, kk);
      sb0 = ld_g4(Bg, n0 + rs, kk);
      sb1 = ld_g4(Bg, n0 + rs + 64, kk);
    }
    s16x8 af[4], bfv[4];
#pragma unroll
    for (int i = 0; i < 4; ++i) af[i] = ld_frag(Lc, wr * 64 + i * 16 + l15, kq);
#pragma unroll
    for (int j = 0; j < 4; ++j) bfv[j] = ld_frag(Lc + 4096, wc * 64 + j * 16 + l15, kq);
#pragma unroll
    for (int i = 0; i < 4; ++i)
#pragma unroll
      for (int j = 0; j < 4; ++j)
        acc[i][j] = __builtin_amdgcn_mfma_f32_16x16x32_bf16(af[i], bfv[j], acc[i][j], 0, 0, 0);
    __syncthreads();
    if (kt < 11) {
      ushort* Ln = lds + ((kt + 1) & 1) * 8192;
      st_tile(Ln, rs, kb, sa0);
      st_tile(Ln, rs + 64, kb, sa1);
      st_tile(Ln + 4096, rs, kb, sb0);
      st_tile(Ln + 4096, rs + 64, kb, sb1);
    }
    __syncthreads();
  }

  // ---- epilogue: C via LDS (coalesced), optional Ct ----
  // C layout: byte = row*256 + ((col*2) ^ ((row&15)<<4))
#pragma unroll
  for (int i = 0; i < 4; ++i)
#pragma unroll
    for (int j = 0; j < 4; ++j) {
      int row0 = wr * 64 + i * 16 + kq * 4;
      int col = wc * 64 + j * 16 + l15;
#pragma unroll
      for (int v = 0; v < 4; ++v) {
        int row = row0 + v;
        float f = amul * acc[i][j][v] + ((m0 + row) == (n0 + col) ? dadd : 0.f);
        int byt = row * 256 + ((col * 2) ^ ((row & 15) << 4));
        *(ushort*)((char*)lds + byt) = f2bf(f);
      }
    }
  __syncthreads();
#pragma unroll
  for (int h = 0; h < 8; ++h) {
    int id = tid + 256 * h;
    int row = id >> 4, c16 = id & 15;
    int byt = row * 256 + ((c16 * 16) ^ ((row & 15) << 4));
    s16x8 vv = *(const s16x8*)((char*)lds + byt);
    *(s16x8*)(C + boff + (size_t)(m0 + row) * kD + n0 + c16 * 8) = vv;
  }
  if (Ct) {
    __syncthreads();
#pragma unroll
    for (int i = 0; i < 4; ++i)
#pragma unroll
      for (int j = 0; j < 4; ++j) {
        int row0 = wr * 64 + i * 16 + kq * 4;
        int col = wc * 64 + j * 16 + l15;
        u16x4 pk;
#pragma unroll
        for (int v = 0; v < 4; ++v) {
          float f = amul * acc[i][j][v] + ((m0 + row0 + v) == (n0 + col) ? dadd : 0.f);
          pk[v] = f2bf(f);
        }
        int byt = col * 256 + ((row0 * 2) ^ ((col & 15) << 4));
        *(u16x4*)((char*)lds + byt) = pk;
      }
    __syncthreads();
#pragma unroll
    for (int h = 0; h < 8; ++h) {
      int id = tid + 256 * h;
      int p = id >> 4, c16 = id & 15;
      int byt = p * 256 + ((c16 * 16) ^ ((p & 15) << 4));
      s16x8 vv = *(const s16x8*)((char*)lds + byt);
      *(s16x8*)(Ct + boff + (size_t)(n0 + p) * kD + m0 + c16 * 8) = vv;
    }
  }
}

__global__ void k_trigather_bf(const ushort* __restrict__ y, const float* __restrict__ tsc,
                               float* __restrict__ m2v) {
  size_t total = (size_t)kB * kTRI;
  for (size_t i = (size_t)blockIdx.x * blockDim.x + threadIdx.x; i < total;
       i += (size_t)gridDim.x * blockDim.x) {
    int b = (int)(i / kTRI);
    int t = (int)(i % kTRI);
    float disc = 591361.0f - 8.0f * (float)t;  // (2D+1)^2 - 8t
    int r = (int)((769.0f - sqrtf(disc)) * 0.5f);
    if (r > kD - 1) r = kD - 1;
    if (r < 0) r = 0;
    while (r > 0 && (r * (769 - r)) / 2 > t) --r;
    while (r < kD - 1 && ((r + 1) * (769 - (r + 1))) / 2 <= t) ++r;
    int base = (r * (769 - r)) / 2;
    int c = r + (t - base);
    m2v[i] = bf2f(y[(size_t)b * kDD + (size_t)r * kD + c]) * tsc[b];
  }
}

__global__ void k_bias_init(float* __restrict__ dst, const float* __restrict__ bias,
                            int cols, int ldo) {
  int total = kB * cols;
  for (int i = blockIdx.x * blockDim.x + threadIdx.x; i < total;
       i += gridDim.x * blockDim.x) {
    int row = i / cols, col = i % cols;
    dst[(size_t)row * ldo + col] = bias[col];
  }
}

// skinny GEMM, M=64, double-buffered: C[64 x N] += A[64 x K] @ B[K x N]
__global__ __launch_bounds__(256) void k_skinny2(const float* __restrict__ A, int lda,
                                                 const float* __restrict__ Bm, int ldb,
                                                 float* __restrict__ C, int ldc,
                                                 int ktiles) {
  __shared__ float As[2][16][68];
  __shared__ float Bs[2][16][68];
  int n0 = blockIdx.x * 64;
  int kt0 = blockIdx.y * ktiles * 16;
  int tid = threadIdx.x, tx = tid & 15, ty = tid >> 4;
  int ar = tid >> 2, aq = tid & 3;
  int bk = tid >> 4, bq = tid & 15;
  float4 apre = *(const float4*)&A[(size_t)ar * lda + kt0 + aq * 4];
  float4 bpre = *(const float4*)&Bm[(size_t)(kt0 + bk) * ldb + n0 + bq * 4];
  As[0][aq * 4 + 0][ar] = apre.x;
  As[0][aq * 4 + 1][ar] = apre.y;
  As[0][aq * 4 + 2][ar] = apre.z;
  As[0][aq * 4 + 3][ar] = apre.w;
  *(float4*)&Bs[0][bk][bq * 4] = bpre;
  __syncthreads();
  float acc[4][4] = {};
  for (int t = 0; t < ktiles; ++t) {
    int cur = t & 1;
    if (t + 1 < ktiles) {
      int kt = kt0 + (t + 1) * 16;
      apre = *(const float4*)&A[(size_t)ar * lda + kt + aq * 4];
      bpre = *(const float4*)&Bm[(size_t)(kt + bk) * ldb + n0 + bq * 4];
    }
#pragma unroll
    for (int k = 0; k < 16; ++k) {
      float a[4], bb[4];
#pragma unroll
      for (int i = 0; i < 4; ++i) a[i] = As[cur][k][ty * 4 + i];
#pragma unroll
      for (int j = 0; j < 4; ++j) bb[j] = Bs[cur][k][tx * 4 + j];
#pragma unroll
      for (int i = 0; i < 4; ++i)
#pragma unroll
        for (int j = 0; j < 4; ++j) acc[i][j] += a[i] * bb[j];
    }
    __syncthreads();
    if (t + 1 < ktiles) {
      int nxt = cur ^ 1;
      As[nxt][aq * 4 + 0][ar] = apre.x;
      As[nxt][aq * 4 + 1][ar] = apre.y;
      As[nxt][aq * 4 + 2][ar] = apre.z;
      As[nxt][aq * 4 + 3][ar] = apre.w;
      *(float4*)&Bs[nxt][bk][bq * 4] = bpre;
    }
    __syncthreads();
  }
  for (int i = 0; i < 4; ++i)
    for (int j = 0; j < 4; ++j)
      atomicAdd(&C[(size_t)(ty * 4 + i) * ldc + n0 + tx * 4 + j], acc[i][j]);
}

__global__ void k_bngelu(const float* __restrict__ h, const float* __restrict__ gamma,
                         const float* __restrict__ beta, const float* __restrict__ rm,
                         const float* __restrict__ rv, float* __restrict__ o, int cols) {
  int total = kB * cols;
  for (int i = blockIdx.x * blockDim.x + threadIdx.x; i < total;
       i += gridDim.x * blockDim.x) {
    int col = i % cols;
    float x = h[i];
    float xn = (x - rm[col]) / sqrtf(rv[col] + kBNEPS) * gamma[col] + beta[col];
    o[i] = xn * 0.5f * (1.0f + erff(xn * 0.70710678118654752f));
  }
}

__global__ void k_sketch(const float* __restrict__ wc, const int* __restrict__ h1,
                         const int* __restrict__ h2, const int* __restrict__ h3,
                         const float* __restrict__ s1, const float* __restrict__ s2,
                         const float* __restrict__ s3, float* __restrict__ sk) {
  __shared__ float L1[kS];
  __shared__ float L2[kS];
  __shared__ float L3[kS];
  int b = blockIdx.x;
  for (int i = threadIdx.x; i < kS; i += blockDim.x) {
    L1[i] = 0.f;
    L2[i] = 0.f;
    L3[i] = 0.f;
  }
  __syncthreads();
  for (int d = threadIdx.x; d < kD; d += blockDim.x) {
    float w = wc[b * kD + d];
    atomicAdd(&L1[h1[d]], w * s1[d]);
    atomicAdd(&L2[h2[d]], w * s2[d]);
    atomicAdd(&L3[h3[d]], w * s3[d]);
  }
  __syncthreads();
  for (int i = threadIdx.x; i < kS; i += blockDim.x)
    sk[(size_t)b * kS + i] = L1[i] * L2[i] * L3[i];
}

}  // namespace

extern "C" void kernel_launch(void* const* d_in, const int* in_sizes, int n_in,
                              void* d_out, int out_size, void* d_ws, size_t ws_size,
                              hipStream_t stream) {
  (void)in_sizes; (void)n_in; (void)out_size; (void)ws_size;
  const float* tokens = (const float*)d_in[0];
  const float* graph  = (const float*)d_in[1];
  const int*   hash1  = (const int*)d_in[2];
  const int*   hash2  = (const int*)d_in[3];
  const int*   hash3  = (const int*)d_in[4];
  const float* sign1  = (const float*)d_in[5];
  const float* sign2  = (const float*)d_in[6];
  const float* sign3  = (const float*)d_in[7];
  const float* w1_2   = (const float*)d_in[8];
  const float* b1_2   = (const float*)d_in[9];
  const float* gamma2 = (const float*)d_in[10];
  const float* beta2  = (const float*)d_in[11];
  const float* rm2    = (const float*)d_in[12];
  const float* rv2    = (const float*)d_in[13];
  const float* w2_2   = (const float*)d_in[14];
  const float* b2_2   = (const float*)d_in[15];
  const float* w1_3   = (const float*)d_in[16];
  const float* b1_3   = (const float*)d_in[17];
  const float* gamma3 = (const float*)d_in[18];
  const float* beta3  = (const float*)d_in[19];
  const float* rm3    = (const float*)d_in[20];
  const float* rv3    = (const float*)d_in[21];
  const float* w2_3   = (const float*)d_in[22];
  const float* b2_3   = (const float*)d_in[23];
  float* outp = (float*)d_out;

  char* cp = (char*)d_ws;
  auto takeB = [&](size_t bytes) {
    char* q = cp;
    cp += (bytes + 255) & ~(size_t)255;
    return q;
  };
  float* isq  = (float*)takeB((size_t)kB * kN * 4);
  float* rsb  = (float*)takeB((size_t)kB * kN * 4);
  float* trw  = (float*)takeB(256);
  float* tinv = (float*)takeB(256);
  float* tsc  = (float*)takeB(256);
  float* mu   = (float*)takeB((size_t)kB * kD * 4);
  float* wc   = (float*)takeB((size_t)kB * kD * 4);
  float* xc   = (float*)takeB((size_t)kB * kN * kD * 4);
  float* wx   = (float*)takeB((size_t)kB * kN * kD * 4);
  float* M2   = (float*)takeB((size_t)kB * kDD * 4);
  ushort* AT  = (ushort*)takeB((size_t)kB * kDD * 2);
  ushort* Ya  = (ushort*)takeB((size_t)kB * kDD * 2);
  ushort* Yb2 = (ushort*)takeB((size_t)kB * kDD * 2);
  ushort* YTa = (ushort*)takeB((size_t)kB * kDD * 2);
  ushort* YTb = (ushort*)takeB((size_t)kB * kDD * 2);
  float* m2v  = (float*)takeB((size_t)kB * kTRI * 4);
  float* h1b  = (float*)takeB((size_t)kB * 1024 * 4);
  float* h1g  = (float*)takeB((size_t)kB * 1024 * 4);
  float* h3b  = (float*)takeB((size_t)kB * 1024 * 4);
  float* h3g  = (float*)takeB((size_t)kB * 1024 * 4);
  float* sk   = (float*)takeB((size_t)kB * kS * 4);
  // after k_init2, M2 fp32 region is dead -> reuse as two bf16 buffers
  ushort* Tbuf = (ushort*)M2;
  ushort* Vbuf = (ushort*)M2 + (size_t)kB * kDD;

  hipLaunchKernelGGL(k_zero64, dim3(1), dim3(64), 0, stream, trw);
  hipLaunchKernelGGL(k_deg, dim3(kN, kB), dim3(64), 0, stream, graph, isq);
  hipLaunchKernelGGL(k_rowsum, dim3(kN, kB), dim3(64), 0, stream, graph, isq, rsb, trw);
  hipLaunchKernelGGL(k_mu_wc, dim3(kB), dim3(kD), 0, stream, tokens, rsb, trw, mu, wc);
  hipLaunchKernelGGL(k_xc, dim3(8192), dim3(256), 0, stream, tokens, mu, xc);
  hipLaunchKernelGGL(k_wx, dim3(6, 4, kB), dim3(256), 0, stream, graph, isq, xc, wx);
  hipLaunchKernelGGL(k_m2, dim3(6, 6, kB), dim3(256), 0, stream, xc, wx, M2);
  hipLaunchKernelGGL(k_trace, dim3(kB), dim3(64), 0, stream, M2, tinv, tsc);
  hipLaunchKernelGGL(k_init2, dim3(6, 6, kB), dim3(256), 0, stream, M2, tinv, Ya, AT, YTa);

  // Newton-Schulz: per iter  T=Y*Y;  V=1.5I-0.5*T*A;  Ynext=V*Y (+Ynext^T)
  ushort* Yc = Ya;
  ushort* YTc = YTa;
  ushort* Yn = Yb2;
  ushort* YTn = YTb;
  for (int it = 0; it < 4; ++it) {
    hipLaunchKernelGGL(k_mfma384, dim3(3, 3, kB), dim3(256), 0, stream,
                       Yc, YTc, Tbuf, (ushort*)nullptr, 1.f, 0.f);
    hipLaunchKernelGGL(k_mfma384, dim3(3, 3, kB), dim3(256), 0, stream,
                       Tbuf, AT, Vbuf, (ushort*)nullptr, -0.5f, 1.5f);
    hipLaunchKernelGGL(k_mfma384, dim3(3, 3, kB), dim3(256), 0, stream,
                       Vbuf, YTc, Yn, it < 3 ? YTn : (ushort*)nullptr, 1.f, 0.f);
    ushort* t1 = Yc; Yc = Yn; Yn = t1;
    ushort* t2 = YTc; YTc = YTn; YTn = t2;
  }

  hipLaunchKernelGGL(k_trigather_bf, dim3(8192), dim3(256), 0, stream, Yc, tsc, m2v);

  // second path MLP
  hipLaunchKernelGGL(k_bias_init, dim3(256), dim3(256), 0, stream, h1b, b1_2, 1024, 1024);
  hipLaunchKernelGGL(k_skinny2, dim3(16, 66), dim3(256), 0, stream,
                     m2v, kTRI, w1_2, 1024, h1b, 1024, 70);  // 66*70*16 = 73920
  hipLaunchKernelGGL(k_bngelu, dim3(256), dim3(256), 0, stream,
                     h1b, gamma2, beta2, rm2, rv2, h1g, 1024);
  hipLaunchKernelGGL(k_bias_init, dim3(128), dim3(256), 0, stream, outp, b2_2, 512, 1024);
  hipLaunchKernelGGL(k_bias_init, dim3(128), dim3(256), 0, stream, outp + 512, b2_3, 512, 1024);
  hipLaunchKernelGGL(k_skinny2, dim3(8, 16), dim3(256), 0, stream,
                     h1g, 1024, w2_2, 512, outp, 1024, 4);  // 16*4*16 = 1024

  // third path (count-sketch MLP)
  hipLaunchKernelGGL(k_sketch, dim3(kB), dim3(256), 0, stream,
                     wc, hash1, hash2, hash3, sign1, sign2, sign3, sk);
  hipLaunchKernelGGL(k_bias_init, dim3(256), dim3(256), 0, stream, h3b, b1_3, 1024, 1024);
  hipLaunchKernelGGL(k_skinny2, dim3(16, 32), dim3(256), 0, stream,
                     sk, kS, w1_3, 1024, h3b, 1024, 8);  // 32*8*16 = 4096
  hipLaunchKernelGGL(k_bngelu, dim3(256), dim3(256), 0, stream,
                     h3b, gamma3, beta3, rm3, rv3, h3g, 1024);
  hipLaunchKernelGGL(k_skinny2, dim3(8, 16), dim3(256), 0, stream,
                     h3g, 1024, w2_3, 512, outp + 512, 1024, 4);
}

// Round 3
// 918.029 us; speedup vs baseline: 2.0601x; 1.1612x over previous
//
#include <hip/hip_runtime.h>
#include <math.h>

namespace {

constexpr int kB   = 64;
constexpr int kN   = 196;
constexpr int kD   = 384;
constexpr int kS   = 4096;
constexpr int kTRI = 73920;
constexpr int kDD  = kD * kD;          // 147456
constexpr float kEPS   = 1e-5f;
constexpr float kBNEPS = 1e-5f;

typedef __attribute__((ext_vector_type(8))) short s16x8;
typedef __attribute__((ext_vector_type(4))) float f32x4;
typedef __attribute__((ext_vector_type(4))) ushort u16x4;

__device__ inline float bf2f(ushort h) {
  union { uint u; float f; } v; v.u = (uint)h << 16; return v.f;
}
__device__ inline ushort f2bf(float f) {
  union { float f; uint u; } v; v.f = f;
  uint r = v.u + 0x7FFF + ((v.u >> 16) & 1);
  return (ushort)(r >> 16);
}

// ---------------- small utility kernels ----------------

__global__ void k_zero64(float* p) { p[threadIdx.x] = 0.f; }

__global__ void k_deg(const float* __restrict__ g, float* __restrict__ isq) {
  int i = blockIdx.x, b = blockIdx.y;
  const float* row = g + ((size_t)b * kN + i) * kN;
  float s = 0.f;
  for (int j = threadIdx.x; j < kN; j += 64) s += row[j];
#pragma unroll
  for (int off = 32; off; off >>= 1) s += __shfl_down(s, off);
  if (threadIdx.x == 0) {
    float dg = s < kEPS ? kEPS : s;
    isq[b * kN + i] = 1.0f / sqrtf(dg);
  }
}

__global__ void k_rowsum(const float* __restrict__ g, const float* __restrict__ isq,
                         float* __restrict__ rs, float* __restrict__ trw) {
  int i = blockIdx.x, b = blockIdx.y;
  const float* row = g + ((size_t)b * kN + i) * kN;
  const float* is = isq + b * kN;
  float s = 0.f, diag = 0.f;
  for (int j = threadIdx.x; j < kN; j += 64) {
    float gv = row[j];
    s += gv * is[j];
    if (j == i) diag = gv;
  }
#pragma unroll
  for (int off = 32; off; off >>= 1) {
    s += __shfl_down(s, off);
    diag += __shfl_down(diag, off);
  }
  if (threadIdx.x == 0) {
    float isi = is[i];
    rs[b * kN + i] = isi * s;
    atomicAdd(&trw[b], diag * isi * isi);
  }
}

__global__ void k_mu_wc(const float* __restrict__ tokens, const float* __restrict__ rs,
                        const float* __restrict__ trw, float* __restrict__ mu,
                        float* __restrict__ wc) {
  int b = blockIdx.x, d = threadIdx.x;  // blockDim = 384
  const float* r = rs + b * kN;
  const float* tb = tokens + (size_t)b * kN * kD + d;
  float T = 0.f, S = 0.f;
  for (int n = 0; n < kN; ++n) {
    float rv = r[n];
    T += tb[(size_t)n * kD] * rv;
    S += rv;
  }
  float invtr = 1.0f / (trw[b] + kEPS);
  float m = T * invtr;
  mu[b * kD + d] = m;
  wc[b * kD + d] = m * (1.0f - S * invtr);
}

__global__ void k_xc(const float* __restrict__ tokens, const float* __restrict__ mu,
                     float* __restrict__ xc) {
  size_t total = (size_t)kB * kN * kD;
  for (size_t i = (size_t)blockIdx.x * blockDim.x + threadIdx.x; i < total;
       i += (size_t)gridDim.x * blockDim.x) {
    int d = (int)(i % kD);
    int b = (int)(i / ((size_t)kN * kD));
    xc[i] = tokens[i] - mu[b * kD + d];
  }
}

__global__ __launch_bounds__(256) void k_wx(const float* __restrict__ g,
                                            const float* __restrict__ isq,
                                            const float* __restrict__ xc,
                                            float* __restrict__ wx) {
  __shared__ float Gs[16][68];
  __shared__ float Bs[16][68];
  int b = blockIdx.z;
  int n0 = blockIdx.x * 64, i0 = blockIdx.y * 64;
  int tid = threadIdx.x, tx = tid & 15, ty = tid >> 4;
  const float* gb = g + (size_t)b * kN * kN;
  const float* is = isq + b * kN;
  const float* xb = xc + (size_t)b * kN * kD;
  float acc[4][4] = {};
  for (int kt = 0; kt < kN; kt += 16) {
#pragma unroll
    for (int l = 0; l < 4; ++l) {
      int idx = tid + 256 * l;
      int r = idx >> 4, k = idx & 15;
      int ii = i0 + r, kk = kt + k;
      float v = 0.f;
      if (ii < kN && kk < kN) v = gb[(size_t)ii * kN + kk] * is[ii] * is[kk];
      Gs[k][r] = v;
      int n = idx & 63, k2 = idx >> 6;
      int kk2 = kt + k2;
      float v2 = 0.f;
      if (kk2 < kN) v2 = xb[(size_t)kk2 * kD + n0 + n];
      Bs[k2][n] = v2;
    }
    __syncthreads();
#pragma unroll
    for (int k = 0; k < 16; ++k) {
      float a[4], bb[4];
#pragma unroll
      for (int i = 0; i < 4; ++i) a[i] = Gs[k][ty * 4 + i];
#pragma unroll
      for (int j = 0; j < 4; ++j) bb[j] = Bs[k][tx * 4 + j];
#pragma unroll
      for (int i = 0; i < 4; ++i)
#pragma unroll
        for (int j = 0; j < 4; ++j) acc[i][j] += a[i] * bb[j];
    }
    __syncthreads();
  }
  for (int i = 0; i < 4; ++i) {
    int row = i0 + ty * 4 + i;
    if (row < kN) {
      float4 v = make_float4(acc[i][0], acc[i][1], acc[i][2], acc[i][3]);
      *(float4*)&wx[(size_t)b * kN * kD + (size_t)row * kD + n0 + tx * 4] = v;
    }
  }
}

__global__ __launch_bounds__(256) void k_m2(const float* __restrict__ xc,
                                            const float* __restrict__ wx,
                                            float* __restrict__ m2) {
  __shared__ float As[16][68];
  __shared__ float Bs[16][68];
  int b = blockIdx.z;
  int e0 = blockIdx.x * 64, d0 = blockIdx.y * 64;
  int tid = threadIdx.x, tx = tid & 15, ty = tid >> 4;
  const float* xb = xc + (size_t)b * kN * kD;
  const float* wb = wx + (size_t)b * kN * kD;
  float acc[4][4] = {};
  for (int kt = 0; kt < kN; kt += 16) {
#pragma unroll
    for (int l = 0; l < 4; ++l) {
      int idx = tid + 256 * l;
      int m = idx & 63, k = idx >> 6;
      int kk = kt + k;
      float va = 0.f, vb = 0.f;
      if (kk < kN) {
        va = xb[(size_t)kk * kD + d0 + m];
        vb = wb[(size_t)kk * kD + e0 + m];
      }
      As[k][m] = va;
      Bs[k][m] = vb;
    }
    __syncthreads();
#pragma unroll
    for (int k = 0; k < 16; ++k) {
      float a[4], bb[4];
#pragma unroll
      for (int i = 0; i < 4; ++i) a[i] = As[k][ty * 4 + i];
#pragma unroll
      for (int j = 0; j < 4; ++j) bb[j] = Bs[k][tx * 4 + j];
#pragma unroll
      for (int i = 0; i < 4; ++i)
#pragma unroll
        for (int j = 0; j < 4; ++j) acc[i][j] += a[i] * bb[j];
    }
    __syncthreads();
  }
  for (int i = 0; i < 4; ++i) {
    int row = d0 + ty * 4 + i;
    float4 v = make_float4(acc[i][0], acc[i][1], acc[i][2], acc[i][3]);
    *(float4*)&m2[(size_t)b * kDD + (size_t)row * kD + e0 + tx * 4] = v;
  }
}

__global__ void k_trace(const float* __restrict__ m2, float* __restrict__ tinv,
                        float* __restrict__ tsc) {
  int b = blockIdx.x;
  const float* mb = m2 + (size_t)b * kDD;
  float s = 0.f;
  for (int d = threadIdx.x; d < kD; d += 64) s += mb[(size_t)d * kD + d];
#pragma unroll
  for (int off = 32; off; off >>= 1) s += __shfl_down(s, off);
  if (threadIdx.x == 0) {
    float t = s + kEPS;
    tinv[b] = 1.0f / t;
    tsc[b] = 1.0f / sqrtf(t);
  }
}

// M2 fp32 -> Y1 (bf16 row-major), AT (bf16, =A^T), Y1T (bf16, =Y1^T)
__global__ __launch_bounds__(256) void k_init2(const float* __restrict__ M2,
                                               const float* __restrict__ tinv,
                                               ushort* __restrict__ Y1,
                                               ushort* __restrict__ AT,
                                               ushort* __restrict__ Y1T) {
  __shared__ ushort Ls[64][72];
  int b = blockIdx.z;
  int r0 = blockIdx.y * 64, c0 = blockIdx.x * 64;
  int tid = threadIdx.x;
  float ti = tinv[b];
  const float* Mb = M2 + (size_t)b * kDD;
  ushort* Yb = Y1 + (size_t)b * kDD;
#pragma unroll
  for (int h = 0; h < 4; ++h) {
    int id = tid + 256 * h;
    int r = id >> 4, c4 = id & 15;
    float4 m = *(const float4*)(Mb + (size_t)(r0 + r) * kD + c0 + c4 * 4);
    const float* mp = (const float*)&m;
    u16x4 y;
#pragma unroll
    for (int e = 0; e < 4; ++e) {
      float av = mp[e] * ti;
      Ls[r][c4 * 4 + e] = f2bf(av);
      float yv = ((r0 + r) == (c0 + c4 * 4 + e) ? 1.5f : 0.f) - 0.5f * av;
      y[e] = f2bf(yv);
    }
    *(u16x4*)(Yb + (size_t)(r0 + r) * kD + c0 + c4 * 4) = y;
  }
  __syncthreads();
  int oc = tid >> 2, och = tid & 3;
  ushort atv[16], ytv[16];
#pragma unroll
  for (int s = 0; s < 16; ++s) {
    int r = och * 16 + s;
    ushort a = Ls[r][oc];
    atv[s] = a;
    float av = bf2f(a);
    float yv = ((c0 + oc) == (r0 + r) ? 1.5f : 0.f) - 0.5f * av;
    ytv[s] = f2bf(yv);
  }
  size_t obase = (size_t)b * kDD + (size_t)(c0 + oc) * kD + r0 + och * 16;
  *(s16x8*)(AT + obase) = *(s16x8*)&atv[0];
  *(s16x8*)(AT + obase + 8) = *(s16x8*)&atv[8];
  *(s16x8*)(Y1T + obase) = *(s16x8*)&ytv[0];
  *(s16x8*)(Y1T + obase + 8) = *(s16x8*)&ytv[8];
}

// ---------------- batched bf16 MFMA GEMM 384x384x384 ----------------

__device__ inline float4 ld_g4(const ushort* g, int row, int col) {
  return *(const float4*)(g + (size_t)row * kD + col);
}
__device__ inline void st_tile(ushort* base, int r, int kb, float4 v) {
  *(float4*)((char*)base + kb * 2048 + ((r ^ (kb << 2)) << 4)) = v;
}
__device__ inline s16x8 ld_frag(const ushort* base, int row, int kq) {
  return *(const s16x8*)((const char*)base + kq * 2048 + ((row ^ (kq << 2)) << 4));
}

__global__ __launch_bounds__(256) void k_mfma384(const ushort* __restrict__ A,
                                                 const ushort* __restrict__ Bt,
                                                 ushort* __restrict__ C,
                                                 ushort* __restrict__ Ct,
                                                 float amul, float dadd) {
  __shared__ ushort lds[16384];  // 32KB: 2 x (A 4096 + B 4096)
  int b = blockIdx.z;
  size_t boff = (size_t)b * kDD;
  int m0 = blockIdx.y * 128, n0 = blockIdx.x * 128;
  int tid = threadIdx.x;
  int lane = tid & 63, wid = tid >> 6;
  int wr = wid >> 1, wc = wid & 1;
  int l15 = lane & 15, kq = lane >> 4;
  const ushort* Ag = A + boff;
  const ushort* Bg = Bt + boff;
  int rs = tid >> 2, kb = tid & 3;

  f32x4 acc[4][4];
#pragma unroll
  for (int i = 0; i < 4; ++i)
#pragma unroll
    for (int j = 0; j < 4; ++j) acc[i][j] = (f32x4){0.f, 0.f, 0.f, 0.f};

  float4 sa0 = ld_g4(Ag, m0 + rs, kb * 8);
  float4 sa1 = ld_g4(Ag, m0 + rs + 64, kb * 8);
  float4 sb0 = ld_g4(Bg, n0 + rs, kb * 8);
  float4 sb1 = ld_g4(Bg, n0 + rs + 64, kb * 8);
  st_tile(lds, rs, kb, sa0);
  st_tile(lds, rs + 64, kb, sa1);
  st_tile(lds + 4096, rs, kb, sb0);
  st_tile(lds + 4096, rs + 64, kb, sb1);
  __syncthreads();

  for (int kt = 0; kt < 12; ++kt) {
    ushort* Lc = lds + (kt & 1) * 8192;
    if (kt < 11) {
      int kk = (kt + 1) * 32 + kb * 8;
      sa0 = ld_g4(Ag, m0 + rs, kk);
      sa1 = ld_g4(Ag, m0 + rs + 64, kk);
      sb0 = ld_g4(Bg, n0 + rs, kk);
      sb1 = ld_g4(Bg, n0 + rs + 64, kk);
    }
    s16x8 af[4], bfv[4];
#pragma unroll
    for (int i = 0; i < 4; ++i) af[i] = ld_frag(Lc, wr * 64 + i * 16 + l15, kq);
#pragma unroll
    for (int j = 0; j < 4; ++j) bfv[j] = ld_frag(Lc + 4096, wc * 64 + j * 16 + l15, kq);
#pragma unroll
    for (int i = 0; i < 4; ++i)
#pragma unroll
      for (int j = 0; j < 4; ++j)
        acc[i][j] = __builtin_amdgcn_mfma_f32_16x16x32_bf16(af[i], bfv[j], acc[i][j], 0, 0, 0);
    __syncthreads();
    if (kt < 11) {
      ushort* Ln = lds + ((kt + 1) & 1) * 8192;
      st_tile(Ln, rs, kb, sa0);
      st_tile(Ln, rs + 64, kb, sa1);
      st_tile(Ln + 4096, rs, kb, sb0);
      st_tile(Ln + 4096, rs + 64, kb, sb1);
    }
    __syncthreads();
  }

  // ---- epilogue: C via LDS (coalesced), optional Ct ----
#pragma unroll
  for (int i = 0; i < 4; ++i)
#pragma unroll
    for (int j = 0; j < 4; ++j) {
      int row0 = wr * 64 + i * 16 + kq * 4;
      int col = wc * 64 + j * 16 + l15;
#pragma unroll
      for (int v = 0; v < 4; ++v) {
        int row = row0 + v;
        float f = amul * acc[i][j][v] + ((m0 + row) == (n0 + col) ? dadd : 0.f);
        int byt = row * 256 + ((col * 2) ^ ((row & 15) << 4));
        *(ushort*)((char*)lds + byt) = f2bf(f);
      }
    }
  __syncthreads();
#pragma unroll
  for (int h = 0; h < 8; ++h) {
    int id = tid + 256 * h;
    int row = id >> 4, c16 = id & 15;
    int byt = row * 256 + ((c16 * 16) ^ ((row & 15) << 4));
    s16x8 vv = *(const s16x8*)((char*)lds + byt);
    *(s16x8*)(C + boff + (size_t)(m0 + row) * kD + n0 + c16 * 8) = vv;
  }
  if (Ct) {
    __syncthreads();
#pragma unroll
    for (int i = 0; i < 4; ++i)
#pragma unroll
      for (int j = 0; j < 4; ++j) {
        int row0 = wr * 64 + i * 16 + kq * 4;
        int col = wc * 64 + j * 16 + l15;
        u16x4 pk;
#pragma unroll
        for (int v = 0; v < 4; ++v) {
          float f = amul * acc[i][j][v] + ((m0 + row0 + v) == (n0 + col) ? dadd : 0.f);
          pk[v] = f2bf(f);
        }
        int byt = col * 256 + ((row0 * 2) ^ ((col & 15) << 4));
        *(u16x4*)((char*)lds + byt) = pk;
      }
    __syncthreads();
#pragma unroll
    for (int h = 0; h < 8; ++h) {
      int id = tid + 256 * h;
      int p = id >> 4, c16 = id & 15;
      int byt = p * 256 + ((c16 * 16) ^ ((p & 15) << 4));
      s16x8 vv = *(const s16x8*)((char*)lds + byt);
      *(s16x8*)(Ct + boff + (size_t)(n0 + p) * kD + m0 + c16 * 8) = vv;
    }
  }
}

// trigather: now emits bf16 m2v (A-operand of the big MFMA skinny GEMM)
__global__ void k_trigather_bf(const ushort* __restrict__ y, const float* __restrict__ tsc,
                               ushort* __restrict__ m2v) {
  size_t total = (size_t)kB * kTRI;
  for (size_t i = (size_t)blockIdx.x * blockDim.x + threadIdx.x; i < total;
       i += (size_t)gridDim.x * blockDim.x) {
    int b = (int)(i / kTRI);
    int t = (int)(i % kTRI);
    float disc = 591361.0f - 8.0f * (float)t;  // (2D+1)^2 - 8t
    int r = (int)((769.0f - sqrtf(disc)) * 0.5f);
    if (r > kD - 1) r = kD - 1;
    if (r < 0) r = 0;
    while (r > 0 && (r * (769 - r)) / 2 > t) --r;
    while (r < kD - 1 && ((r + 1) * (769 - (r + 1))) / 2 <= t) ++r;
    int base = (r * (769 - r)) / 2;
    int c = r + (t - base);
    m2v[i] = f2bf(bf2f(y[(size_t)b * kDD + (size_t)r * kD + c]) * tsc[b]);
  }
}

__global__ void k_bias_init(float* __restrict__ dst, const float* __restrict__ bias,
                            int cols, int ldo) {
  int total = kB * cols;
  for (int i = blockIdx.x * blockDim.x + threadIdx.x; i < total;
       i += gridDim.x * blockDim.x) {
    int row = i / cols, col = i % cols;
    dst[(size_t)row * ldo + col] = bias[col];
  }
}

// ---- big skinny GEMM via MFMA: C[64][1024] += A_bf16[64][73920] @ W_fp32[73920][1024]
// grid (16 ncol, KSPLIT); block 256 = 4 waves; wave owns 16 cols; K chunk = steps*32.
__global__ __launch_bounds__(256) void k_skinny_mfma(const ushort* __restrict__ A,
                                                     const float* __restrict__ W,
                                                     float* __restrict__ C,
                                                     int steps) {
  __shared__ ushort As[2][64][40];  // A tile [m][k] bf16, row stride 80B (16B-aligned frags)
  __shared__ ushort Ws[2][32][74];  // W tile [k][n] bf16, pad 74 -> scalar reads spread banks
  int tid = threadIdx.x;
  int lane = tid & 63, w = tid >> 6;
  int l15 = lane & 15, kq = lane >> 4;
  int n0 = blockIdx.x * 64;
  int k0base = blockIdx.y * steps * 32;

  // staging indices
  int ar = tid >> 2, aks = tid & 3;          // A: row, k-segment(8)
  int wr = tid >> 3, wc0 = (tid & 7) * 8;    // W: k-row, col0

  f32x4 acc[4];
#pragma unroll
  for (int i = 0; i < 4; ++i) acc[i] = (f32x4){0.f, 0.f, 0.f, 0.f};

  // prologue: stage step 0
  {
    int k0 = k0base;
    s16x8 av = *(const s16x8*)(A + (size_t)ar * kTRI + k0 + aks * 8);
    *(s16x8*)&As[0][ar][aks * 8] = av;
    float4 w0 = *(const float4*)(W + (size_t)(k0 + wr) * 1024 + n0 + wc0);
    float4 w1 = *(const float4*)(W + (size_t)(k0 + wr) * 1024 + n0 + wc0 + 4);
    uint p0 = (uint)f2bf(w0.x) | ((uint)f2bf(w0.y) << 16);
    uint p1 = (uint)f2bf(w0.z) | ((uint)f2bf(w0.w) << 16);
    uint p2 = (uint)f2bf(w1.x) | ((uint)f2bf(w1.y) << 16);
    uint p3 = (uint)f2bf(w1.z) | ((uint)f2bf(w1.w) << 16);
    *(uint*)&Ws[0][wr][wc0 + 0] = p0;
    *(uint*)&Ws[0][wr][wc0 + 2] = p1;
    *(uint*)&Ws[0][wr][wc0 + 4] = p2;
    *(uint*)&Ws[0][wr][wc0 + 6] = p3;
  }
  __syncthreads();

  for (int t = 0; t < steps; ++t) {
    int cur = t & 1;
    s16x8 av;
    uint p0, p1, p2, p3;
    if (t + 1 < steps) {
      int k0 = k0base + (t + 1) * 32;
      av = *(const s16x8*)(A + (size_t)ar * kTRI + k0 + aks * 8);
      float4 w0 = *(const float4*)(W + (size_t)(k0 + wr) * 1024 + n0 + wc0);
      float4 w1 = *(const float4*)(W + (size_t)(k0 + wr) * 1024 + n0 + wc0 + 4);
      p0 = (uint)f2bf(w0.x) | ((uint)f2bf(w0.y) << 16);
      p1 = (uint)f2bf(w0.z) | ((uint)f2bf(w0.w) << 16);
      p2 = (uint)f2bf(w1.x) | ((uint)f2bf(w1.y) << 16);
      p3 = (uint)f2bf(w1.z) | ((uint)f2bf(w1.w) << 16);
    }
    // B fragment: lane col = w*16 + l15, 8 consecutive k at kq*8
    s16x8 bf;
    ushort* bp = (ushort*)&bf;
    int bcol = w * 16 + l15;
#pragma unroll
    for (int s = 0; s < 8; ++s) bp[s] = Ws[cur][kq * 8 + s][bcol];
    // A fragments + MFMA
#pragma unroll
    for (int i = 0; i < 4; ++i) {
      s16x8 af = *(const s16x8*)&As[cur][i * 16 + l15][kq * 8];
      acc[i] = __builtin_amdgcn_mfma_f32_16x16x32_bf16(af, bf, acc[i], 0, 0, 0);
    }
    __syncthreads();
    if (t + 1 < steps) {
      int nxt = cur ^ 1;
      *(s16x8*)&As[nxt][ar][aks * 8] = av;
      *(uint*)&Ws[nxt][wr][wc0 + 0] = p0;
      *(uint*)&Ws[nxt][wr][wc0 + 2] = p1;
      *(uint*)&Ws[nxt][wr][wc0 + 4] = p2;
      *(uint*)&Ws[nxt][wr][wc0 + 6] = p3;
    }
    __syncthreads();
  }

  int col = n0 + w * 16 + l15;
#pragma unroll
  for (int i = 0; i < 4; ++i) {
#pragma unroll
    for (int v = 0; v < 4; ++v) {
      int m = i * 16 + kq * 4 + v;
      atomicAdd(&C[(size_t)m * 1024 + col], acc[i][v]);
    }
  }
}

// skinny GEMM, M=64, double-buffered fp32 (small GEMMs)
__global__ __launch_bounds__(256) void k_skinny2(const float* __restrict__ A, int lda,
                                                 const float* __restrict__ Bm, int ldb,
                                                 float* __restrict__ C, int ldc,
                                                 int ktiles) {
  __shared__ float As[2][16][68];
  __shared__ float Bs[2][16][68];
  int n0 = blockIdx.x * 64;
  int kt0 = blockIdx.y * ktiles * 16;
  int tid = threadIdx.x, tx = tid & 15, ty = tid >> 4;
  int ar = tid >> 2, aq = tid & 3;
  int bk = tid >> 4, bq = tid & 15;
  float4 apre = *(const float4*)&A[(size_t)ar * lda + kt0 + aq * 4];
  float4 bpre = *(const float4*)&Bm[(size_t)(kt0 + bk) * ldb + n0 + bq * 4];
  As[0][aq * 4 + 0][ar] = apre.x;
  As[0][aq * 4 + 1][ar] = apre.y;
  As[0][aq * 4 + 2][ar] = apre.z;
  As[0][aq * 4 + 3][ar] = apre.w;
  *(float4*)&Bs[0][bk][bq * 4] = bpre;
  __syncthreads();
  float acc[4][4] = {};
  for (int t = 0; t < ktiles; ++t) {
    int cur = t & 1;
    if (t + 1 < ktiles) {
      int kt = kt0 + (t + 1) * 16;
      apre = *(const float4*)&A[(size_t)ar * lda + kt + aq * 4];
      bpre = *(const float4*)&Bm[(size_t)(kt + bk) * ldb + n0 + bq * 4];
    }
#pragma unroll
    for (int k = 0; k < 16; ++k) {
      float a[4], bb[4];
#pragma unroll
      for (int i = 0; i < 4; ++i) a[i] = As[cur][k][ty * 4 + i];
#pragma unroll
      for (int j = 0; j < 4; ++j) bb[j] = Bs[cur][k][tx * 4 + j];
#pragma unroll
      for (int i = 0; i < 4; ++i)
#pragma unroll
        for (int j = 0; j < 4; ++j) acc[i][j] += a[i] * bb[j];
    }
    __syncthreads();
    if (t + 1 < ktiles) {
      int nxt = cur ^ 1;
      As[nxt][aq * 4 + 0][ar] = apre.x;
      As[nxt][aq * 4 + 1][ar] = apre.y;
      As[nxt][aq * 4 + 2][ar] = apre.z;
      As[nxt][aq * 4 + 3][ar] = apre.w;
      *(float4*)&Bs[nxt][bk][bq * 4] = bpre;
    }
    __syncthreads();
  }
  for (int i = 0; i < 4; ++i)
    for (int j = 0; j < 4; ++j)
      atomicAdd(&C[(size_t)(ty * 4 + i) * ldc + n0 + tx * 4 + j], acc[i][j]);
}

__global__ void k_bngelu(const float* __restrict__ h, const float* __restrict__ gamma,
                         const float* __restrict__ beta, const float* __restrict__ rm,
                         const float* __restrict__ rv, float* __restrict__ o, int cols) {
  int total = kB * cols;
  for (int i = blockIdx.x * blockDim.x + threadIdx.x; i < total;
       i += gridDim.x * blockDim.x) {
    int col = i % cols;
    float x = h[i];
    float xn = (x - rm[col]) / sqrtf(rv[col] + kBNEPS) * gamma[col] + beta[col];
    o[i] = xn * 0.5f * (1.0f + erff(xn * 0.70710678118654752f));
  }
}

__global__ void k_sketch(const float* __restrict__ wc, const int* __restrict__ h1,
                         const int* __restrict__ h2, const int* __restrict__ h3,
                         const float* __restrict__ s1, const float* __restrict__ s2,
                         const float* __restrict__ s3, float* __restrict__ sk) {
  __shared__ float L1[kS];
  __shared__ float L2[kS];
  __shared__ float L3[kS];
  int b = blockIdx.x;
  for (int i = threadIdx.x; i < kS; i += blockDim.x) {
    L1[i] = 0.f;
    L2[i] = 0.f;
    L3[i] = 0.f;
  }
  __syncthreads();
  for (int d = threadIdx.x; d < kD; d += blockDim.x) {
    float w = wc[b * kD + d];
    atomicAdd(&L1[h1[d]], w * s1[d]);
    atomicAdd(&L2[h2[d]], w * s2[d]);
    atomicAdd(&L3[h3[d]], w * s3[d]);
  }
  __syncthreads();
  for (int i = threadIdx.x; i < kS; i += blockDim.x)
    sk[(size_t)b * kS + i] = L1[i] * L2[i] * L3[i];
}

}  // namespace

extern "C" void kernel_launch(void* const* d_in, const int* in_sizes, int n_in,
                              void* d_out, int out_size, void* d_ws, size_t ws_size,
                              hipStream_t stream) {
  (void)in_sizes; (void)n_in; (void)out_size; (void)ws_size;
  const float* tokens = (const float*)d_in[0];
  const float* graph  = (const float*)d_in[1];
  const int*   hash1  = (const int*)d_in[2];
  const int*   hash2  = (const int*)d_in[3];
  const int*   hash3  = (const int*)d_in[4];
  const float* sign1  = (const float*)d_in[5];
  const float* sign2  = (const float*)d_in[6];
  const float* sign3  = (const float*)d_in[7];
  const float* w1_2   = (const float*)d_in[8];
  const float* b1_2   = (const float*)d_in[9];
  const float* gamma2 = (const float*)d_in[10];
  const float* beta2  = (const float*)d_in[11];
  const float* rm2    = (const float*)d_in[12];
  const float* rv2    = (const float*)d_in[13];
  const float* w2_2   = (const float*)d_in[14];
  const float* b2_2   = (const float*)d_in[15];
  const float* w1_3   = (const float*)d_in[16];
  const float* b1_3   = (const float*)d_in[17];
  const float* gamma3 = (const float*)d_in[18];
  const float* beta3  = (const float*)d_in[19];
  const float* rm3    = (const float*)d_in[20];
  const float* rv3    = (const float*)d_in[21];
  const float* w2_3   = (const float*)d_in[22];
  const float* b2_3   = (const float*)d_in[23];
  float* outp = (float*)d_out;

  char* cp = (char*)d_ws;
  auto takeB = [&](size_t bytes) {
    char* q = cp;
    cp += (bytes + 255) & ~(size_t)255;
    return q;
  };
  float* isq  = (float*)takeB((size_t)kB * kN * 4);
  float* rsb  = (float*)takeB((size_t)kB * kN * 4);
  float* trw  = (float*)takeB(256);
  float* tinv = (float*)takeB(256);
  float* tsc  = (float*)takeB(256);
  float* mu   = (float*)takeB((size_t)kB * kD * 4);
  float* wc   = (float*)takeB((size_t)kB * kD * 4);
  float* xc   = (float*)takeB((size_t)kB * kN * kD * 4);
  float* wx   = (float*)takeB((size_t)kB * kN * kD * 4);
  float* M2   = (float*)takeB((size_t)kB * kDD * 4);
  ushort* AT  = (ushort*)takeB((size_t)kB * kDD * 2);
  ushort* Ya  = (ushort*)takeB((size_t)kB * kDD * 2);
  ushort* Yb2 = (ushort*)takeB((size_t)kB * kDD * 2);
  ushort* YTa = (ushort*)takeB((size_t)kB * kDD * 2);
  ushort* YTb = (ushort*)takeB((size_t)kB * kDD * 2);
  ushort* m2v = (ushort*)takeB((size_t)kB * kTRI * 2);
  float* h1b  = (float*)takeB((size_t)kB * 1024 * 4);
  float* h1g  = (float*)takeB((size_t)kB * 1024 * 4);
  float* h3b  = (float*)takeB((size_t)kB * 1024 * 4);
  float* h3g  = (float*)takeB((size_t)kB * 1024 * 4);
  float* sk   = (float*)takeB((size_t)kB * kS * 4);
  // after k_init2, M2 fp32 region is dead -> reuse as two bf16 buffers
  ushort* Tbuf = (ushort*)M2;
  ushort* Vbuf = (ushort*)M2 + (size_t)kB * kDD;

  hipLaunchKernelGGL(k_zero64, dim3(1), dim3(64), 0, stream, trw);
  hipLaunchKernelGGL(k_deg, dim3(kN, kB), dim3(64), 0, stream, graph, isq);
  hipLaunchKernelGGL(k_rowsum, dim3(kN, kB), dim3(64), 0, stream, graph, isq, rsb, trw);
  hipLaunchKernelGGL(k_mu_wc, dim3(kB), dim3(kD), 0, stream, tokens, rsb, trw, mu, wc);
  hipLaunchKernelGGL(k_xc, dim3(8192), dim3(256), 0, stream, tokens, mu, xc);
  hipLaunchKernelGGL(k_wx, dim3(6, 4, kB), dim3(256), 0, stream, graph, isq, xc, wx);
  hipLaunchKernelGGL(k_m2, dim3(6, 6, kB), dim3(256), 0, stream, xc, wx, M2);
  hipLaunchKernelGGL(k_trace, dim3(kB), dim3(64), 0, stream, M2, tinv, tsc);
  hipLaunchKernelGGL(k_init2, dim3(6, 6, kB), dim3(256), 0, stream, M2, tinv, Ya, AT, YTa);

  // Newton-Schulz: per iter  T=Y*Y;  V=1.5I-0.5*T*A;  Ynext=V*Y (+Ynext^T)
  ushort* Yc = Ya;
  ushort* YTc = YTa;
  ushort* Yn = Yb2;
  ushort* YTn = YTb;
  for (int it = 0; it < 4; ++it) {
    hipLaunchKernelGGL(k_mfma384, dim3(3, 3, kB), dim3(256), 0, stream,
                       Yc, YTc, Tbuf, (ushort*)nullptr, 1.f, 0.f);
    hipLaunchKernelGGL(k_mfma384, dim3(3, 3, kB), dim3(256), 0, stream,
                       Tbuf, AT, Vbuf, (ushort*)nullptr, -0.5f, 1.5f);
    hipLaunchKernelGGL(k_mfma384, dim3(3, 3, kB), dim3(256), 0, stream,
                       Vbuf, YTc, Yn, it < 3 ? YTn : (ushort*)nullptr, 1.f, 0.f);
    ushort* t1 = Yc; Yc = Yn; Yn = t1;
    ushort* t2 = YTc; YTc = YTn; YTn = t2;
  }

  hipLaunchKernelGGL(k_trigather_bf, dim3(8192), dim3(256), 0, stream, Yc, tsc, m2v);

  // second path MLP: big GEMM now bf16 MFMA
  hipLaunchKernelGGL(k_bias_init, dim3(256), dim3(256), 0, stream, h1b, b1_2, 1024, 1024);
  hipLaunchKernelGGL(k_skinny_mfma, dim3(16, 110), dim3(256), 0, stream,
                     m2v, w1_2, h1b, 21);  // 110*21*32 = 73920
  hipLaunchKernelGGL(k_bngelu, dim3(256), dim3(256), 0, stream,
                     h1b, gamma2, beta2, rm2, rv2, h1g, 1024);
  hipLaunchKernelGGL(k_bias_init, dim3(128), dim3(256), 0, stream, outp, b2_2, 512, 1024);
  hipLaunchKernelGGL(k_bias_init, dim3(128), dim3(256), 0, stream, outp + 512, b2_3, 512, 1024);
  hipLaunchKernelGGL(k_skinny2, dim3(8, 16), dim3(256), 0, stream,
                     h1g, 1024, w2_2, 512, outp, 1024, 4);  // 16*4*16 = 1024

  // third path (count-sketch MLP)
  hipLaunchKernelGGL(k_sketch, dim3(kB), dim3(256), 0, stream,
                     wc, hash1, hash2, hash3, sign1, sign2, sign3, sk);
  hipLaunchKernelGGL(k_bias_init, dim3(256), dim3(256), 0, stream, h3b, b1_3, 1024, 1024);
  hipLaunchKernelGGL(k_skinny2, dim3(16, 32), dim3(256), 0, stream,
                     sk, kS, w1_3, 1024, h3b, 1024, 8);  // 32*8*16 = 4096
  hipLaunchKernelGGL(k_bngelu, dim3(256), dim3(256), 0, stream,
                     h3b, gamma3, beta3, rm3, rv3, h3g, 1024);
  hipLaunchKernelGGL(k_skinny2, dim3(8, 16), dim3(256), 0, stream,
                     h3g, 1024, w2_3, 512, outp + 512, 1024, 4);
}

// Round 4
// 863.688 us; speedup vs baseline: 2.1897x; 1.0629x over previous
//
#include <hip/hip_runtime.h>
#include <math.h>

namespace {

constexpr int kB   = 64;
constexpr int kN   = 196;
constexpr int kD   = 384;
constexpr int kS   = 4096;
constexpr int kTRI = 73920;
constexpr int kDD  = kD * kD;          // 147456
constexpr int kNP  = 256;              // padded token dim for MFMA moment path
constexpr float kEPS   = 1e-5f;
constexpr float kBNEPS = 1e-5f;

typedef __attribute__((ext_vector_type(8))) short s16x8;
typedef __attribute__((ext_vector_type(4))) float f32x4;
typedef __attribute__((ext_vector_type(4))) ushort u16x4;

__device__ inline float bf2f(ushort h) {
  union { uint u; float f; } v; v.u = (uint)h << 16; return v.f;
}
__device__ inline ushort f2bf(float f) {
  union { float f; uint u; } v; v.f = f;
  uint r = v.u + 0x7FFF + ((v.u >> 16) & 1);
  return (ushort)(r >> 16);
}

// ---------------- small utility kernels ----------------

__global__ void k_deg(const float* __restrict__ g, float* __restrict__ isq,
                      float* __restrict__ trw) {
  int i = blockIdx.x, b = blockIdx.y;
  if (i == 0 && threadIdx.x == 0) trw[b] = 0.f;  // runs before k_rowsum's atomics
  const float* row = g + ((size_t)b * kN + i) * kN;
  float s = 0.f;
  for (int j = threadIdx.x; j < kN; j += 64) s += row[j];
#pragma unroll
  for (int off = 32; off; off >>= 1) s += __shfl_down(s, off);
  if (threadIdx.x == 0) {
    float dg = s < kEPS ? kEPS : s;
    isq[b * kN + i] = 1.0f / sqrtf(dg);
  }
}

__global__ void k_rowsum(const float* __restrict__ g, const float* __restrict__ isq,
                         float* __restrict__ rs, float* __restrict__ trw) {
  int i = blockIdx.x, b = blockIdx.y;
  const float* row = g + ((size_t)b * kN + i) * kN;
  const float* is = isq + b * kN;
  float s = 0.f, diag = 0.f;
  for (int j = threadIdx.x; j < kN; j += 64) {
    float gv = row[j];
    s += gv * is[j];
    if (j == i) diag = gv;
  }
#pragma unroll
  for (int off = 32; off; off >>= 1) {
    s += __shfl_down(s, off);
    diag += __shfl_down(diag, off);
  }
  if (threadIdx.x == 0) {
    float isi = is[i];
    rs[b * kN + i] = isi * s;
    atomicAdd(&trw[b], diag * isi * isi);
  }
}

__global__ void k_mu_wc(const float* __restrict__ tokens, const float* __restrict__ rs,
                        const float* __restrict__ trw, float* __restrict__ mu,
                        float* __restrict__ wc) {
  int b = blockIdx.x, d = threadIdx.x;  // blockDim = 384
  const float* r = rs + b * kN;
  const float* tb = tokens + (size_t)b * kN * kD + d;
  float T = 0.f, S = 0.f;
  for (int n = 0; n < kN; ++n) {
    float rv = r[n];
    T += tb[(size_t)n * kD] * rv;
    S += rv;
  }
  float invtr = 1.0f / (trw[b] + kEPS);
  float m = T * invtr;
  mu[b * kD + d] = m;
  wc[b * kD + d] = m * (1.0f - S * invtr);
}

// W_bf[b][n][m] = g[n,m]*is[n]*is[m] bf16, zero-padded to 256x256
__global__ __launch_bounds__(256) void k_prep_w(const float* __restrict__ g,
                                                const float* __restrict__ isq,
                                                ushort* __restrict__ wbf) {
  int b = blockIdx.y;
  int row0 = blockIdx.x * 64;
  const float* gb = g + (size_t)b * kN * kN;
  const float* is = isq + b * kN;
  ushort* wb = wbf + (size_t)b * kNP * kNP;
  for (int n = row0; n < row0 + 64; ++n) {
    float isn = (n < kN) ? is[n] : 0.f;
    int m = threadIdx.x;
    float v = 0.f;
    if (n < kN && m < kN) v = gb[(size_t)n * kN + m] * isn * is[m];
    wb[(size_t)n * kNP + m] = f2bf(v);
  }
}

// XcT[b][d][n] = bf16(tokens[b,n,d] - mu[b,d]), zero-padded n -> 256
__global__ __launch_bounds__(256) void k_prep_xct(const float* __restrict__ tokens,
                                                  const float* __restrict__ mu,
                                                  ushort* __restrict__ xct) {
  __shared__ ushort Ls[64][72];
  int b = blockIdx.z;
  int n0 = blockIdx.x * 64, d0 = blockIdx.y * 64;
  int tid = threadIdx.x;
  const float* tb = tokens + (size_t)b * kN * kD;
  const float* mb = mu + b * kD;
#pragma unroll
  for (int h = 0; h < 4; ++h) {
    int id = tid + 256 * h;
    int r = id >> 4, c4 = id & 15;
    bool ok = (n0 + r) < kN;
    float4 mv = *(const float4*)(mb + d0 + c4 * 4);
    float4 t = make_float4(0.f, 0.f, 0.f, 0.f);
    if (ok) t = *(const float4*)(tb + (size_t)(n0 + r) * kD + d0 + c4 * 4);
    Ls[r][c4 * 4 + 0] = f2bf(ok ? t.x - mv.x : 0.f);
    Ls[r][c4 * 4 + 1] = f2bf(ok ? t.y - mv.y : 0.f);
    Ls[r][c4 * 4 + 2] = f2bf(ok ? t.z - mv.z : 0.f);
    Ls[r][c4 * 4 + 3] = f2bf(ok ? t.w - mv.w : 0.f);
  }
  __syncthreads();
#pragma unroll
  for (int h = 0; h < 2; ++h) {
    int id = tid + 256 * h;
    int dr = id >> 3, c8 = id & 7;
    ushort v[8];
#pragma unroll
    for (int s = 0; s < 8; ++s) v[s] = Ls[c8 * 8 + s][dr];
    *(s16x8*)(xct + (size_t)b * kD * kNP + (size_t)(d0 + dr) * kNP + n0 + c8 * 8) =
        *(s16x8*)v;
  }
}

// ---- generalized batched bf16 MFMA GEMM (A row-major, Bt = B^T row-major) ----
// tile 128x128, BK=32; C fp32 or bf16 per flag.
__global__ __launch_bounds__(256) void k_gemm_bf(const ushort* __restrict__ A, int lda, int sa,
                                                 const ushort* __restrict__ Bt, int ldb, int sb,
                                                 void* __restrict__ Cv, int ldc, int sc,
                                                 int ksteps, int f32out) {
  __shared__ ushort lds[16384];
  int b = blockIdx.z;
  int m0 = blockIdx.y * 128, n0 = blockIdx.x * 128;
  int tid = threadIdx.x;
  int lane = tid & 63, wid = tid >> 6;
  int wr = wid >> 1, wc = wid & 1;
  int l15 = lane & 15, kq = lane >> 4;
  const ushort* Ag = A + (size_t)b * sa;
  const ushort* Bg = Bt + (size_t)b * sb;
  int rs = tid >> 2, kb = tid & 3;

  f32x4 acc[4][4];
#pragma unroll
  for (int i = 0; i < 4; ++i)
#pragma unroll
    for (int j = 0; j < 4; ++j) acc[i][j] = (f32x4){0.f, 0.f, 0.f, 0.f};

  auto st_tile = [&](ushort* base, int r, float4 v) {
    *(float4*)((char*)base + kb * 2048 + ((r ^ (kb << 2)) << 4)) = v;
  };

  float4 sa0 = *(const float4*)(Ag + (size_t)(m0 + rs) * lda + kb * 8);
  float4 sa1 = *(const float4*)(Ag + (size_t)(m0 + rs + 64) * lda + kb * 8);
  float4 sb0 = *(const float4*)(Bg + (size_t)(n0 + rs) * ldb + kb * 8);
  float4 sb1 = *(const float4*)(Bg + (size_t)(n0 + rs + 64) * ldb + kb * 8);
  st_tile(lds, rs, sa0);
  st_tile(lds, rs + 64, sa1);
  st_tile(lds + 4096, rs, sb0);
  st_tile(lds + 4096, rs + 64, sb1);
  __syncthreads();

  for (int kt = 0; kt < ksteps; ++kt) {
    ushort* Lc = lds + (kt & 1) * 8192;
    if (kt + 1 < ksteps) {
      int kk = (kt + 1) * 32 + kb * 8;
      sa0 = *(const float4*)(Ag + (size_t)(m0 + rs) * lda + kk);
      sa1 = *(const float4*)(Ag + (size_t)(m0 + rs + 64) * lda + kk);
      sb0 = *(const float4*)(Bg + (size_t)(n0 + rs) * ldb + kk);
      sb1 = *(const float4*)(Bg + (size_t)(n0 + rs + 64) * ldb + kk);
    }
    s16x8 af[4], bfv[4];
#pragma unroll
    for (int i = 0; i < 4; ++i)
      af[i] = *(const s16x8*)((const char*)Lc + kq * 2048 +
                              (((wr * 64 + i * 16 + l15) ^ (kq << 2)) << 4));
#pragma unroll
    for (int j = 0; j < 4; ++j)
      bfv[j] = *(const s16x8*)((const char*)(Lc + 4096) + kq * 2048 +
                               (((wc * 64 + j * 16 + l15) ^ (kq << 2)) << 4));
#pragma unroll
    for (int i = 0; i < 4; ++i)
#pragma unroll
      for (int j = 0; j < 4; ++j)
        acc[i][j] = __builtin_amdgcn_mfma_f32_16x16x32_bf16(af[i], bfv[j], acc[i][j], 0, 0, 0);
    __syncthreads();
    if (kt + 1 < ksteps) {
      ushort* Ln = lds + ((kt + 1) & 1) * 8192;
      st_tile(Ln, rs, sa0);
      st_tile(Ln, rs + 64, sa1);
      st_tile(Ln + 4096, rs, sb0);
      st_tile(Ln + 4096, rs + 64, sb1);
    }
    __syncthreads();
  }

  if (f32out) {
    float* Cb = (float*)Cv + (size_t)b * sc;
#pragma unroll
    for (int i = 0; i < 4; ++i)
#pragma unroll
      for (int j = 0; j < 4; ++j) {
        int row0 = wr * 64 + i * 16 + kq * 4;
        int col = wc * 64 + j * 16 + l15;
#pragma unroll
        for (int v = 0; v < 4; ++v)
          Cb[(size_t)(m0 + row0 + v) * ldc + n0 + col] = acc[i][j][v];
      }
  } else {
    ushort* Cb = (ushort*)Cv + (size_t)b * sc;
#pragma unroll
    for (int i = 0; i < 4; ++i)
#pragma unroll
      for (int j = 0; j < 4; ++j) {
        int row0 = wr * 64 + i * 16 + kq * 4;
        int col = wc * 64 + j * 16 + l15;
#pragma unroll
        for (int v = 0; v < 4; ++v) {
          int row = row0 + v;
          int byt = row * 256 + ((col * 2) ^ ((row & 15) << 4));
          *(ushort*)((char*)lds + byt) = f2bf(acc[i][j][v]);
        }
      }
    __syncthreads();
#pragma unroll
    for (int h = 0; h < 8; ++h) {
      int id = tid + 256 * h;
      int row = id >> 4, c16 = id & 15;
      int byt = row * 256 + ((c16 * 16) ^ ((row & 15) << 4));
      s16x8 vv = *(const s16x8*)((char*)lds + byt);
      *(s16x8*)(Cb + (size_t)(m0 + row) * ldc + n0 + c16 * 8) = vv;
    }
  }
}

__global__ void k_trace(const float* __restrict__ m2, float* __restrict__ tinv,
                        float* __restrict__ tsc) {
  int b = blockIdx.x;
  const float* mb = m2 + (size_t)b * kDD;
  float s = 0.f;
  for (int d = threadIdx.x; d < kD; d += 64) s += mb[(size_t)d * kD + d];
#pragma unroll
  for (int off = 32; off; off >>= 1) s += __shfl_down(s, off);
  if (threadIdx.x == 0) {
    float t = s + kEPS;
    tinv[b] = 1.0f / t;
    tsc[b] = 1.0f / sqrtf(t);
  }
}

// M2 fp32 -> Y1 (bf16 row-major), AT (bf16, =A^T), Y1T (bf16, =Y1^T)
__global__ __launch_bounds__(256) void k_init2(const float* __restrict__ M2,
                                               const float* __restrict__ tinv,
                                               ushort* __restrict__ Y1,
                                               ushort* __restrict__ AT,
                                               ushort* __restrict__ Y1T) {
  __shared__ ushort Ls[64][72];
  int b = blockIdx.z;
  int r0 = blockIdx.y * 64, c0 = blockIdx.x * 64;
  int tid = threadIdx.x;
  float ti = tinv[b];
  const float* Mb = M2 + (size_t)b * kDD;
  ushort* Yb = Y1 + (size_t)b * kDD;
#pragma unroll
  for (int h = 0; h < 4; ++h) {
    int id = tid + 256 * h;
    int r = id >> 4, c4 = id & 15;
    float4 m = *(const float4*)(Mb + (size_t)(r0 + r) * kD + c0 + c4 * 4);
    const float* mp = (const float*)&m;
    u16x4 y;
#pragma unroll
    for (int e = 0; e < 4; ++e) {
      float av = mp[e] * ti;
      Ls[r][c4 * 4 + e] = f2bf(av);
      float yv = ((r0 + r) == (c0 + c4 * 4 + e) ? 1.5f : 0.f) - 0.5f * av;
      y[e] = f2bf(yv);
    }
    *(u16x4*)(Yb + (size_t)(r0 + r) * kD + c0 + c4 * 4) = y;
  }
  __syncthreads();
  int oc = tid >> 2, och = tid & 3;
  ushort atv[16], ytv[16];
#pragma unroll
  for (int s = 0; s < 16; ++s) {
    int r = och * 16 + s;
    ushort a = Ls[r][oc];
    atv[s] = a;
    float av = bf2f(a);
    float yv = ((c0 + oc) == (r0 + r) ? 1.5f : 0.f) - 0.5f * av;
    ytv[s] = f2bf(yv);
  }
  size_t obase = (size_t)b * kDD + (size_t)(c0 + oc) * kD + r0 + och * 16;
  *(s16x8*)(AT + obase) = *(s16x8*)&atv[0];
  *(s16x8*)(AT + obase + 8) = *(s16x8*)&atv[8];
  *(s16x8*)(Y1T + obase) = *(s16x8*)&ytv[0];
  *(s16x8*)(Y1T + obase + 8) = *(s16x8*)&ytv[8];
}

// ---------------- batched bf16 MFMA GEMM 384x384x384 (NS iterations) ----------------

__device__ inline float4 ld_g4(const ushort* g, int row, int col) {
  return *(const float4*)(g + (size_t)row * kD + col);
}
__device__ inline void st_tile384(ushort* base, int r, int kb, float4 v) {
  *(float4*)((char*)base + kb * 2048 + ((r ^ (kb << 2)) << 4)) = v;
}
__device__ inline s16x8 ld_frag384(const ushort* base, int row, int kq) {
  return *(const s16x8*)((const char*)base + kq * 2048 + ((row ^ (kq << 2)) << 4));
}

__global__ __launch_bounds__(256) void k_mfma384(const ushort* __restrict__ A,
                                                 const ushort* __restrict__ Bt,
                                                 ushort* __restrict__ C,
                                                 ushort* __restrict__ Ct,
                                                 float amul, float dadd) {
  __shared__ ushort lds[16384];  // 32KB: 2 x (A 4096 + B 4096)
  int b = blockIdx.z;
  size_t boff = (size_t)b * kDD;
  int m0 = blockIdx.y * 128, n0 = blockIdx.x * 128;
  int tid = threadIdx.x;
  int lane = tid & 63, wid = tid >> 6;
  int wr = wid >> 1, wc = wid & 1;
  int l15 = lane & 15, kq = lane >> 4;
  const ushort* Ag = A + boff;
  const ushort* Bg = Bt + boff;
  int rs = tid >> 2, kb = tid & 3;

  f32x4 acc[4][4];
#pragma unroll
  for (int i = 0; i < 4; ++i)
#pragma unroll
    for (int j = 0; j < 4; ++j) acc[i][j] = (f32x4){0.f, 0.f, 0.f, 0.f};

  float4 sa0 = ld_g4(Ag, m0 + rs, kb * 8);
  float4 sa1 = ld_g4(Ag, m0 + rs + 64, kb * 8);
  float4 sb0 = ld_g4(Bg, n0 + rs, kb * 8);
  float4 sb1 = ld_g4(Bg, n0 + rs + 64, kb * 8);
  st_tile384(lds, rs, kb, sa0);
  st_tile384(lds, rs + 64, kb, sa1);
  st_tile384(lds + 4096, rs, kb, sb0);
  st_tile384(lds + 4096, rs + 64, kb, sb1);
  __syncthreads();

  for (int kt = 0; kt < 12; ++kt) {
    ushort* Lc = lds + (kt & 1) * 8192;
    if (kt < 11) {
      int kk = (kt + 1) * 32 + kb * 8;
      sa0 = ld_g4(Ag, m0 + rs, kk);
      sa1 = ld_g4(Ag, m0 + rs + 64, kk);
      sb0 = ld_g4(Bg, n0 + rs, kk);
      sb1 = ld_g4(Bg, n0 + rs + 64, kk);
    }
    s16x8 af[4], bfv[4];
#pragma unroll
    for (int i = 0; i < 4; ++i) af[i] = ld_frag384(Lc, wr * 64 + i * 16 + l15, kq);
#pragma unroll
    for (int j = 0; j < 4; ++j) bfv[j] = ld_frag384(Lc + 4096, wc * 64 + j * 16 + l15, kq);
#pragma unroll
    for (int i = 0; i < 4; ++i)
#pragma unroll
      for (int j = 0; j < 4; ++j)
        acc[i][j] = __builtin_amdgcn_mfma_f32_16x16x32_bf16(af[i], bfv[j], acc[i][j], 0, 0, 0);
    __syncthreads();
    if (kt < 11) {
      ushort* Ln = lds + ((kt + 1) & 1) * 8192;
      st_tile384(Ln, rs, kb, sa0);
      st_tile384(Ln, rs + 64, kb, sa1);
      st_tile384(Ln + 4096, rs, kb, sb0);
      st_tile384(Ln + 4096, rs + 64, kb, sb1);
    }
    __syncthreads();
  }

  // ---- epilogue: C via LDS (coalesced), optional Ct ----
#pragma unroll
  for (int i = 0; i < 4; ++i)
#pragma unroll
    for (int j = 0; j < 4; ++j) {
      int row0 = wr * 64 + i * 16 + kq * 4;
      int col = wc * 64 + j * 16 + l15;
#pragma unroll
      for (int v = 0; v < 4; ++v) {
        int row = row0 + v;
        float f = amul * acc[i][j][v] + ((m0 + row) == (n0 + col) ? dadd : 0.f);
        int byt = row * 256 + ((col * 2) ^ ((row & 15) << 4));
        *(ushort*)((char*)lds + byt) = f2bf(f);
      }
    }
  __syncthreads();
#pragma unroll
  for (int h = 0; h < 8; ++h) {
    int id = tid + 256 * h;
    int row = id >> 4, c16 = id & 15;
    int byt = row * 256 + ((c16 * 16) ^ ((row & 15) << 4));
    s16x8 vv = *(const s16x8*)((char*)lds + byt);
    *(s16x8*)(C + boff + (size_t)(m0 + row) * kD + n0 + c16 * 8) = vv;
  }
  if (Ct) {
    __syncthreads();
#pragma unroll
    for (int i = 0; i < 4; ++i)
#pragma unroll
      for (int j = 0; j < 4; ++j) {
        int row0 = wr * 64 + i * 16 + kq * 4;
        int col = wc * 64 + j * 16 + l15;
        u16x4 pk;
#pragma unroll
        for (int v = 0; v < 4; ++v) {
          float f = amul * acc[i][j][v] + ((m0 + row0 + v) == (n0 + col) ? dadd : 0.f);
          pk[v] = f2bf(f);
        }
        int byt = col * 256 + ((row0 * 2) ^ ((col & 15) << 4));
        *(u16x4*)((char*)lds + byt) = pk;
      }
    __syncthreads();
#pragma unroll
    for (int h = 0; h < 8; ++h) {
      int id = tid + 256 * h;
      int p = id >> 4, c16 = id & 15;
      int byt = p * 256 + ((c16 * 16) ^ ((p & 15) << 4));
      s16x8 vv = *(const s16x8*)((char*)lds + byt);
      *(s16x8*)(Ct + boff + (size_t)(n0 + p) * kD + m0 + c16 * 8) = vv;
    }
  }
}

// trigather: emits bf16 m2v (A-operand of the big streaming GEMM)
__global__ void k_trigather_bf(const ushort* __restrict__ y, const float* __restrict__ tsc,
                               ushort* __restrict__ m2v) {
  size_t total = (size_t)kB * kTRI;
  for (size_t i = (size_t)blockIdx.x * blockDim.x + threadIdx.x; i < total;
       i += (size_t)gridDim.x * blockDim.x) {
    int b = (int)(i / kTRI);
    int t = (int)(i % kTRI);
    float disc = 591361.0f - 8.0f * (float)t;  // (2D+1)^2 - 8t
    int r = (int)((769.0f - sqrtf(disc)) * 0.5f);
    if (r > kD - 1) r = kD - 1;
    if (r < 0) r = 0;
    while (r > 0 && (r * (769 - r)) / 2 > t) --r;
    while (r < kD - 1 && ((r + 1) * (769 - (r + 1))) / 2 <= t) ++r;
    int base = (r * (769 - r)) / 2;
    int c = r + (t - base);
    m2v[i] = f2bf(bf2f(y[(size_t)b * kDD + (size_t)r * kD + c]) * tsc[b]);
  }
}

__global__ void k_bias_init(float* __restrict__ dst, const float* __restrict__ bias,
                            int cols, int ldo) {
  int total = kB * cols;
  for (int i = blockIdx.x * blockDim.x + threadIdx.x; i < total;
       i += gridDim.x * blockDim.x) {
    int row = i / cols, col = i % cols;
    dst[(size_t)row * ldo + col] = bias[col];
  }
}

// ---- big skinny GEMM, LDS-free streaming MFMA:
// C[64][1024] += A_bf16[64][73920] @ W_fp32[73920][1024]
// grid (16, 110); 4 waves; wave owns 16 cols; per-lane B-fragment loaded
// directly from global (8 dwords, 64B segments across the 16-lane group).
__global__ __launch_bounds__(256) void k_skinny_stream(const ushort* __restrict__ A,
                                                       const float* __restrict__ W,
                                                       float* __restrict__ C,
                                                       int steps) {
  int tid = threadIdx.x;
  int lane = tid & 63, w = tid >> 6;
  int l15 = lane & 15, kq = lane >> 4;
  int n0 = blockIdx.x * 64;
  int col = n0 + w * 16 + l15;
  int k0 = blockIdx.y * steps * 32;

  f32x4 acc[4];
#pragma unroll
  for (int i = 0; i < 4; ++i) acc[i] = (f32x4){0.f, 0.f, 0.f, 0.f};

  float wv[8];
  {
    int kk = k0 + kq * 8;
#pragma unroll
    for (int s = 0; s < 8; ++s) wv[s] = W[(size_t)(kk + s) * 1024 + col];
  }
  for (int t = 0; t < steps; ++t) {
    float nv[8];
    if (t + 1 < steps) {
      int kk = k0 + (t + 1) * 32 + kq * 8;
#pragma unroll
      for (int s = 0; s < 8; ++s) nv[s] = W[(size_t)(kk + s) * 1024 + col];
    } else {
#pragma unroll
      for (int s = 0; s < 8; ++s) nv[s] = 0.f;
    }
    s16x8 bf;
    ushort* bp = (ushort*)&bf;
#pragma unroll
    for (int s = 0; s < 8; ++s) bp[s] = f2bf(wv[s]);
    int kk = k0 + t * 32 + kq * 8;
#pragma unroll
    for (int i = 0; i < 4; ++i) {
      s16x8 af = *(const s16x8*)(A + (size_t)(i * 16 + l15) * kTRI + kk);
      acc[i] = __builtin_amdgcn_mfma_f32_16x16x32_bf16(af, bf, acc[i], 0, 0, 0);
    }
#pragma unroll
    for (int s = 0; s < 8; ++s) wv[s] = nv[s];
  }

#pragma unroll
  for (int i = 0; i < 4; ++i) {
#pragma unroll
    for (int v = 0; v < 4; ++v) {
      int m = i * 16 + kq * 4 + v;
      atomicAdd(&C[(size_t)m * 1024 + col], acc[i][v]);
    }
  }
}

// skinny GEMM, M=64, double-buffered fp32 (small GEMMs)
__global__ __launch_bounds__(256) void k_skinny2(const float* __restrict__ A, int lda,
                                                 const float* __restrict__ Bm, int ldb,
                                                 float* __restrict__ C, int ldc,
                                                 int ktiles) {
  __shared__ float As[2][16][68];
  __shared__ float Bs[2][16][68];
  int n0 = blockIdx.x * 64;
  int kt0 = blockIdx.y * ktiles * 16;
  int tid = threadIdx.x, tx = tid & 15, ty = tid >> 4;
  int ar = tid >> 2, aq = tid & 3;
  int bk = tid >> 4, bq = tid & 15;
  float4 apre = *(const float4*)&A[(size_t)ar * lda + kt0 + aq * 4];
  float4 bpre = *(const float4*)&Bm[(size_t)(kt0 + bk) * ldb + n0 + bq * 4];
  As[0][aq * 4 + 0][ar] = apre.x;
  As[0][aq * 4 + 1][ar] = apre.y;
  As[0][aq * 4 + 2][ar] = apre.z;
  As[0][aq * 4 + 3][ar] = apre.w;
  *(float4*)&Bs[0][bk][bq * 4] = bpre;
  __syncthreads();
  float acc[4][4] = {};
  for (int t = 0; t < ktiles; ++t) {
    int cur = t & 1;
    if (t + 1 < ktiles) {
      int kt = kt0 + (t + 1) * 16;
      apre = *(const float4*)&A[(size_t)ar * lda + kt + aq * 4];
      bpre = *(const float4*)&Bm[(size_t)(kt + bk) * ldb + n0 + bq * 4];
    }
#pragma unroll
    for (int k = 0; k < 16; ++k) {
      float a[4], bb[4];
#pragma unroll
      for (int i = 0; i < 4; ++i) a[i] = As[cur][k][ty * 4 + i];
#pragma unroll
      for (int j = 0; j < 4; ++j) bb[j] = Bs[cur][k][tx * 4 + j];
#pragma unroll
      for (int i = 0; i < 4; ++i)
#pragma unroll
        for (int j = 0; j < 4; ++j) acc[i][j] += a[i] * bb[j];
    }
    __syncthreads();
    if (t + 1 < ktiles) {
      int nxt = cur ^ 1;
      As[nxt][aq * 4 + 0][ar] = apre.x;
      As[nxt][aq * 4 + 1][ar] = apre.y;
      As[nxt][aq * 4 + 2][ar] = apre.z;
      As[nxt][aq * 4 + 3][ar] = apre.w;
      *(float4*)&Bs[nxt][bk][bq * 4] = bpre;
    }
    __syncthreads();
  }
  for (int i = 0; i < 4; ++i)
    for (int j = 0; j < 4; ++j)
      atomicAdd(&C[(size_t)(ty * 4 + i) * ldc + n0 + tx * 4 + j], acc[i][j]);
}

__global__ void k_bngelu(const float* __restrict__ h, const float* __restrict__ gamma,
                         const float* __restrict__ beta, const float* __restrict__ rm,
                         const float* __restrict__ rv, float* __restrict__ o, int cols) {
  int total = kB * cols;
  for (int i = blockIdx.x * blockDim.x + threadIdx.x; i < total;
       i += gridDim.x * blockDim.x) {
    int col = i % cols;
    float x = h[i];
    float xn = (x - rm[col]) / sqrtf(rv[col] + kBNEPS) * gamma[col] + beta[col];
    o[i] = xn * 0.5f * (1.0f + erff(xn * 0.70710678118654752f));
  }
}

__global__ void k_sketch(const float* __restrict__ wc, const int* __restrict__ h1,
                         const int* __restrict__ h2, const int* __restrict__ h3,
                         const float* __restrict__ s1, const float* __restrict__ s2,
                         const float* __restrict__ s3, float* __restrict__ sk) {
  __shared__ float L1[kS];
  __shared__ float L2[kS];
  __shared__ float L3[kS];
  int b = blockIdx.x;
  for (int i = threadIdx.x; i < kS; i += blockDim.x) {
    L1[i] = 0.f;
    L2[i] = 0.f;
    L3[i] = 0.f;
  }
  __syncthreads();
  for (int d = threadIdx.x; d < kD; d += blockDim.x) {
    float w = wc[b * kD + d];
    atomicAdd(&L1[h1[d]], w * s1[d]);
    atomicAdd(&L2[h2[d]], w * s2[d]);
    atomicAdd(&L3[h3[d]], w * s3[d]);
  }
  __syncthreads();
  for (int i = threadIdx.x; i < kS; i += blockDim.x)
    sk[(size_t)b * kS + i] = L1[i] * L2[i] * L3[i];
}

}  // namespace

extern "C" void kernel_launch(void* const* d_in, const int* in_sizes, int n_in,
                              void* d_out, int out_size, void* d_ws, size_t ws_size,
                              hipStream_t stream) {
  (void)in_sizes; (void)n_in; (void)out_size; (void)ws_size;
  const float* tokens = (const float*)d_in[0];
  const float* graph  = (const float*)d_in[1];
  const int*   hash1  = (const int*)d_in[2];
  const int*   hash2  = (const int*)d_in[3];
  const int*   hash3  = (const int*)d_in[4];
  const float* sign1  = (const float*)d_in[5];
  const float* sign2  = (const float*)d_in[6];
  const float* sign3  = (const float*)d_in[7];
  const float* w1_2   = (const float*)d_in[8];
  const float* b1_2   = (const float*)d_in[9];
  const float* gamma2 = (const float*)d_in[10];
  const float* beta2  = (const float*)d_in[11];
  const float* rm2    = (const float*)d_in[12];
  const float* rv2    = (const float*)d_in[13];
  const float* w2_2   = (const float*)d_in[14];
  const float* b2_2   = (const float*)d_in[15];
  const float* w1_3   = (const float*)d_in[16];
  const float* b1_3   = (const float*)d_in[17];
  const float* gamma3 = (const float*)d_in[18];
  const float* beta3  = (const float*)d_in[19];
  const float* rm3    = (const float*)d_in[20];
  const float* rv3    = (const float*)d_in[21];
  const float* w2_3   = (const float*)d_in[22];
  const float* b2_3   = (const float*)d_in[23];
  float* outp = (float*)d_out;

  char* cp = (char*)d_ws;
  auto takeB = [&](size_t bytes) {
    char* q = cp;
    cp += (bytes + 255) & ~(size_t)255;
    return q;
  };
  float* isq  = (float*)takeB((size_t)kB * kN * 4);
  float* rsb  = (float*)takeB((size_t)kB * kN * 4);
  float* trw  = (float*)takeB(256);
  float* tinv = (float*)takeB(256);
  float* tsc  = (float*)takeB(256);
  float* mu   = (float*)takeB((size_t)kB * kD * 4);
  float* wc   = (float*)takeB((size_t)kB * kD * 4);
  ushort* xct = (ushort*)takeB((size_t)kB * kD * kNP * 2);
  ushort* wbf = (ushort*)takeB((size_t)kB * kNP * kNP * 2);
  ushort* wxt = (ushort*)takeB((size_t)kB * kD * kNP * 2);
  float* M2   = (float*)takeB((size_t)kB * kDD * 4);
  ushort* AT  = (ushort*)takeB((size_t)kB * kDD * 2);
  ushort* Ya  = (ushort*)takeB((size_t)kB * kDD * 2);
  ushort* Yb2 = (ushort*)takeB((size_t)kB * kDD * 2);
  ushort* YTa = (ushort*)takeB((size_t)kB * kDD * 2);
  ushort* YTb = (ushort*)takeB((size_t)kB * kDD * 2);
  ushort* m2v = (ushort*)takeB((size_t)kB * kTRI * 2);
  float* h1b  = (float*)takeB((size_t)kB * 1024 * 4);
  float* h1g  = (float*)takeB((size_t)kB * 1024 * 4);
  float* h3b  = (float*)takeB((size_t)kB * 1024 * 4);
  float* h3g  = (float*)takeB((size_t)kB * 1024 * 4);
  float* sk   = (float*)takeB((size_t)kB * kS * 4);
  // after k_init2, M2 fp32 region is dead -> reuse as two bf16 buffers
  ushort* Tbuf = (ushort*)M2;
  ushort* Vbuf = (ushort*)M2 + (size_t)kB * kDD;

  // graph stats
  hipLaunchKernelGGL(k_deg, dim3(kN, kB), dim3(64), 0, stream, graph, isq, trw);
  hipLaunchKernelGGL(k_rowsum, dim3(kN, kB), dim3(64), 0, stream, graph, isq, rsb, trw);
  hipLaunchKernelGGL(k_mu_wc, dim3(kB), dim3(kD), 0, stream, tokens, rsb, trw, mu, wc);

  // moment path via MFMA: XcT, W_bf, then WXT = XcT @ W^T, M2 = XcT @ WX
  hipLaunchKernelGGL(k_prep_w, dim3(4, kB), dim3(256), 0, stream, graph, isq, wbf);
  hipLaunchKernelGGL(k_prep_xct, dim3(4, 6, kB), dim3(256), 0, stream, tokens, mu, xct);
  hipLaunchKernelGGL(k_gemm_bf, dim3(2, 3, kB), dim3(256), 0, stream,
                     xct, kNP, kD * kNP, wbf, kNP, kNP * kNP,
                     (void*)wxt, kNP, kD * kNP, 8, 0);
  hipLaunchKernelGGL(k_gemm_bf, dim3(3, 3, kB), dim3(256), 0, stream,
                     xct, kNP, kD * kNP, wxt, kNP, kD * kNP,
                     (void*)M2, kD, kDD, 8, 1);
  hipLaunchKernelGGL(k_trace, dim3(kB), dim3(64), 0, stream, M2, tinv, tsc);
  hipLaunchKernelGGL(k_init2, dim3(6, 6, kB), dim3(256), 0, stream, M2, tinv, Ya, AT, YTa);

  // Newton-Schulz: per iter  T=Y*Y;  V=1.5I-0.5*T*A;  Ynext=V*Y (+Ynext^T)
  ushort* Yc = Ya;
  ushort* YTc = YTa;
  ushort* Yn = Yb2;
  ushort* YTn = YTb;
  for (int it = 0; it < 4; ++it) {
    hipLaunchKernelGGL(k_mfma384, dim3(3, 3, kB), dim3(256), 0, stream,
                       Yc, YTc, Tbuf, (ushort*)nullptr, 1.f, 0.f);
    hipLaunchKernelGGL(k_mfma384, dim3(3, 3, kB), dim3(256), 0, stream,
                       Tbuf, AT, Vbuf, (ushort*)nullptr, -0.5f, 1.5f);
    hipLaunchKernelGGL(k_mfma384, dim3(3, 3, kB), dim3(256), 0, stream,
                       Vbuf, YTc, Yn, it < 3 ? YTn : (ushort*)nullptr, 1.f, 0.f);
    ushort* t1 = Yc; Yc = Yn; Yn = t1;
    ushort* t2 = YTc; YTc = YTn; YTn = t2;
  }

  hipLaunchKernelGGL(k_trigather_bf, dim3(8192), dim3(256), 0, stream, Yc, tsc, m2v);

  // second path MLP: big GEMM as LDS-free streaming MFMA
  hipLaunchKernelGGL(k_bias_init, dim3(256), dim3(256), 0, stream, h1b, b1_2, 1024, 1024);
  hipLaunchKernelGGL(k_skinny_stream, dim3(16, 110), dim3(256), 0, stream,
                     m2v, w1_2, h1b, 21);  // 110*21*32 = 73920
  hipLaunchKernelGGL(k_bngelu, dim3(256), dim3(256), 0, stream,
                     h1b, gamma2, beta2, rm2, rv2, h1g, 1024);
  hipLaunchKernelGGL(k_bias_init, dim3(128), dim3(256), 0, stream, outp, b2_2, 512, 1024);
  hipLaunchKernelGGL(k_bias_init, dim3(128), dim3(256), 0, stream, outp + 512, b2_3, 512, 1024);
  hipLaunchKernelGGL(k_skinny2, dim3(8, 16), dim3(256), 0, stream,
                     h1g, 1024, w2_2, 512, outp, 1024, 4);  // 16*4*16 = 1024

  // third path (count-sketch MLP)
  hipLaunchKernelGGL(k_sketch, dim3(kB), dim3(256), 0, stream,
                     wc, hash1, hash2, hash3, sign1, sign2, sign3, sk);
  hipLaunchKernelGGL(k_bias_init, dim3(256), dim3(256), 0, stream, h3b, b1_3, 1024, 1024);
  hipLaunchKernelGGL(k_skinny2, dim3(16, 32), dim3(256), 0, stream,
                     sk, kS, w1_3, 1024, h3b, 1024, 8);  // 32*8*16 = 4096
  hipLaunchKernelGGL(k_bngelu, dim3(256), dim3(256), 0, stream,
                     h3b, gamma3, beta3, rm3, rv3, h3g, 1024);
  hipLaunchKernelGGL(k_skinny2, dim3(8, 16), dim3(256), 0, stream,
                     h3g, 1024, w2_3, 512, outp + 512, 1024, 4);
}

// Round 5
// 816.487 us; speedup vs baseline: 2.3163x; 1.0578x over previous
//
#include <hip/hip_runtime.h>
#include <math.h>

namespace {

constexpr int kB   = 64;
constexpr int kN   = 196;
constexpr int kD   = 384;
constexpr int kS   = 4096;
constexpr int kTRI = 73920;
constexpr int kDD  = kD * kD;          // 147456
constexpr int kNP  = 256;              // padded token dim for MFMA moment path
constexpr float kEPS   = 1e-5f;
constexpr float kBNEPS = 1e-5f;

typedef __attribute__((ext_vector_type(8))) short s16x8;
typedef __attribute__((ext_vector_type(4))) float f32x4;
typedef __attribute__((ext_vector_type(4))) ushort u16x4;

__device__ inline float bf2f(ushort h) {
  union { uint u; float f; } v; v.u = (uint)h << 16; return v.f;
}
__device__ inline ushort f2bf(float f) {
  union { float f; uint u; } v; v.f = f;
  uint r = v.u + 0x7FFF + ((v.u >> 16) & 1);
  return (ushort)(r >> 16);
}

// ---------------- small utility kernels ----------------

__global__ void k_deg(const float* __restrict__ g, float* __restrict__ isq,
                      float* __restrict__ trw) {
  int i = blockIdx.x, b = blockIdx.y;
  if (i == 0 && threadIdx.x == 0) trw[b] = 0.f;  // runs before k_rowsum's atomics
  const float* row = g + ((size_t)b * kN + i) * kN;
  float s = 0.f;
  for (int j = threadIdx.x; j < kN; j += 64) s += row[j];
#pragma unroll
  for (int off = 32; off; off >>= 1) s += __shfl_down(s, off);
  if (threadIdx.x == 0) {
    float dg = s < kEPS ? kEPS : s;
    isq[b * kN + i] = 1.0f / sqrtf(dg);
  }
}

__global__ void k_rowsum(const float* __restrict__ g, const float* __restrict__ isq,
                         float* __restrict__ rs, float* __restrict__ trw) {
  int i = blockIdx.x, b = blockIdx.y;
  const float* row = g + ((size_t)b * kN + i) * kN;
  const float* is = isq + b * kN;
  float s = 0.f, diag = 0.f;
  for (int j = threadIdx.x; j < kN; j += 64) {
    float gv = row[j];
    s += gv * is[j];
    if (j == i) diag = gv;
  }
#pragma unroll
  for (int off = 32; off; off >>= 1) {
    s += __shfl_down(s, off);
    diag += __shfl_down(diag, off);
  }
  if (threadIdx.x == 0) {
    float isi = is[i];
    rs[b * kN + i] = isi * s;
    atomicAdd(&trw[b], diag * isi * isi);
  }
}

__global__ void k_mu_wc(const float* __restrict__ tokens, const float* __restrict__ rs,
                        const float* __restrict__ trw, float* __restrict__ mu,
                        float* __restrict__ wc) {
  int b = blockIdx.x, d = threadIdx.x;  // blockDim = 384
  const float* r = rs + b * kN;
  const float* tb = tokens + (size_t)b * kN * kD + d;
  float T = 0.f, S = 0.f;
  for (int n = 0; n < kN; ++n) {
    float rv = r[n];
    T += tb[(size_t)n * kD] * rv;
    S += rv;
  }
  float invtr = 1.0f / (trw[b] + kEPS);
  float m = T * invtr;
  mu[b * kD + d] = m;
  wc[b * kD + d] = m * (1.0f - S * invtr);
}

// W_bf[b][n][m] = g[n,m]*is[n]*is[m] bf16, zero-padded to 256x256
__global__ __launch_bounds__(256) void k_prep_w(const float* __restrict__ g,
                                                const float* __restrict__ isq,
                                                ushort* __restrict__ wbf) {
  int b = blockIdx.y;
  int row0 = blockIdx.x * 64;
  const float* gb = g + (size_t)b * kN * kN;
  const float* is = isq + b * kN;
  ushort* wb = wbf + (size_t)b * kNP * kNP;
  for (int n = row0; n < row0 + 64; ++n) {
    float isn = (n < kN) ? is[n] : 0.f;
    int m = threadIdx.x;
    float v = 0.f;
    if (n < kN && m < kN) v = gb[(size_t)n * kN + m] * isn * is[m];
    wb[(size_t)n * kNP + m] = f2bf(v);
  }
}

// XcT[b][d][n] = bf16(tokens[b,n,d] - mu[b,d]), zero-padded n -> 256
__global__ __launch_bounds__(256) void k_prep_xct(const float* __restrict__ tokens,
                                                  const float* __restrict__ mu,
                                                  ushort* __restrict__ xct) {
  __shared__ ushort Ls[64][72];
  int b = blockIdx.z;
  int n0 = blockIdx.x * 64, d0 = blockIdx.y * 64;
  int tid = threadIdx.x;
  const float* tb = tokens + (size_t)b * kN * kD;
  const float* mb = mu + b * kD;
#pragma unroll
  for (int h = 0; h < 4; ++h) {
    int id = tid + 256 * h;
    int r = id >> 4, c4 = id & 15;
    bool ok = (n0 + r) < kN;
    float4 mv = *(const float4*)(mb + d0 + c4 * 4);
    float4 t = make_float4(0.f, 0.f, 0.f, 0.f);
    if (ok) t = *(const float4*)(tb + (size_t)(n0 + r) * kD + d0 + c4 * 4);
    Ls[r][c4 * 4 + 0] = f2bf(ok ? t.x - mv.x : 0.f);
    Ls[r][c4 * 4 + 1] = f2bf(ok ? t.y - mv.y : 0.f);
    Ls[r][c4 * 4 + 2] = f2bf(ok ? t.z - mv.z : 0.f);
    Ls[r][c4 * 4 + 3] = f2bf(ok ? t.w - mv.w : 0.f);
  }
  __syncthreads();
#pragma unroll
  for (int h = 0; h < 2; ++h) {
    int id = tid + 256 * h;
    int dr = id >> 3, c8 = id & 7;
    ushort v[8];
#pragma unroll
    for (int s = 0; s < 8; ++s) v[s] = Ls[c8 * 8 + s][dr];
    *(s16x8*)(xct + (size_t)b * kD * kNP + (size_t)(d0 + dr) * kNP + n0 + c8 * 8) =
        *(s16x8*)v;
  }
}

// ---- shared 128x128-tile bf16 MFMA main loop (one barrier per K-step) ----
// Reads A rows [m0,m0+128) of lda-stride bf16, Bt rows [n0,n0+128); K = ksteps*32.
__device__ __forceinline__ void mm_body(const ushort* __restrict__ Ag, int lda,
                                        const ushort* __restrict__ Bg, int ldb,
                                        int m0, int n0, int ksteps,
                                        ushort* lds, f32x4 acc[4][4]) {
  int tid = threadIdx.x;
  int lane = tid & 63, wid = tid >> 6;
  int wr = wid >> 1, wc = wid & 1;
  int l15 = lane & 15, kq = lane >> 4;
  int rs = tid >> 2, kb = tid & 3;

  auto st = [&](ushort* base, int r, float4 v) {
    *(float4*)((char*)base + kb * 2048 + ((r ^ (kb << 2)) << 4)) = v;
  };
  auto frag = [&](const ushort* base, int row) {
    return *(const s16x8*)((const char*)base + kq * 2048 + ((row ^ (kq << 2)) << 4));
  };

  float4 sa0 = *(const float4*)(Ag + (size_t)(m0 + rs) * lda + kb * 8);
  float4 sa1 = *(const float4*)(Ag + (size_t)(m0 + rs + 64) * lda + kb * 8);
  float4 sb0 = *(const float4*)(Bg + (size_t)(n0 + rs) * ldb + kb * 8);
  float4 sb1 = *(const float4*)(Bg + (size_t)(n0 + rs + 64) * ldb + kb * 8);
  st(lds, rs, sa0);
  st(lds, rs + 64, sa1);
  st(lds + 4096, rs, sb0);
  st(lds + 4096, rs + 64, sb1);
  __syncthreads();

  for (int kt = 0; kt < ksteps; ++kt) {
    ushort* Lc = lds + (kt & 1) * 8192;
    if (kt + 1 < ksteps) {
      int kk = (kt + 1) * 32 + kb * 8;
      sa0 = *(const float4*)(Ag + (size_t)(m0 + rs) * lda + kk);
      sa1 = *(const float4*)(Ag + (size_t)(m0 + rs + 64) * lda + kk);
      sb0 = *(const float4*)(Bg + (size_t)(n0 + rs) * ldb + kk);
      sb1 = *(const float4*)(Bg + (size_t)(n0 + rs + 64) * ldb + kk);
    }
    s16x8 af[4], bfv[4];
#pragma unroll
    for (int i = 0; i < 4; ++i) af[i] = frag(Lc, wr * 64 + i * 16 + l15);
#pragma unroll
    for (int j = 0; j < 4; ++j) bfv[j] = frag(Lc + 4096, wc * 64 + j * 16 + l15);
#pragma unroll
    for (int i = 0; i < 4; ++i)
#pragma unroll
      for (int j = 0; j < 4; ++j)
        acc[i][j] = __builtin_amdgcn_mfma_f32_16x16x32_bf16(af[i], bfv[j], acc[i][j], 0, 0, 0);
    if (kt + 1 < ksteps) {
      ushort* Ln = lds + ((kt + 1) & 1) * 8192;
      st(Ln, rs, sa0);
      st(Ln, rs + 64, sa1);
      st(Ln + 4096, rs, sb0);
      st(Ln + 4096, rs + 64, sb1);
    }
    __syncthreads();
  }
}

// ---- generalized batched bf16 MFMA GEMM (moment path) ----
__global__ __launch_bounds__(256) void k_gemm_bf(const ushort* __restrict__ A, int lda, int sa,
                                                 const ushort* __restrict__ Bt, int ldb, int sb,
                                                 void* __restrict__ Cv, int ldc, int sc,
                                                 int ksteps, int f32out) {
  __shared__ ushort lds[16384];
  int b = blockIdx.z;
  int m0 = blockIdx.y * 128, n0 = blockIdx.x * 128;
  int tid = threadIdx.x;
  int lane = tid & 63, wid = tid >> 6;
  int wr = wid >> 1, wc = wid & 1;
  int l15 = lane & 15, kq = lane >> 4;

  f32x4 acc[4][4];
#pragma unroll
  for (int i = 0; i < 4; ++i)
#pragma unroll
    for (int j = 0; j < 4; ++j) acc[i][j] = (f32x4){0.f, 0.f, 0.f, 0.f};

  mm_body(A + (size_t)b * sa, lda, Bt + (size_t)b * sb, ldb, m0, n0, ksteps, lds, acc);

  if (f32out) {
    float* Cb = (float*)Cv + (size_t)b * sc;
#pragma unroll
    for (int i = 0; i < 4; ++i)
#pragma unroll
      for (int j = 0; j < 4; ++j) {
        int row0 = wr * 64 + i * 16 + kq * 4;
        int col = wc * 64 + j * 16 + l15;
#pragma unroll
        for (int v = 0; v < 4; ++v)
          Cb[(size_t)(m0 + row0 + v) * ldc + n0 + col] = acc[i][j][v];
      }
  } else {
    ushort* Cb = (ushort*)Cv + (size_t)b * sc;
#pragma unroll
    for (int i = 0; i < 4; ++i)
#pragma unroll
      for (int j = 0; j < 4; ++j) {
        int row0 = wr * 64 + i * 16 + kq * 4;
        int col = wc * 64 + j * 16 + l15;
#pragma unroll
        for (int v = 0; v < 4; ++v) {
          int row = row0 + v;
          int byt = row * 256 + ((col * 2) ^ ((row & 15) << 4));
          *(ushort*)((char*)lds + byt) = f2bf(acc[i][j][v]);
        }
      }
    __syncthreads();
#pragma unroll
    for (int h = 0; h < 8; ++h) {
      int id = tid + 256 * h;
      int row = id >> 4, c16 = id & 15;
      int byt = row * 256 + ((c16 * 16) ^ ((row & 15) << 4));
      s16x8 vv = *(const s16x8*)((char*)lds + byt);
      *(s16x8*)(Cb + (size_t)(m0 + row) * ldc + n0 + c16 * 8) = vv;
    }
  }
}

__global__ void k_trace(const float* __restrict__ m2, float* __restrict__ tinv,
                        float* __restrict__ tsc) {
  int b = blockIdx.x;
  const float* mb = m2 + (size_t)b * kDD;
  float s = 0.f;
  for (int d = threadIdx.x; d < kD; d += 64) s += mb[(size_t)d * kD + d];
#pragma unroll
  for (int off = 32; off; off >>= 1) s += __shfl_down(s, off);
  if (threadIdx.x == 0) {
    float t = s + kEPS;
    tinv[b] = 1.0f / t;
    tsc[b] = 1.0f / sqrtf(t);
  }
}

// M2 fp32 -> Y1 (bf16 row-major), AT (bf16, =A^T), Y1T (bf16, =Y1^T)
__global__ __launch_bounds__(256) void k_init2(const float* __restrict__ M2,
                                               const float* __restrict__ tinv,
                                               ushort* __restrict__ Y1,
                                               ushort* __restrict__ AT,
                                               ushort* __restrict__ Y1T) {
  __shared__ ushort Ls[64][72];
  int b = blockIdx.z;
  int r0 = blockIdx.y * 64, c0 = blockIdx.x * 64;
  int tid = threadIdx.x;
  float ti = tinv[b];
  const float* Mb = M2 + (size_t)b * kDD;
  ushort* Yb = Y1 + (size_t)b * kDD;
#pragma unroll
  for (int h = 0; h < 4; ++h) {
    int id = tid + 256 * h;
    int r = id >> 4, c4 = id & 15;
    float4 m = *(const float4*)(Mb + (size_t)(r0 + r) * kD + c0 + c4 * 4);
    const float* mp = (const float*)&m;
    u16x4 y;
#pragma unroll
    for (int e = 0; e < 4; ++e) {
      float av = mp[e] * ti;
      Ls[r][c4 * 4 + e] = f2bf(av);
      float yv = ((r0 + r) == (c0 + c4 * 4 + e) ? 1.5f : 0.f) - 0.5f * av;
      y[e] = f2bf(yv);
    }
    *(u16x4*)(Yb + (size_t)(r0 + r) * kD + c0 + c4 * 4) = y;
  }
  __syncthreads();
  int oc = tid >> 2, och = tid & 3;
  ushort atv[16], ytv[16];
#pragma unroll
  for (int s = 0; s < 16; ++s) {
    int r = och * 16 + s;
    ushort a = Ls[r][oc];
    atv[s] = a;
    float av = bf2f(a);
    float yv = ((c0 + oc) == (r0 + r) ? 1.5f : 0.f) - 0.5f * av;
    ytv[s] = f2bf(yv);
  }
  size_t obase = (size_t)b * kDD + (size_t)(c0 + oc) * kD + r0 + och * 16;
  *(s16x8*)(AT + obase) = *(s16x8*)&atv[0];
  *(s16x8*)(AT + obase + 8) = *(s16x8*)&atv[8];
  *(s16x8*)(Y1T + obase) = *(s16x8*)&ytv[0];
  *(s16x8*)(Y1T + obase + 8) = *(s16x8*)&ytv[8];
}

// ---- NS dispatch 1 (fused pair): z<64: U=Y*A (row-major);  z>=64: St=(Y*Y)^T
__global__ __launch_bounds__(256) void k_ns_pair(const ushort* __restrict__ Y,
                                                 const ushort* __restrict__ AT,
                                                 const ushort* __restrict__ YT,
                                                 ushort* __restrict__ U,
                                                 ushort* __restrict__ St) {
  __shared__ ushort lds[16384];
  int z = blockIdx.z, b = z & 63, second = z >> 6;
  size_t boff = (size_t)b * kDD;
  int m0 = blockIdx.y * 128, n0 = blockIdx.x * 128;
  int tid = threadIdx.x;
  int lane = tid & 63, wid = tid >> 6;
  int wr = wid >> 1, wc = wid & 1;
  int l15 = lane & 15, kq = lane >> 4;

  f32x4 acc[4][4];
#pragma unroll
  for (int i = 0; i < 4; ++i)
#pragma unroll
    for (int j = 0; j < 4; ++j) acc[i][j] = (f32x4){0.f, 0.f, 0.f, 0.f};

  const ushort* Bg = (second ? YT : AT) + boff;
  mm_body(Y + boff, kD, Bg, kD, m0, n0, 12, lds, acc);

  // stage bf16 tile into lds (swizzled row-major)
#pragma unroll
  for (int i = 0; i < 4; ++i)
#pragma unroll
    for (int j = 0; j < 4; ++j) {
      int row0 = wr * 64 + i * 16 + kq * 4;
      int col = wc * 64 + j * 16 + l15;
#pragma unroll
      for (int v = 0; v < 4; ++v) {
        int row = row0 + v;
        int byt = row * 256 + ((col * 2) ^ ((row & 15) << 4));
        *(ushort*)((char*)lds + byt) = f2bf(acc[i][j][v]);
      }
    }
  __syncthreads();
  if (!second) {  // U row-major
#pragma unroll
    for (int h = 0; h < 8; ++h) {
      int id = tid + 256 * h;
      int row = id >> 4, c16 = id & 15;
      int byt = row * 256 + ((c16 * 16) ^ ((row & 15) << 4));
      s16x8 vv = *(const s16x8*)((char*)lds + byt);
      *(s16x8*)(U + boff + (size_t)(m0 + row) * kD + n0 + c16 * 8) = vv;
    }
  } else {  // St = S^T
#pragma unroll
    for (int h = 0; h < 8; ++h) {
      int id = tid + 256 * h;
      int p = id >> 4, c16 = id & 15;
      ushort vv[8];
#pragma unroll
      for (int s = 0; s < 8; ++s) {
        int r = c16 * 8 + s;
        vv[s] = *(const ushort*)((char*)lds + r * 256 + ((p * 2) ^ ((r & 15) << 4)));
      }
      *(s16x8*)(St + boff + (size_t)(n0 + p) * kD + m0 + c16 * 8) = *(s16x8*)vv;
    }
  }
}

// ---- NS dispatch 2: Ynext = 1.5*Y - 0.5*U*S  (Bt = St = S^T)
// if m2v != null (final iter): write upper-tri of Ynext scaled by tsc into m2v only.
__global__ __launch_bounds__(256) void k_ns_upd(const ushort* __restrict__ U,
                                                const ushort* __restrict__ St,
                                                const ushort* __restrict__ Y,
                                                ushort* __restrict__ Yn,
                                                ushort* __restrict__ YTn,
                                                ushort* __restrict__ m2v,
                                                const float* __restrict__ tsc) {
  __shared__ ushort lds[16384];
  int b = blockIdx.z;
  size_t boff = (size_t)b * kDD;
  int m0 = blockIdx.y * 128, n0 = blockIdx.x * 128;
  if (m2v && m0 > n0 + 127) return;  // strictly-lower tile, nothing to emit
  int tid = threadIdx.x;
  int lane = tid & 63, wid = tid >> 6;
  int wr = wid >> 1, wc = wid & 1;
  int l15 = lane & 15, kq = lane >> 4;

  f32x4 acc[4][4];
#pragma unroll
  for (int i = 0; i < 4; ++i)
#pragma unroll
    for (int j = 0; j < 4; ++j) acc[i][j] = (f32x4){0.f, 0.f, 0.f, 0.f};

  mm_body(U + boff, kD, St + boff, kD, m0, n0, 12, lds, acc);

  if (m2v) {
    float scale = tsc[b];
#pragma unroll
    for (int i = 0; i < 4; ++i)
#pragma unroll
      for (int j = 0; j < 4; ++j) {
        int row0 = m0 + wr * 64 + i * 16 + kq * 4;
        int gcol = n0 + wc * 64 + j * 16 + l15;
#pragma unroll
        for (int v = 0; v < 4; ++v) {
          int grow = row0 + v;
          if (grow <= gcol) {
            float f = 1.5f * bf2f(Y[boff + (size_t)grow * kD + gcol]) - 0.5f * acc[i][j][v];
            int t = (grow * (769 - grow)) / 2 + (gcol - grow);
            m2v[(size_t)b * kTRI + t] = f2bf(f * scale);
          }
        }
      }
    return;
  }

  // stage f = 1.5Y - 0.5*acc into lds
#pragma unroll
  for (int i = 0; i < 4; ++i)
#pragma unroll
    for (int j = 0; j < 4; ++j) {
      int row0 = wr * 64 + i * 16 + kq * 4;
      int col = wc * 64 + j * 16 + l15;
#pragma unroll
      for (int v = 0; v < 4; ++v) {
        int row = row0 + v;
        float f = 1.5f * bf2f(Y[boff + (size_t)(m0 + row) * kD + n0 + col]) -
                  0.5f * acc[i][j][v];
        int byt = row * 256 + ((col * 2) ^ ((row & 15) << 4));
        *(ushort*)((char*)lds + byt) = f2bf(f);
      }
    }
  __syncthreads();
#pragma unroll
  for (int h = 0; h < 8; ++h) {
    int id = tid + 256 * h;
    int row = id >> 4, c16 = id & 15;
    int byt = row * 256 + ((c16 * 16) ^ ((row & 15) << 4));
    s16x8 vv = *(const s16x8*)((char*)lds + byt);
    *(s16x8*)(Yn + boff + (size_t)(m0 + row) * kD + n0 + c16 * 8) = vv;
  }
  // YTn via transposed lds reads (no restage needed)
#pragma unroll
  for (int h = 0; h < 8; ++h) {
    int id = tid + 256 * h;
    int p = id >> 4, c16 = id & 15;
    ushort vv[8];
#pragma unroll
    for (int s = 0; s < 8; ++s) {
      int r = c16 * 8 + s;
      vv[s] = *(const ushort*)((char*)lds + r * 256 + ((p * 2) ^ ((r & 15) << 4)));
    }
    *(s16x8*)(YTn + boff + (size_t)(n0 + p) * kD + m0 + c16 * 8) = *(s16x8*)vv;
  }
}

__global__ void k_bias_init(float* __restrict__ dst, const float* __restrict__ bias,
                            int cols, int ldo) {
  int total = kB * cols;
  for (int i = blockIdx.x * blockDim.x + threadIdx.x; i < total;
       i += gridDim.x * blockDim.x) {
    int row = i / cols, col = i % cols;
    dst[(size_t)row * ldo + col] = bias[col];
  }
}

// ---- big skinny GEMM, LDS-free streaming MFMA:
// C[64][1024] += A_bf16[64][73920] @ W_fp32[73920][1024]
__global__ __launch_bounds__(256) void k_skinny_stream(const ushort* __restrict__ A,
                                                       const float* __restrict__ W,
                                                       float* __restrict__ C,
                                                       int steps) {
  int tid = threadIdx.x;
  int lane = tid & 63, w = tid >> 6;
  int l15 = lane & 15, kq = lane >> 4;
  int n0 = blockIdx.x * 64;
  int col = n0 + w * 16 + l15;
  int k0 = blockIdx.y * steps * 32;

  f32x4 acc[4];
#pragma unroll
  for (int i = 0; i < 4; ++i) acc[i] = (f32x4){0.f, 0.f, 0.f, 0.f};

  float wv[8];
  {
    int kk = k0 + kq * 8;
#pragma unroll
    for (int s = 0; s < 8; ++s) wv[s] = W[(size_t)(kk + s) * 1024 + col];
  }
  for (int t = 0; t < steps; ++t) {
    float nv[8];
    if (t + 1 < steps) {
      int kk = k0 + (t + 1) * 32 + kq * 8;
#pragma unroll
      for (int s = 0; s < 8; ++s) nv[s] = W[(size_t)(kk + s) * 1024 + col];
    } else {
#pragma unroll
      for (int s = 0; s < 8; ++s) nv[s] = 0.f;
    }
    s16x8 bf;
    ushort* bp = (ushort*)&bf;
#pragma unroll
    for (int s = 0; s < 8; ++s) bp[s] = f2bf(wv[s]);
    int kk = k0 + t * 32 + kq * 8;
#pragma unroll
    for (int i = 0; i < 4; ++i) {
      s16x8 af = *(const s16x8*)(A + (size_t)(i * 16 + l15) * kTRI + kk);
      acc[i] = __builtin_amdgcn_mfma_f32_16x16x32_bf16(af, bf, acc[i], 0, 0, 0);
    }
#pragma unroll
    for (int s = 0; s < 8; ++s) wv[s] = nv[s];
  }

#pragma unroll
  for (int i = 0; i < 4; ++i) {
#pragma unroll
    for (int v = 0; v < 4; ++v) {
      int m = i * 16 + kq * 4 + v;
      atomicAdd(&C[(size_t)m * 1024 + col], acc[i][v]);
    }
  }
}

// skinny GEMM, M=64, double-buffered fp32 (small GEMMs)
__global__ __launch_bounds__(256) void k_skinny2(const float* __restrict__ A, int lda,
                                                 const float* __restrict__ Bm, int ldb,
                                                 float* __restrict__ C, int ldc,
                                                 int ktiles) {
  __shared__ float As[2][16][68];
  __shared__ float Bs[2][16][68];
  int n0 = blockIdx.x * 64;
  int kt0 = blockIdx.y * ktiles * 16;
  int tid = threadIdx.x, tx = tid & 15, ty = tid >> 4;
  int ar = tid >> 2, aq = tid & 3;
  int bk = tid >> 4, bq = tid & 15;
  float4 apre = *(const float4*)&A[(size_t)ar * lda + kt0 + aq * 4];
  float4 bpre = *(const float4*)&Bm[(size_t)(kt0 + bk) * ldb + n0 + bq * 4];
  As[0][aq * 4 + 0][ar] = apre.x;
  As[0][aq * 4 + 1][ar] = apre.y;
  As[0][aq * 4 + 2][ar] = apre.z;
  As[0][aq * 4 + 3][ar] = apre.w;
  *(float4*)&Bs[0][bk][bq * 4] = bpre;
  __syncthreads();
  float acc[4][4] = {};
  for (int t = 0; t < ktiles; ++t) {
    int cur = t & 1;
    if (t + 1 < ktiles) {
      int kt = kt0 + (t + 1) * 16;
      apre = *(const float4*)&A[(size_t)ar * lda + kt + aq * 4];
      bpre = *(const float4*)&Bm[(size_t)(kt + bk) * ldb + n0 + bq * 4];
    }
#pragma unroll
    for (int k = 0; k < 16; ++k) {
      float a[4], bb[4];
#pragma unroll
      for (int i = 0; i < 4; ++i) a[i] = As[cur][k][ty * 4 + i];
#pragma unroll
      for (int j = 0; j < 4; ++j) bb[j] = Bs[cur][k][tx * 4 + j];
#pragma unroll
      for (int i = 0; i < 4; ++i)
#pragma unroll
        for (int j = 0; j < 4; ++j) acc[i][j] += a[i] * bb[j];
    }
    __syncthreads();
    if (t + 1 < ktiles) {
      int nxt = cur ^ 1;
      As[nxt][aq * 4 + 0][ar] = apre.x;
      As[nxt][aq * 4 + 1][ar] = apre.y;
      As[nxt][aq * 4 + 2][ar] = apre.z;
      As[nxt][aq * 4 + 3][ar] = apre.w;
      *(float4*)&Bs[nxt][bk][bq * 4] = bpre;
    }
    __syncthreads();
  }
  for (int i = 0; i < 4; ++i)
    for (int j = 0; j < 4; ++j)
      atomicAdd(&C[(size_t)(ty * 4 + i) * ldc + n0 + tx * 4 + j], acc[i][j]);
}

__global__ void k_bngelu(const float* __restrict__ h, const float* __restrict__ gamma,
                         const float* __restrict__ beta, const float* __restrict__ rm,
                         const float* __restrict__ rv, float* __restrict__ o, int cols) {
  int total = kB * cols;
  for (int i = blockIdx.x * blockDim.x + threadIdx.x; i < total;
       i += gridDim.x * blockDim.x) {
    int col = i % cols;
    float x = h[i];
    float xn = (x - rm[col]) / sqrtf(rv[col] + kBNEPS) * gamma[col] + beta[col];
    o[i] = xn * 0.5f * (1.0f + erff(xn * 0.70710678118654752f));
  }
}

__global__ void k_sketch(const float* __restrict__ wc, const int* __restrict__ h1,
                         const int* __restrict__ h2, const int* __restrict__ h3,
                         const float* __restrict__ s1, const float* __restrict__ s2,
                         const float* __restrict__ s3, float* __restrict__ sk) {
  __shared__ float L1[kS];
  __shared__ float L2[kS];
  __shared__ float L3[kS];
  int b = blockIdx.x;
  for (int i = threadIdx.x; i < kS; i += blockDim.x) {
    L1[i] = 0.f;
    L2[i] = 0.f;
    L3[i] = 0.f;
  }
  __syncthreads();
  for (int d = threadIdx.x; d < kD; d += blockDim.x) {
    float w = wc[b * kD + d];
    atomicAdd(&L1[h1[d]], w * s1[d]);
    atomicAdd(&L2[h2[d]], w * s2[d]);
    atomicAdd(&L3[h3[d]], w * s3[d]);
  }
  __syncthreads();
  for (int i = threadIdx.x; i < kS; i += blockDim.x)
    sk[(size_t)b * kS + i] = L1[i] * L2[i] * L3[i];
}

}  // namespace

extern "C" void kernel_launch(void* const* d_in, const int* in_sizes, int n_in,
                              void* d_out, int out_size, void* d_ws, size_t ws_size,
                              hipStream_t stream) {
  (void)in_sizes; (void)n_in; (void)out_size; (void)ws_size;
  const float* tokens = (const float*)d_in[0];
  const float* graph  = (const float*)d_in[1];
  const int*   hash1  = (const int*)d_in[2];
  const int*   hash2  = (const int*)d_in[3];
  const int*   hash3  = (const int*)d_in[4];
  const float* sign1  = (const float*)d_in[5];
  const float* sign2  = (const float*)d_in[6];
  const float* sign3  = (const float*)d_in[7];
  const float* w1_2   = (const float*)d_in[8];
  const float* b1_2   = (const float*)d_in[9];
  const float* gamma2 = (const float*)d_in[10];
  const float* beta2  = (const float*)d_in[11];
  const float* rm2    = (const float*)d_in[12];
  const float* rv2    = (const float*)d_in[13];
  const float* w2_2   = (const float*)d_in[14];
  const float* b2_2   = (const float*)d_in[15];
  const float* w1_3   = (const float*)d_in[16];
  const float* b1_3   = (const float*)d_in[17];
  const float* gamma3 = (const float*)d_in[18];
  const float* beta3  = (const float*)d_in[19];
  const float* rm3    = (const float*)d_in[20];
  const float* rv3    = (const float*)d_in[21];
  const float* w2_3   = (const float*)d_in[22];
  const float* b2_3   = (const float*)d_in[23];
  float* outp = (float*)d_out;

  char* cp = (char*)d_ws;
  auto takeB = [&](size_t bytes) {
    char* q = cp;
    cp += (bytes + 255) & ~(size_t)255;
    return q;
  };
  float* isq  = (float*)takeB((size_t)kB * kN * 4);
  float* rsb  = (float*)takeB((size_t)kB * kN * 4);
  float* trw  = (float*)takeB(256);
  float* tinv = (float*)takeB(256);
  float* tsc  = (float*)takeB(256);
  float* mu   = (float*)takeB((size_t)kB * kD * 4);
  float* wc   = (float*)takeB((size_t)kB * kD * 4);
  ushort* xct = (ushort*)takeB((size_t)kB * kD * kNP * 2);
  ushort* wbf = (ushort*)takeB((size_t)kB * kNP * kNP * 2);
  ushort* wxt = (ushort*)takeB((size_t)kB * kD * kNP * 2);
  float* M2   = (float*)takeB((size_t)kB * kDD * 4);
  ushort* AT  = (ushort*)takeB((size_t)kB * kDD * 2);
  ushort* Ya  = (ushort*)takeB((size_t)kB * kDD * 2);
  ushort* Yb2 = (ushort*)takeB((size_t)kB * kDD * 2);
  ushort* YTa = (ushort*)takeB((size_t)kB * kDD * 2);
  ushort* YTb = (ushort*)takeB((size_t)kB * kDD * 2);
  ushort* m2v = (ushort*)takeB((size_t)kB * kTRI * 2);
  float* h1b  = (float*)takeB((size_t)kB * 1024 * 4);
  float* h1g  = (float*)takeB((size_t)kB * 1024 * 4);
  float* h3b  = (float*)takeB((size_t)kB * 1024 * 4);
  float* h3g  = (float*)takeB((size_t)kB * 1024 * 4);
  float* sk   = (float*)takeB((size_t)kB * kS * 4);
  // after k_init2, M2 fp32 region is dead -> reuse as two bf16 buffers
  ushort* Ubuf = (ushort*)M2;
  ushort* Stbuf = (ushort*)M2 + (size_t)kB * kDD;

  // graph stats
  hipLaunchKernelGGL(k_deg, dim3(kN, kB), dim3(64), 0, stream, graph, isq, trw);
  hipLaunchKernelGGL(k_rowsum, dim3(kN, kB), dim3(64), 0, stream, graph, isq, rsb, trw);
  hipLaunchKernelGGL(k_mu_wc, dim3(kB), dim3(kD), 0, stream, tokens, rsb, trw, mu, wc);

  // moment path via MFMA: XcT, W_bf, then WXT = XcT @ W^T, M2 = XcT @ WX
  hipLaunchKernelGGL(k_prep_w, dim3(4, kB), dim3(256), 0, stream, graph, isq, wbf);
  hipLaunchKernelGGL(k_prep_xct, dim3(4, 6, kB), dim3(256), 0, stream, tokens, mu, xct);
  hipLaunchKernelGGL(k_gemm_bf, dim3(2, 3, kB), dim3(256), 0, stream,
                     xct, kNP, kD * kNP, wbf, kNP, kNP * kNP,
                     (void*)wxt, kNP, kD * kNP, 8, 0);
  hipLaunchKernelGGL(k_gemm_bf, dim3(3, 3, kB), dim3(256), 0, stream,
                     xct, kNP, kD * kNP, wxt, kNP, kD * kNP,
                     (void*)M2, kD, kDD, 8, 1);
  hipLaunchKernelGGL(k_trace, dim3(kB), dim3(64), 0, stream, M2, tinv, tsc);
  hipLaunchKernelGGL(k_init2, dim3(6, 6, kB), dim3(256), 0, stream, M2, tinv, Ya, AT, YTa);

  // Newton-Schulz: per iter  {U=Y*A & St=(Y*Y)^T} ; Ynext = 1.5Y - 0.5*U*S
  ushort* Yc = Ya;
  ushort* YTc = YTa;
  ushort* Yn = Yb2;
  ushort* YTn = YTb;
  for (int it = 0; it < 4; ++it) {
    hipLaunchKernelGGL(k_ns_pair, dim3(3, 3, 128), dim3(256), 0, stream,
                       Yc, AT, YTc, Ubuf, Stbuf);
    if (it < 3) {
      hipLaunchKernelGGL(k_ns_upd, dim3(3, 3, kB), dim3(256), 0, stream,
                         Ubuf, Stbuf, Yc, Yn, YTn, (ushort*)nullptr, (const float*)nullptr);
    } else {
      hipLaunchKernelGGL(k_ns_upd, dim3(3, 3, kB), dim3(256), 0, stream,
                         Ubuf, Stbuf, Yc, (ushort*)nullptr, (ushort*)nullptr, m2v, tsc);
    }
    ushort* t1 = Yc; Yc = Yn; Yn = t1;
    ushort* t2 = YTc; YTc = YTn; YTn = t2;
  }

  // second path MLP: big GEMM as LDS-free streaming MFMA
  hipLaunchKernelGGL(k_bias_init, dim3(256), dim3(256), 0, stream, h1b, b1_2, 1024, 1024);
  hipLaunchKernelGGL(k_skinny_stream, dim3(16, 110), dim3(256), 0, stream,
                     m2v, w1_2, h1b, 21);  // 110*21*32 = 73920
  hipLaunchKernelGGL(k_bngelu, dim3(256), dim3(256), 0, stream,
                     h1b, gamma2, beta2, rm2, rv2, h1g, 1024);
  hipLaunchKernelGGL(k_bias_init, dim3(128), dim3(256), 0, stream, outp, b2_2, 512, 1024);
  hipLaunchKernelGGL(k_bias_init, dim3(128), dim3(256), 0, stream, outp + 512, b2_3, 512, 1024);
  hipLaunchKernelGGL(k_skinny2, dim3(8, 16), dim3(256), 0, stream,
                     h1g, 1024, w2_2, 512, outp, 1024, 4);  // 16*4*16 = 1024

  // third path (count-sketch MLP)
  hipLaunchKernelGGL(k_sketch, dim3(kB), dim3(256), 0, stream,
                     wc, hash1, hash2, hash3, sign1, sign2, sign3, sk);
  hipLaunchKernelGGL(k_bias_init, dim3(256), dim3(256), 0, stream, h3b, b1_3, 1024, 1024);
  hipLaunchKernelGGL(k_skinny2, dim3(16, 32), dim3(256), 0, stream,
                     sk, kS, w1_3, 1024, h3b, 1024, 8);  // 32*8*16 = 4096
  hipLaunchKernelGGL(k_bngelu, dim3(256), dim3(256), 0, stream,
                     h3b, gamma3, beta3, rm3, rv3, h3g, 1024);
  hipLaunchKernelGGL(k_skinny2, dim3(8, 16), dim3(256), 0, stream,
                     h3g, 1024, w2_3, 512, outp + 512, 1024, 4);
}

// Round 6
// 771.778 us; speedup vs baseline: 2.4505x; 1.0579x over previous
//
#include <hip/hip_runtime.h>
#include <math.h>

namespace {

constexpr int kB   = 64;
constexpr int kN   = 196;
constexpr int kD   = 384;
constexpr int kS   = 4096;
constexpr int kTRI = 73920;
constexpr int kDD  = kD * kD;          // 147456
constexpr int kNP  = 256;              // padded token dim for MFMA moment path
constexpr float kEPS   = 1e-5f;
constexpr float kBNEPS = 1e-5f;

typedef __attribute__((ext_vector_type(8))) short s16x8;
typedef __attribute__((ext_vector_type(4))) float f32x4;
typedef __attribute__((ext_vector_type(4))) ushort u16x4;

__device__ inline float bf2f(ushort h) {
  union { uint u; float f; } v; v.u = (uint)h << 16; return v.f;
}
__device__ inline ushort f2bf(float f) {
  union { float f; uint u; } v; v.f = f;
  uint r = v.u + 0x7FFF + ((v.u >> 16) & 1);
  return (ushort)(r >> 16);
}

// ---------------- stats + init kernels ----------------

// deg/isq; also zero-inits trw, tr2, h1b, h3b, outp using spare threads.
__global__ void k_deg(const float* __restrict__ g, float* __restrict__ isq,
                      float* __restrict__ trw, float* __restrict__ tr2,
                      float* __restrict__ h1b, float* __restrict__ h3b,
                      float* __restrict__ outp) {
  int i = blockIdx.x, b = blockIdx.y;
  int bid = blockIdx.y * gridDim.x + blockIdx.x;
  int gid = bid * 64 + threadIdx.x;
  if (gid < 65536) h1b[gid] = 0.f;
  else if (gid < 131072) h3b[gid - 65536] = 0.f;
  else if (gid < 196608) outp[gid - 131072] = 0.f;
  if (gid < 64) { trw[gid] = 0.f; tr2[gid] = 0.f; }
  const float* row = g + ((size_t)b * kN + i) * kN;
  float s = 0.f;
  for (int j = threadIdx.x; j < kN; j += 64) s += row[j];
#pragma unroll
  for (int off = 32; off; off >>= 1) s += __shfl_down(s, off);
  if (threadIdx.x == 0) {
    float dg = s < kEPS ? kEPS : s;
    isq[b * kN + i] = 1.0f / sqrtf(dg);
  }
}

// fused: rs/trw + padded bf16 W write. grid (196, 64), 64 threads.
__global__ void k_rowsum_w(const float* __restrict__ g, const float* __restrict__ isq,
                           float* __restrict__ rs, float* __restrict__ trw,
                           ushort* __restrict__ wbf) {
  int i = blockIdx.x, b = blockIdx.y;
  const float* row = g + ((size_t)b * kN + i) * kN;
  const float* is = isq + b * kN;
  float isi = is[i];
  ushort* wrow = wbf + (size_t)b * kNP * kNP + (size_t)i * kNP;
  float s = 0.f, diag = 0.f;
  for (int j = threadIdx.x; j < kNP; j += 64) {
    float wv = 0.f;
    if (j < kN) {
      float gv = row[j];
      float t = gv * is[j];
      s += t;
      if (j == i) diag = gv;
      wv = t * isi;
    }
    wrow[j] = f2bf(wv);
  }
#pragma unroll
  for (int off = 32; off; off >>= 1) {
    s += __shfl_down(s, off);
    diag += __shfl_down(diag, off);
  }
  if (threadIdx.x == 0) {
    rs[b * kN + i] = isi * s;
    atomicAdd(&trw[b], diag * isi * isi);
  }
  if (i < kNP - kN) {  // zero pad rows 196..255
    ushort* prow = wbf + (size_t)b * kNP * kNP + (size_t)(kN + i) * kNP;
    for (int j = threadIdx.x; j < kNP; j += 64) prow[j] = 0;
  }
}

// fused: mu + wc + XcT (bf16, n-padded to 256). grid (6, 64), 256 threads.
__global__ __launch_bounds__(256) void k_mu_xct(const float* __restrict__ tokens,
                                                const float* __restrict__ rs,
                                                const float* __restrict__ trw,
                                                float* __restrict__ wc,
                                                ushort* __restrict__ xct) {
  __shared__ float Ltok[kN][65];
  __shared__ float rs_l[kN];
  __shared__ float red[4][64];
  __shared__ float mu_l[64];
  __shared__ float Ssum;
  int b = blockIdx.y, d0 = blockIdx.x * 64;
  int tid = threadIdx.x, dloc = tid & 63, part = tid >> 6;
  if (tid < kN) rs_l[tid] = rs[b * kN + tid];
  __syncthreads();
  if (tid == 0) {
    float S = 0.f;
    for (int n = 0; n < kN; ++n) S += rs_l[n];
    Ssum = S;
  }
  float T = 0.f;
  const float* tb = tokens + (size_t)b * kN * kD + d0 + dloc;
  for (int n = part; n < kN; n += 4) {
    float t = tb[(size_t)n * kD];
    Ltok[n][dloc] = t;
    T += t * rs_l[n];
  }
  red[part][dloc] = T;
  __syncthreads();
  if (part == 0) {
    float invtr = 1.0f / (trw[b] + kEPS);
    float m = (red[0][dloc] + red[1][dloc] + red[2][dloc] + red[3][dloc]) * invtr;
    mu_l[dloc] = m;
    wc[b * kD + d0 + dloc] = m * (1.0f - Ssum * invtr);
  }
  __syncthreads();
  ushort* xb = xct + (size_t)b * kD * kNP + (size_t)d0 * kNP;
  int c0 = dloc * 4;
#pragma unroll
  for (int r4 = 0; r4 < 16; ++r4) {
    int drow = r4 * 4 + part;
    float m = mu_l[drow];
    u16x4 pk;
#pragma unroll
    for (int c = 0; c < 4; ++c) {
      int col = c0 + c;
      float v = (col < kN) ? (Ltok[col][drow] - m) : 0.f;
      pk[c] = f2bf(v);
    }
    *(u16x4*)(xb + (size_t)drow * kNP + c0) = pk;
  }
}

// ---- shared 128x128-tile bf16 MFMA main loop (one barrier per K-step) ----
__device__ __forceinline__ void mm_body(const ushort* __restrict__ Ag, int lda,
                                        const ushort* __restrict__ Bg, int ldb,
                                        int m0, int n0, int ksteps,
                                        ushort* lds, f32x4 acc[4][4]) {
  int tid = threadIdx.x;
  int lane = tid & 63, wid = tid >> 6;
  int wr = wid >> 1, wc = wid & 1;
  int l15 = lane & 15, kq = lane >> 4;
  int rs = tid >> 2, kb = tid & 3;

  auto st = [&](ushort* base, int r, float4 v) {
    *(float4*)((char*)base + kb * 2048 + ((r ^ (kb << 2)) << 4)) = v;
  };
  auto frag = [&](const ushort* base, int row) {
    return *(const s16x8*)((const char*)base + kq * 2048 + ((row ^ (kq << 2)) << 4));
  };

  float4 sa0 = *(const float4*)(Ag + (size_t)(m0 + rs) * lda + kb * 8);
  float4 sa1 = *(const float4*)(Ag + (size_t)(m0 + rs + 64) * lda + kb * 8);
  float4 sb0 = *(const float4*)(Bg + (size_t)(n0 + rs) * ldb + kb * 8);
  float4 sb1 = *(const float4*)(Bg + (size_t)(n0 + rs + 64) * ldb + kb * 8);
  st(lds, rs, sa0);
  st(lds, rs + 64, sa1);
  st(lds + 4096, rs, sb0);
  st(lds + 4096, rs + 64, sb1);
  __syncthreads();

  for (int kt = 0; kt < ksteps; ++kt) {
    ushort* Lc = lds + (kt & 1) * 8192;
    if (kt + 1 < ksteps) {
      int kk = (kt + 1) * 32 + kb * 8;
      sa0 = *(const float4*)(Ag + (size_t)(m0 + rs) * lda + kk);
      sa1 = *(const float4*)(Ag + (size_t)(m0 + rs + 64) * lda + kk);
      sb0 = *(const float4*)(Bg + (size_t)(n0 + rs) * ldb + kk);
      sb1 = *(const float4*)(Bg + (size_t)(n0 + rs + 64) * ldb + kk);
    }
    s16x8 af[4], bfv[4];
#pragma unroll
    for (int i = 0; i < 4; ++i) af[i] = frag(Lc, wr * 64 + i * 16 + l15);
#pragma unroll
    for (int j = 0; j < 4; ++j) bfv[j] = frag(Lc + 4096, wc * 64 + j * 16 + l15);
#pragma unroll
    for (int i = 0; i < 4; ++i)
#pragma unroll
      for (int j = 0; j < 4; ++j)
        acc[i][j] = __builtin_amdgcn_mfma_f32_16x16x32_bf16(af[i], bfv[j], acc[i][j], 0, 0, 0);
    if (kt + 1 < ksteps) {
      ushort* Ln = lds + ((kt + 1) & 1) * 8192;
      st(Ln, rs, sa0);
      st(Ln, rs + 64, sa1);
      st(Ln + 4096, rs, sb0);
      st(Ln + 4096, rs + 64, sb1);
    }
    __syncthreads();
  }
}

// ---- generalized batched bf16 MFMA GEMM (moment path); optional trace atomics ----
__global__ __launch_bounds__(256) void k_gemm_bf(const ushort* __restrict__ A, int lda, int sa,
                                                 const ushort* __restrict__ Bt, int ldb, int sb,
                                                 void* __restrict__ Cv, int ldc, int sc,
                                                 int ksteps, int f32out,
                                                 float* __restrict__ tr2) {
  __shared__ ushort lds[16384];
  int b = blockIdx.z;
  int m0 = blockIdx.y * 128, n0 = blockIdx.x * 128;
  int tid = threadIdx.x;
  int lane = tid & 63, wid = tid >> 6;
  int wr = wid >> 1, wc = wid & 1;
  int l15 = lane & 15, kq = lane >> 4;

  f32x4 acc[4][4];
#pragma unroll
  for (int i = 0; i < 4; ++i)
#pragma unroll
    for (int j = 0; j < 4; ++j) acc[i][j] = (f32x4){0.f, 0.f, 0.f, 0.f};

  mm_body(A + (size_t)b * sa, lda, Bt + (size_t)b * sb, ldb, m0, n0, ksteps, lds, acc);

  if (f32out) {
    float* Cb = (float*)Cv + (size_t)b * sc;
    float trpart = 0.f;
#pragma unroll
    for (int i = 0; i < 4; ++i)
#pragma unroll
      for (int j = 0; j < 4; ++j) {
        int row0 = wr * 64 + i * 16 + kq * 4;
        int col = wc * 64 + j * 16 + l15;
#pragma unroll
        for (int v = 0; v < 4; ++v) {
          float val = acc[i][j][v];
          Cb[(size_t)(m0 + row0 + v) * ldc + n0 + col] = val;
          if (tr2 && (m0 + row0 + v) == (n0 + col)) trpart += val;
        }
      }
    if (tr2 && trpart != 0.f) atomicAdd(&tr2[b], trpart);
  } else {
    ushort* Cb = (ushort*)Cv + (size_t)b * sc;
#pragma unroll
    for (int i = 0; i < 4; ++i)
#pragma unroll
      for (int j = 0; j < 4; ++j) {
        int row0 = wr * 64 + i * 16 + kq * 4;
        int col = wc * 64 + j * 16 + l15;
#pragma unroll
        for (int v = 0; v < 4; ++v) {
          int row = row0 + v;
          int byt = row * 256 + ((col * 2) ^ ((row & 15) << 4));
          *(ushort*)((char*)lds + byt) = f2bf(acc[i][j][v]);
        }
      }
    __syncthreads();
#pragma unroll
    for (int h = 0; h < 8; ++h) {
      int id = tid + 256 * h;
      int row = id >> 4, c16 = id & 15;
      int byt = row * 256 + ((c16 * 16) ^ ((row & 15) << 4));
      s16x8 vv = *(const s16x8*)((char*)lds + byt);
      *(s16x8*)(Cb + (size_t)(m0 + row) * ldc + n0 + c16 * 8) = vv;
    }
  }
}

// M2 fp32 -> Y1 (bf16 row-major), AT (bf16, =A^T), Y1T (bf16, =Y1^T); also tsc.
__global__ __launch_bounds__(256) void k_init2(const float* __restrict__ M2,
                                               const float* __restrict__ tr2,
                                               ushort* __restrict__ Y1,
                                               ushort* __restrict__ AT,
                                               ushort* __restrict__ Y1T,
                                               float* __restrict__ tsc) {
  __shared__ ushort Ls[64][72];
  int b = blockIdx.z;
  int r0 = blockIdx.y * 64, c0 = blockIdx.x * 64;
  int tid = threadIdx.x;
  float tr = tr2[b] + kEPS;
  float ti = 1.0f / tr;
  if (r0 == 0 && c0 == 0 && tid == 0) tsc[b] = rsqrtf(tr);
  const float* Mb = M2 + (size_t)b * kDD;
  ushort* Yb = Y1 + (size_t)b * kDD;
#pragma unroll
  for (int h = 0; h < 4; ++h) {
    int id = tid + 256 * h;
    int r = id >> 4, c4 = id & 15;
    float4 m = *(const float4*)(Mb + (size_t)(r0 + r) * kD + c0 + c4 * 4);
    const float* mp = (const float*)&m;
    u16x4 y;
#pragma unroll
    for (int e = 0; e < 4; ++e) {
      float av = mp[e] * ti;
      Ls[r][c4 * 4 + e] = f2bf(av);
      float yv = ((r0 + r) == (c0 + c4 * 4 + e) ? 1.5f : 0.f) - 0.5f * av;
      y[e] = f2bf(yv);
    }
    *(u16x4*)(Yb + (size_t)(r0 + r) * kD + c0 + c4 * 4) = y;
  }
  __syncthreads();
  int oc = tid >> 2, och = tid & 3;
  ushort atv[16], ytv[16];
#pragma unroll
  for (int s = 0; s < 16; ++s) {
    int r = och * 16 + s;
    ushort a = Ls[r][oc];
    atv[s] = a;
    float av = bf2f(a);
    float yv = ((c0 + oc) == (r0 + r) ? 1.5f : 0.f) - 0.5f * av;
    ytv[s] = f2bf(yv);
  }
  size_t obase = (size_t)b * kDD + (size_t)(c0 + oc) * kD + r0 + och * 16;
  *(s16x8*)(AT + obase) = *(s16x8*)&atv[0];
  *(s16x8*)(AT + obase + 8) = *(s16x8*)&atv[8];
  *(s16x8*)(Y1T + obase) = *(s16x8*)&ytv[0];
  *(s16x8*)(Y1T + obase + 8) = *(s16x8*)&ytv[8];
}

// ---- NS dispatch 1 (fused pair): z<64: U=Y*A;  z>=64: St=(Y*Y)^T
__global__ __launch_bounds__(256) void k_ns_pair(const ushort* __restrict__ Y,
                                                 const ushort* __restrict__ AT,
                                                 const ushort* __restrict__ YT,
                                                 ushort* __restrict__ U,
                                                 ushort* __restrict__ St) {
  __shared__ ushort lds[16384];
  int z = blockIdx.z, b = z & 63, second = z >> 6;
  size_t boff = (size_t)b * kDD;
  int m0 = blockIdx.y * 128, n0 = blockIdx.x * 128;
  int tid = threadIdx.x;
  int lane = tid & 63, wid = tid >> 6;
  int wr = wid >> 1, wc = wid & 1;
  int l15 = lane & 15, kq = lane >> 4;

  f32x4 acc[4][4];
#pragma unroll
  for (int i = 0; i < 4; ++i)
#pragma unroll
    for (int j = 0; j < 4; ++j) acc[i][j] = (f32x4){0.f, 0.f, 0.f, 0.f};

  const ushort* Bg = (second ? YT : AT) + boff;
  mm_body(Y + boff, kD, Bg, kD, m0, n0, 12, lds, acc);

#pragma unroll
  for (int i = 0; i < 4; ++i)
#pragma unroll
    for (int j = 0; j < 4; ++j) {
      int row0 = wr * 64 + i * 16 + kq * 4;
      int col = wc * 64 + j * 16 + l15;
#pragma unroll
      for (int v = 0; v < 4; ++v) {
        int row = row0 + v;
        int byt = row * 256 + ((col * 2) ^ ((row & 15) << 4));
        *(ushort*)((char*)lds + byt) = f2bf(acc[i][j][v]);
      }
    }
  __syncthreads();
  if (!second) {
#pragma unroll
    for (int h = 0; h < 8; ++h) {
      int id = tid + 256 * h;
      int row = id >> 4, c16 = id & 15;
      int byt = row * 256 + ((c16 * 16) ^ ((row & 15) << 4));
      s16x8 vv = *(const s16x8*)((char*)lds + byt);
      *(s16x8*)(U + boff + (size_t)(m0 + row) * kD + n0 + c16 * 8) = vv;
    }
  } else {
#pragma unroll
    for (int h = 0; h < 8; ++h) {
      int id = tid + 256 * h;
      int p = id >> 4, c16 = id & 15;
      ushort vv[8];
#pragma unroll
      for (int s = 0; s < 8; ++s) {
        int r = c16 * 8 + s;
        vv[s] = *(const ushort*)((char*)lds + r * 256 + ((p * 2) ^ ((r & 15) << 4)));
      }
      *(s16x8*)(St + boff + (size_t)(n0 + p) * kD + m0 + c16 * 8) = *(s16x8*)vv;
    }
  }
}

// ---- NS dispatch 2: Ynext = 1.5*Y - 0.5*U*S; final iter emits m2v directly.
__global__ __launch_bounds__(256) void k_ns_upd(const ushort* __restrict__ U,
                                                const ushort* __restrict__ St,
                                                const ushort* __restrict__ Y,
                                                ushort* __restrict__ Yn,
                                                ushort* __restrict__ YTn,
                                                ushort* __restrict__ m2v,
                                                const float* __restrict__ tsc) {
  __shared__ ushort lds[16384];
  int b = blockIdx.z;
  size_t boff = (size_t)b * kDD;
  int m0 = blockIdx.y * 128, n0 = blockIdx.x * 128;
  if (m2v && m0 > n0 + 127) return;
  int tid = threadIdx.x;
  int lane = tid & 63, wid = tid >> 6;
  int wr = wid >> 1, wc = wid & 1;
  int l15 = lane & 15, kq = lane >> 4;

  f32x4 acc[4][4];
#pragma unroll
  for (int i = 0; i < 4; ++i)
#pragma unroll
    for (int j = 0; j < 4; ++j) acc[i][j] = (f32x4){0.f, 0.f, 0.f, 0.f};

  mm_body(U + boff, kD, St + boff, kD, m0, n0, 12, lds, acc);

  if (m2v) {
    float scale = tsc[b];
#pragma unroll
    for (int i = 0; i < 4; ++i)
#pragma unroll
      for (int j = 0; j < 4; ++j) {
        int row0 = m0 + wr * 64 + i * 16 + kq * 4;
        int gcol = n0 + wc * 64 + j * 16 + l15;
#pragma unroll
        for (int v = 0; v < 4; ++v) {
          int grow = row0 + v;
          if (grow <= gcol) {
            float f = 1.5f * bf2f(Y[boff + (size_t)grow * kD + gcol]) - 0.5f * acc[i][j][v];
            int t = (grow * (769 - grow)) / 2 + (gcol - grow);
            m2v[(size_t)b * kTRI + t] = f2bf(f * scale);
          }
        }
      }
    return;
  }

#pragma unroll
  for (int i = 0; i < 4; ++i)
#pragma unroll
    for (int j = 0; j < 4; ++j) {
      int row0 = wr * 64 + i * 16 + kq * 4;
      int col = wc * 64 + j * 16 + l15;
#pragma unroll
      for (int v = 0; v < 4; ++v) {
        int row = row0 + v;
        float f = 1.5f * bf2f(Y[boff + (size_t)(m0 + row) * kD + n0 + col]) -
                  0.5f * acc[i][j][v];
        int byt = row * 256 + ((col * 2) ^ ((row & 15) << 4));
        *(ushort*)((char*)lds + byt) = f2bf(f);
      }
    }
  __syncthreads();
#pragma unroll
  for (int h = 0; h < 8; ++h) {
    int id = tid + 256 * h;
    int row = id >> 4, c16 = id & 15;
    int byt = row * 256 + ((c16 * 16) ^ ((row & 15) << 4));
    s16x8 vv = *(const s16x8*)((char*)lds + byt);
    *(s16x8*)(Yn + boff + (size_t)(m0 + row) * kD + n0 + c16 * 8) = vv;
  }
#pragma unroll
  for (int h = 0; h < 8; ++h) {
    int id = tid + 256 * h;
    int p = id >> 4, c16 = id & 15;
    ushort vv[8];
#pragma unroll
    for (int s = 0; s < 8; ++s) {
      int r = c16 * 8 + s;
      vv[s] = *(const ushort*)((char*)lds + r * 256 + ((p * 2) ^ ((r & 15) << 4)));
    }
    *(s16x8*)(YTn + boff + (size_t)(n0 + p) * kD + m0 + c16 * 8) = *(s16x8*)vv;
  }
}

// ---- big skinny GEMM, LDS-free streaming MFMA ----
__global__ __launch_bounds__(256) void k_skinny_stream(const ushort* __restrict__ A,
                                                       const float* __restrict__ W,
                                                       float* __restrict__ C,
                                                       int steps) {
  int tid = threadIdx.x;
  int lane = tid & 63, w = tid >> 6;
  int l15 = lane & 15, kq = lane >> 4;
  int n0 = blockIdx.x * 64;
  int col = n0 + w * 16 + l15;
  int k0 = blockIdx.y * steps * 32;

  f32x4 acc[4];
#pragma unroll
  for (int i = 0; i < 4; ++i) acc[i] = (f32x4){0.f, 0.f, 0.f, 0.f};

  float wv[8];
  {
    int kk = k0 + kq * 8;
#pragma unroll
    for (int s = 0; s < 8; ++s) wv[s] = W[(size_t)(kk + s) * 1024 + col];
  }
  for (int t = 0; t < steps; ++t) {
    float nv[8];
    if (t + 1 < steps) {
      int kk = k0 + (t + 1) * 32 + kq * 8;
#pragma unroll
      for (int s = 0; s < 8; ++s) nv[s] = W[(size_t)(kk + s) * 1024 + col];
    } else {
#pragma unroll
      for (int s = 0; s < 8; ++s) nv[s] = 0.f;
    }
    s16x8 bf;
    ushort* bp = (ushort*)&bf;
#pragma unroll
    for (int s = 0; s < 8; ++s) bp[s] = f2bf(wv[s]);
    int kk = k0 + t * 32 + kq * 8;
#pragma unroll
    for (int i = 0; i < 4; ++i) {
      s16x8 af = *(const s16x8*)(A + (size_t)(i * 16 + l15) * kTRI + kk);
      acc[i] = __builtin_amdgcn_mfma_f32_16x16x32_bf16(af, bf, acc[i], 0, 0, 0);
    }
#pragma unroll
    for (int s = 0; s < 8; ++s) wv[s] = nv[s];
  }

#pragma unroll
  for (int i = 0; i < 4; ++i) {
#pragma unroll
    for (int v = 0; v < 4; ++v) {
      int m = i * 16 + kq * 4 + v;
      atomicAdd(&C[(size_t)m * 1024 + col], acc[i][v]);
    }
  }
}

// skinny GEMM, M=64, double-buffered fp32 (sketch path hidden GEMM)
__global__ __launch_bounds__(256) void k_skinny2(const float* __restrict__ A, int lda,
                                                 const float* __restrict__ Bm, int ldb,
                                                 float* __restrict__ C, int ldc,
                                                 int ktiles) {
  __shared__ float As[2][16][68];
  __shared__ float Bs[2][16][68];
  int n0 = blockIdx.x * 64;
  int kt0 = blockIdx.y * ktiles * 16;
  int tid = threadIdx.x, tx = tid & 15, ty = tid >> 4;
  int ar = tid >> 2, aq = tid & 3;
  int bk = tid >> 4, bq = tid & 15;
  float4 apre = *(const float4*)&A[(size_t)ar * lda + kt0 + aq * 4];
  float4 bpre = *(const float4*)&Bm[(size_t)(kt0 + bk) * ldb + n0 + bq * 4];
  As[0][aq * 4 + 0][ar] = apre.x;
  As[0][aq * 4 + 1][ar] = apre.y;
  As[0][aq * 4 + 2][ar] = apre.z;
  As[0][aq * 4 + 3][ar] = apre.w;
  *(float4*)&Bs[0][bk][bq * 4] = bpre;
  __syncthreads();
  float acc[4][4] = {};
  for (int t = 0; t < ktiles; ++t) {
    int cur = t & 1;
    if (t + 1 < ktiles) {
      int kt = kt0 + (t + 1) * 16;
      apre = *(const float4*)&A[(size_t)ar * lda + kt + aq * 4];
      bpre = *(const float4*)&Bm[(size_t)(kt + bk) * ldb + n0 + bq * 4];
    }
#pragma unroll
    for (int k = 0; k < 16; ++k) {
      float a[4], bb[4];
#pragma unroll
      for (int i = 0; i < 4; ++i) a[i] = As[cur][k][ty * 4 + i];
#pragma unroll
      for (int j = 0; j < 4; ++j) bb[j] = Bs[cur][k][tx * 4 + j];
#pragma unroll
      for (int i = 0; i < 4; ++i)
#pragma unroll
        for (int j = 0; j < 4; ++j) acc[i][j] += a[i] * bb[j];
    }
    __syncthreads();
    if (t + 1 < ktiles) {
      int nxt = cur ^ 1;
      As[nxt][aq * 4 + 0][ar] = apre.x;
      As[nxt][aq * 4 + 1][ar] = apre.y;
      As[nxt][aq * 4 + 2][ar] = apre.z;
      As[nxt][aq * 4 + 3][ar] = apre.w;
      *(float4*)&Bs[nxt][bk][bq * 4] = bpre;
    }
    __syncthreads();
  }
  for (int i = 0; i < 4; ++i)
    for (int j = 0; j < 4; ++j)
      atomicAdd(&C[(size_t)(ty * 4 + i) * ldc + n0 + tx * 4 + j], acc[i][j]);
}

// ---- fused final MLP (both paths): bias+BN+GELU on A-load, then GEMM + bias2.
// grid (8, 16, 2): n-block, k-split (64 k each), path.
__global__ __launch_bounds__(256) void k_out(
    const float* __restrict__ h1, const float* __restrict__ h3,
    const float* __restrict__ b12, const float* __restrict__ g2,
    const float* __restrict__ be2, const float* __restrict__ rm2,
    const float* __restrict__ rv2,
    const float* __restrict__ b13, const float* __restrict__ g3,
    const float* __restrict__ be3, const float* __restrict__ rm3,
    const float* __restrict__ rv3,
    const float* __restrict__ w2, const float* __restrict__ w3,
    const float* __restrict__ bo2, const float* __restrict__ bo3,
    float* __restrict__ out) {
  __shared__ float As[16][68];
  __shared__ float Bs[16][68];
  int path = blockIdx.z;
  const float* A  = path ? h3 : h1;
  const float* b1 = path ? b13 : b12;
  const float* ga = path ? g3 : g2;
  const float* be = path ? be3 : be2;
  const float* rm = path ? rm3 : rm2;
  const float* rv = path ? rv3 : rv2;
  const float* W  = path ? w3 : w2;
  const float* bo = path ? bo3 : bo2;
  float* C = out + path * 512;

  int n0 = blockIdx.x * 64;
  int kt0 = blockIdx.y * 64;  // 4 k-tiles of 16
  int tid = threadIdx.x, tx = tid & 15, ty = tid >> 4;
  int ar = tid >> 2, aq = tid & 3;
  int bk = tid >> 4, bq = tid & 15;
  float acc[4][4] = {};
  for (int t = 0; t < 4; ++t) {
    int kt = kt0 + t * 16;
    float4 a = *(const float4*)&A[(size_t)ar * 1024 + kt + aq * 4];
    float4 vb = *(const float4*)&b1[kt + aq * 4];
    float4 vr = *(const float4*)&rm[kt + aq * 4];
    float4 vv = *(const float4*)&rv[kt + aq * 4];
    float4 vg = *(const float4*)&ga[kt + aq * 4];
    float4 ve = *(const float4*)&be[kt + aq * 4];
    const float* ap = (const float*)&a;
    const float* bp = (const float*)&vb;
    const float* rp = (const float*)&vr;
    const float* vp = (const float*)&vv;
    const float* gp = (const float*)&vg;
    const float* ep = (const float*)&ve;
#pragma unroll
    for (int e = 0; e < 4; ++e) {
      float xn = (ap[e] + bp[e] - rp[e]) * rsqrtf(vp[e] + kBNEPS) * gp[e] + ep[e];
      As[aq * 4 + e][ar] = xn * 0.5f * (1.0f + erff(xn * 0.70710678118654752f));
    }
    float4 bv = *(const float4*)&W[(size_t)(kt + bk) * 512 + n0 + bq * 4];
    *(float4*)&Bs[bk][bq * 4] = bv;
    __syncthreads();
#pragma unroll
    for (int k = 0; k < 16; ++k) {
      float av[4], bb[4];
#pragma unroll
      for (int i = 0; i < 4; ++i) av[i] = As[k][ty * 4 + i];
#pragma unroll
      for (int j = 0; j < 4; ++j) bb[j] = Bs[k][tx * 4 + j];
#pragma unroll
      for (int i = 0; i < 4; ++i)
#pragma unroll
        for (int j = 0; j < 4; ++j) acc[i][j] += av[i] * bb[j];
    }
    __syncthreads();
  }
  for (int i = 0; i < 4; ++i)
    for (int j = 0; j < 4; ++j) {
      int col = n0 + tx * 4 + j;
      float add = (blockIdx.y == 0) ? bo[col] : 0.f;
      atomicAdd(&C[(size_t)(ty * 4 + i) * 1024 + col], acc[i][j] + add);
    }
}

__global__ void k_sketch(const float* __restrict__ wc, const int* __restrict__ h1,
                         const int* __restrict__ h2, const int* __restrict__ h3,
                         const float* __restrict__ s1, const float* __restrict__ s2,
                         const float* __restrict__ s3, float* __restrict__ sk) {
  __shared__ float L1[kS];
  __shared__ float L2[kS];
  __shared__ float L3[kS];
  int b = blockIdx.x;
  for (int i = threadIdx.x; i < kS; i += blockDim.x) {
    L1[i] = 0.f;
    L2[i] = 0.f;
    L3[i] = 0.f;
  }
  __syncthreads();
  for (int d = threadIdx.x; d < kD; d += blockDim.x) {
    float w = wc[b * kD + d];
    atomicAdd(&L1[h1[d]], w * s1[d]);
    atomicAdd(&L2[h2[d]], w * s2[d]);
    atomicAdd(&L3[h3[d]], w * s3[d]);
  }
  __syncthreads();
  for (int i = threadIdx.x; i < kS; i += blockDim.x)
    sk[(size_t)b * kS + i] = L1[i] * L2[i] * L3[i];
}

}  // namespace

extern "C" void kernel_launch(void* const* d_in, const int* in_sizes, int n_in,
                              void* d_out, int out_size, void* d_ws, size_t ws_size,
                              hipStream_t stream) {
  (void)in_sizes; (void)n_in; (void)out_size; (void)ws_size;
  const float* tokens = (const float*)d_in[0];
  const float* graph  = (const float*)d_in[1];
  const int*   hash1  = (const int*)d_in[2];
  const int*   hash2  = (const int*)d_in[3];
  const int*   hash3  = (const int*)d_in[4];
  const float* sign1  = (const float*)d_in[5];
  const float* sign2  = (const float*)d_in[6];
  const float* sign3  = (const float*)d_in[7];
  const float* w1_2   = (const float*)d_in[8];
  const float* b1_2   = (const float*)d_in[9];
  const float* gamma2 = (const float*)d_in[10];
  const float* beta2  = (const float*)d_in[11];
  const float* rm2    = (const float*)d_in[12];
  const float* rv2    = (const float*)d_in[13];
  const float* w2_2   = (const float*)d_in[14];
  const float* b2_2   = (const float*)d_in[15];
  const float* w1_3   = (const float*)d_in[16];
  const float* b1_3   = (const float*)d_in[17];
  const float* gamma3 = (const float*)d_in[18];
  const float* beta3  = (const float*)d_in[19];
  const float* rm3    = (const float*)d_in[20];
  const float* rv3    = (const float*)d_in[21];
  const float* w2_3   = (const float*)d_in[22];
  const float* b2_3   = (const float*)d_in[23];
  float* outp = (float*)d_out;

  char* cp = (char*)d_ws;
  auto takeB = [&](size_t bytes) {
    char* q = cp;
    cp += (bytes + 255) & ~(size_t)255;
    return q;
  };
  float* isq  = (float*)takeB((size_t)kB * kN * 4);
  float* rsb  = (float*)takeB((size_t)kB * kN * 4);
  float* trw  = (float*)takeB(256);
  float* tr2  = (float*)takeB(256);
  float* tsc  = (float*)takeB(256);
  float* wc   = (float*)takeB((size_t)kB * kD * 4);
  ushort* xct = (ushort*)takeB((size_t)kB * kD * kNP * 2);
  ushort* wbf = (ushort*)takeB((size_t)kB * kNP * kNP * 2);
  ushort* wxt = (ushort*)takeB((size_t)kB * kD * kNP * 2);
  float* M2   = (float*)takeB((size_t)kB * kDD * 4);
  ushort* AT  = (ushort*)takeB((size_t)kB * kDD * 2);
  ushort* Ya  = (ushort*)takeB((size_t)kB * kDD * 2);
  ushort* Yb2 = (ushort*)takeB((size_t)kB * kDD * 2);
  ushort* YTa = (ushort*)takeB((size_t)kB * kDD * 2);
  ushort* YTb = (ushort*)takeB((size_t)kB * kDD * 2);
  ushort* m2v = (ushort*)takeB((size_t)kB * kTRI * 2);
  float* h1b  = (float*)takeB((size_t)kB * 1024 * 4);
  float* h3b  = (float*)takeB((size_t)kB * 1024 * 4);
  float* sk   = (float*)takeB((size_t)kB * kS * 4);
  // after k_init2, M2 fp32 region is dead -> reuse as two bf16 buffers
  ushort* Ubuf = (ushort*)M2;
  ushort* Stbuf = (ushort*)M2 + (size_t)kB * kDD;

  // stats + zero-init
  hipLaunchKernelGGL(k_deg, dim3(kN, kB), dim3(64), 0, stream,
                     graph, isq, trw, tr2, h1b, h3b, outp);
  hipLaunchKernelGGL(k_rowsum_w, dim3(kN, kB), dim3(64), 0, stream,
                     graph, isq, rsb, trw, wbf);
  hipLaunchKernelGGL(k_mu_xct, dim3(6, kB), dim3(256), 0, stream,
                     tokens, rsb, trw, wc, xct);

  // third path front (independent of NS)
  hipLaunchKernelGGL(k_sketch, dim3(kB), dim3(256), 0, stream,
                     wc, hash1, hash2, hash3, sign1, sign2, sign3, sk);
  hipLaunchKernelGGL(k_skinny2, dim3(16, 32), dim3(256), 0, stream,
                     sk, kS, w1_3, 1024, h3b, 1024, 8);  // 32*8*16 = 4096

  // moment path: WXT = XcT @ W^T, M2 = XcT @ WX (+trace)
  hipLaunchKernelGGL(k_gemm_bf, dim3(2, 3, kB), dim3(256), 0, stream,
                     xct, kNP, kD * kNP, wbf, kNP, kNP * kNP,
                     (void*)wxt, kNP, kD * kNP, 8, 0, (float*)nullptr);
  hipLaunchKernelGGL(k_gemm_bf, dim3(3, 3, kB), dim3(256), 0, stream,
                     xct, kNP, kD * kNP, wxt, kNP, kD * kNP,
                     (void*)M2, kD, kDD, 8, 1, tr2);
  hipLaunchKernelGGL(k_init2, dim3(6, 6, kB), dim3(256), 0, stream,
                     M2, tr2, Ya, AT, YTa, tsc);

  // Newton-Schulz: per iter  {U=Y*A & St=(Y*Y)^T} ; Ynext = 1.5Y - 0.5*U*S
  ushort* Yc = Ya;
  ushort* YTc = YTa;
  ushort* Yn = Yb2;
  ushort* YTn = YTb;
  for (int it = 0; it < 4; ++it) {
    hipLaunchKernelGGL(k_ns_pair, dim3(3, 3, 128), dim3(256), 0, stream,
                       Yc, AT, YTc, Ubuf, Stbuf);
    if (it < 3) {
      hipLaunchKernelGGL(k_ns_upd, dim3(3, 3, kB), dim3(256), 0, stream,
                         Ubuf, Stbuf, Yc, Yn, YTn, (ushort*)nullptr, (const float*)nullptr);
    } else {
      hipLaunchKernelGGL(k_ns_upd, dim3(3, 3, kB), dim3(256), 0, stream,
                         Ubuf, Stbuf, Yc, (ushort*)nullptr, (ushort*)nullptr, m2v, tsc);
    }
    ushort* t1 = Yc; Yc = Yn; Yn = t1;
    ushort* t2 = YTc; YTc = YTn; YTn = t2;
  }

  // second path big GEMM (h1b zeroed in k_deg; bias folded into k_out)
  hipLaunchKernelGGL(k_skinny_stream, dim3(16, 110), dim3(256), 0, stream,
                     m2v, w1_2, h1b, 21);  // 110*21*32 = 73920

  // fused final MLP for both paths
  hipLaunchKernelGGL(k_out, dim3(8, 16, 2), dim3(256), 0, stream,
                     h1b, h3b,
                     b1_2, gamma2, beta2, rm2, rv2,
                     b1_3, gamma3, beta3, rm3, rv3,
                     w2_2, w2_3, b2_2, b2_3, outp);
}

// Round 7
// 618.141 us; speedup vs baseline: 3.0596x; 1.2485x over previous
//
#include <hip/hip_runtime.h>
#include <math.h>

namespace {

constexpr int kB   = 64;
constexpr int kN   = 196;
constexpr int kD   = 384;
constexpr int kS   = 4096;
constexpr int kTRI = 73920;
constexpr int kDD  = kD * kD;          // 147456
constexpr int kNP  = 256;              // padded token dim for MFMA moment path
constexpr float kEPS   = 1e-5f;
constexpr float kBNEPS = 1e-5f;

typedef __attribute__((ext_vector_type(8))) short s16x8;
typedef __attribute__((ext_vector_type(4))) float f32x4;
typedef __attribute__((ext_vector_type(4))) ushort u16x4;

__device__ inline float bf2f(ushort h) {
  union { uint u; float f; } v; v.u = (uint)h << 16; return v.f;
}
__device__ inline ushort f2bf(float f) {
  union { float f; uint u; } v; v.f = f;
  uint r = v.u + 0x7FFF + ((v.u >> 16) & 1);
  return (ushort)(r >> 16);
}

// ---------------- stats + init kernels ----------------

// deg/isq; also zero-inits trw, tr2, h1b, h3b, outp using spare threads.
__global__ void k_deg(const float* __restrict__ g, float* __restrict__ isq,
                      float* __restrict__ trw, float* __restrict__ tr2,
                      float* __restrict__ h1b, float* __restrict__ h3b,
                      float* __restrict__ outp) {
  int i = blockIdx.x, b = blockIdx.y;
  int bid = blockIdx.y * gridDim.x + blockIdx.x;
  int gid = bid * 64 + threadIdx.x;
  if (gid < 65536) h1b[gid] = 0.f;
  else if (gid < 131072) h3b[gid - 65536] = 0.f;
  else if (gid < 196608) outp[gid - 131072] = 0.f;
  if (gid < 64) { trw[gid] = 0.f; tr2[gid] = 0.f; }
  const float* row = g + ((size_t)b * kN + i) * kN;
  float s = 0.f;
  for (int j = threadIdx.x; j < kN; j += 64) s += row[j];
#pragma unroll
  for (int off = 32; off; off >>= 1) s += __shfl_down(s, off);
  if (threadIdx.x == 0) {
    float dg = s < kEPS ? kEPS : s;
    isq[b * kN + i] = 1.0f / sqrtf(dg);
  }
}

// fused: rs/trw + padded bf16 W write. grid (196, 64), 64 threads.
__global__ void k_rowsum_w(const float* __restrict__ g, const float* __restrict__ isq,
                           float* __restrict__ rs, float* __restrict__ trw,
                           ushort* __restrict__ wbf) {
  int i = blockIdx.x, b = blockIdx.y;
  const float* row = g + ((size_t)b * kN + i) * kN;
  const float* is = isq + b * kN;
  float isi = is[i];
  ushort* wrow = wbf + (size_t)b * kNP * kNP + (size_t)i * kNP;
  float s = 0.f, diag = 0.f;
  for (int j = threadIdx.x; j < kNP; j += 64) {
    float wv = 0.f;
    if (j < kN) {
      float gv = row[j];
      float t = gv * is[j];
      s += t;
      if (j == i) diag = gv;
      wv = t * isi;
    }
    wrow[j] = f2bf(wv);
  }
#pragma unroll
  for (int off = 32; off; off >>= 1) {
    s += __shfl_down(s, off);
    diag += __shfl_down(diag, off);
  }
  if (threadIdx.x == 0) {
    rs[b * kN + i] = isi * s;
    atomicAdd(&trw[b], diag * isi * isi);
  }
  if (i < kNP - kN) {  // zero pad rows 196..255
    ushort* prow = wbf + (size_t)b * kNP * kNP + (size_t)(kN + i) * kNP;
    for (int j = threadIdx.x; j < kNP; j += 64) prow[j] = 0;
  }
}

// fused: mu + wc + XcT (bf16, n-padded to 256). grid (6, 64), 256 threads.
__global__ __launch_bounds__(256) void k_mu_xct(const float* __restrict__ tokens,
                                                const float* __restrict__ rs,
                                                const float* __restrict__ trw,
                                                float* __restrict__ wc,
                                                ushort* __restrict__ xct) {
  __shared__ float Ltok[kN][65];
  __shared__ float rs_l[kN];
  __shared__ float red[4][64];
  __shared__ float mu_l[64];
  __shared__ float Ssum;
  int b = blockIdx.y, d0 = blockIdx.x * 64;
  int tid = threadIdx.x, dloc = tid & 63, part = tid >> 6;
  if (tid < kN) rs_l[tid] = rs[b * kN + tid];
  __syncthreads();
  if (tid == 0) {
    float S = 0.f;
    for (int n = 0; n < kN; ++n) S += rs_l[n];
    Ssum = S;
  }
  float T = 0.f;
  const float* tb = tokens + (size_t)b * kN * kD + d0 + dloc;
  for (int n = part; n < kN; n += 4) {
    float t = tb[(size_t)n * kD];
    Ltok[n][dloc] = t;
    T += t * rs_l[n];
  }
  red[part][dloc] = T;
  __syncthreads();
  if (part == 0) {
    float invtr = 1.0f / (trw[b] + kEPS);
    float m = (red[0][dloc] + red[1][dloc] + red[2][dloc] + red[3][dloc]) * invtr;
    mu_l[dloc] = m;
    wc[b * kD + d0 + dloc] = m * (1.0f - Ssum * invtr);
  }
  __syncthreads();
  ushort* xb = xct + (size_t)b * kD * kNP + (size_t)d0 * kNP;
  int c0 = dloc * 4;
#pragma unroll
  for (int r4 = 0; r4 < 16; ++r4) {
    int drow = r4 * 4 + part;
    float m = mu_l[drow];
    u16x4 pk;
#pragma unroll
    for (int c = 0; c < 4; ++c) {
      int col = c0 + c;
      float v = (col < kN) ? (Ltok[col][drow] - m) : 0.f;
      pk[c] = f2bf(v);
    }
    *(u16x4*)(xb + (size_t)drow * kNP + c0) = pk;
  }
}

// ---- shared 128x128-tile bf16 MFMA main loop (one barrier per K-step) ----
__device__ __forceinline__ void mm_body(const ushort* __restrict__ Ag, int lda,
                                        const ushort* __restrict__ Bg, int ldb,
                                        int m0, int n0, int ksteps,
                                        ushort* lds, f32x4 acc[4][4]) {
  int tid = threadIdx.x;
  int lane = tid & 63, wid = tid >> 6;
  int wr = wid >> 1, wc = wid & 1;
  int l15 = lane & 15, kq = lane >> 4;
  int rs = tid >> 2, kb = tid & 3;

  auto st = [&](ushort* base, int r, float4 v) {
    *(float4*)((char*)base + kb * 2048 + ((r ^ (kb << 2)) << 4)) = v;
  };
  auto frag = [&](const ushort* base, int row) {
    return *(const s16x8*)((const char*)base + kq * 2048 + ((row ^ (kq << 2)) << 4));
  };

  float4 sa0 = *(const float4*)(Ag + (size_t)(m0 + rs) * lda + kb * 8);
  float4 sa1 = *(const float4*)(Ag + (size_t)(m0 + rs + 64) * lda + kb * 8);
  float4 sb0 = *(const float4*)(Bg + (size_t)(n0 + rs) * ldb + kb * 8);
  float4 sb1 = *(const float4*)(Bg + (size_t)(n0 + rs + 64) * ldb + kb * 8);
  st(lds, rs, sa0);
  st(lds, rs + 64, sa1);
  st(lds + 4096, rs, sb0);
  st(lds + 4096, rs + 64, sb1);
  __syncthreads();

  for (int kt = 0; kt < ksteps; ++kt) {
    ushort* Lc = lds + (kt & 1) * 8192;
    if (kt + 1 < ksteps) {
      int kk = (kt + 1) * 32 + kb * 8;
      sa0 = *(const float4*)(Ag + (size_t)(m0 + rs) * lda + kk);
      sa1 = *(const float4*)(Ag + (size_t)(m0 + rs + 64) * lda + kk);
      sb0 = *(const float4*)(Bg + (size_t)(n0 + rs) * ldb + kk);
      sb1 = *(const float4*)(Bg + (size_t)(n0 + rs + 64) * ldb + kk);
    }
    s16x8 af[4], bfv[4];
#pragma unroll
    for (int i = 0; i < 4; ++i) af[i] = frag(Lc, wr * 64 + i * 16 + l15);
#pragma unroll
    for (int j = 0; j < 4; ++j) bfv[j] = frag(Lc + 4096, wc * 64 + j * 16 + l15);
#pragma unroll
    for (int i = 0; i < 4; ++i)
#pragma unroll
      for (int j = 0; j < 4; ++j)
        acc[i][j] = __builtin_amdgcn_mfma_f32_16x16x32_bf16(af[i], bfv[j], acc[i][j], 0, 0, 0);
    if (kt + 1 < ksteps) {
      ushort* Ln = lds + ((kt + 1) & 1) * 8192;
      st(Ln, rs, sa0);
      st(Ln, rs + 64, sa1);
      st(Ln + 4096, rs, sb0);
      st(Ln + 4096, rs + 64, sb1);
    }
    __syncthreads();
  }
}

// stage acc (optionally f = a*acc + b*Yterm) into swizzled LDS bf16 tile
__device__ __forceinline__ void stage_tile(ushort* lds, f32x4 acc[4][4]) {
  int tid = threadIdx.x;
  int lane = tid & 63, wid = tid >> 6;
  int wr = wid >> 1, wc = wid & 1;
  int l15 = lane & 15, kq = lane >> 4;
#pragma unroll
  for (int i = 0; i < 4; ++i)
#pragma unroll
    for (int j = 0; j < 4; ++j) {
      int row0 = wr * 64 + i * 16 + kq * 4;
      int col = wc * 64 + j * 16 + l15;
#pragma unroll
      for (int v = 0; v < 4; ++v) {
        int row = row0 + v;
        int byt = row * 256 + ((col * 2) ^ ((row & 15) << 4));
        *(ushort*)((char*)lds + byt) = f2bf(acc[i][j][v]);
      }
    }
}

__device__ __forceinline__ void write_rowmajor(const ushort* lds, ushort* out,
                                               size_t boff, int m0, int n0) {
  int tid = threadIdx.x;
#pragma unroll
  for (int h = 0; h < 8; ++h) {
    int id = tid + 256 * h;
    int row = id >> 4, c16 = id & 15;
    int byt = row * 256 + ((c16 * 16) ^ ((row & 15) << 4));
    s16x8 vv = *(const s16x8*)((const char*)lds + byt);
    *(s16x8*)(out + boff + (size_t)(m0 + row) * kD + n0 + c16 * 8) = vv;
  }
}

__device__ __forceinline__ void write_transposed(const ushort* lds, ushort* out,
                                                 size_t boff, int m0, int n0) {
  int tid = threadIdx.x;
#pragma unroll
  for (int h = 0; h < 8; ++h) {
    int id = tid + 256 * h;
    int p = id >> 4, c16 = id & 15;
    ushort vv[8];
#pragma unroll
    for (int s = 0; s < 8; ++s) {
      int r = c16 * 8 + s;
      vv[s] = *(const ushort*)((const char*)lds + r * 256 + ((p * 2) ^ ((r & 15) << 4)));
    }
    *(s16x8*)(out + boff + (size_t)(n0 + p) * kD + m0 + c16 * 8) = *(s16x8*)vv;
  }
}

// ---- generalized batched bf16 MFMA GEMM (moment path); optional trace atomics ----
__global__ __launch_bounds__(256) void k_gemm_bf(const ushort* __restrict__ A, int lda, int sa,
                                                 const ushort* __restrict__ Bt, int ldb, int sb,
                                                 void* __restrict__ Cv, int ldc, int sc,
                                                 int ksteps, int f32out,
                                                 float* __restrict__ tr2) {
  __shared__ ushort lds[16384];
  int b = blockIdx.z;
  int m0 = blockIdx.y * 128, n0 = blockIdx.x * 128;
  int tid = threadIdx.x;
  int lane = tid & 63, wid = tid >> 6;
  int wr = wid >> 1, wc = wid & 1;
  int l15 = lane & 15, kq = lane >> 4;

  f32x4 acc[4][4];
#pragma unroll
  for (int i = 0; i < 4; ++i)
#pragma unroll
    for (int j = 0; j < 4; ++j) acc[i][j] = (f32x4){0.f, 0.f, 0.f, 0.f};

  mm_body(A + (size_t)b * sa, lda, Bt + (size_t)b * sb, ldb, m0, n0, ksteps, lds, acc);

  if (f32out) {
    float* Cb = (float*)Cv + (size_t)b * sc;
    float trpart = 0.f;
#pragma unroll
    for (int i = 0; i < 4; ++i)
#pragma unroll
      for (int j = 0; j < 4; ++j) {
        int row0 = wr * 64 + i * 16 + kq * 4;
        int col = wc * 64 + j * 16 + l15;
#pragma unroll
        for (int v = 0; v < 4; ++v) {
          float val = acc[i][j][v];
          Cb[(size_t)(m0 + row0 + v) * ldc + n0 + col] = val;
          if (tr2 && (m0 + row0 + v) == (n0 + col)) trpart += val;
        }
      }
    if (tr2 && trpart != 0.f) atomicAdd(&tr2[b], trpart);
  } else {
    ushort* Cb = (ushort*)Cv;
    stage_tile(lds, acc);
    __syncthreads();
#pragma unroll
    for (int h = 0; h < 8; ++h) {
      int id = tid + 256 * h;
      int row = id >> 4, c16 = id & 15;
      int byt = row * 256 + ((c16 * 16) ^ ((row & 15) << 4));
      s16x8 vv = *(const s16x8*)((char*)lds + byt);
      *(s16x8*)(Cb + (size_t)b * sc + (size_t)(m0 + row) * ldc + n0 + c16 * 8) = vv;
    }
  }
}

// M2 fp32 -> A bf16 (= M2*tinv) + Y1 bf16 (= 1.5I - 0.5A); also tsc. grid (6,6,64).
__global__ __launch_bounds__(256) void k_init_sym(const float* __restrict__ M2,
                                                  const float* __restrict__ tr2,
                                                  ushort* __restrict__ Abf,
                                                  ushort* __restrict__ Y1,
                                                  float* __restrict__ tsc) {
  int b = blockIdx.z;
  int r0 = blockIdx.y * 64, c0 = blockIdx.x * 64;
  int tid = threadIdx.x;
  float tr = tr2[b] + kEPS;
  float ti = 1.0f / tr;
  if (r0 == 0 && c0 == 0 && tid == 0) tsc[b] = rsqrtf(tr);
  const float* Mb = M2 + (size_t)b * kDD;
#pragma unroll
  for (int h = 0; h < 4; ++h) {
    int id = tid + 256 * h;
    int r = id >> 4, c4 = id & 15;
    float4 m = *(const float4*)(Mb + (size_t)(r0 + r) * kD + c0 + c4 * 4);
    const float* mp = (const float*)&m;
    u16x4 a, y;
#pragma unroll
    for (int e = 0; e < 4; ++e) {
      float av = mp[e] * ti;
      a[e] = f2bf(av);
      float yv = ((r0 + r) == (c0 + c4 * 4 + e) ? 1.5f : 0.f) - 0.5f * av;
      y[e] = f2bf(yv);
    }
    size_t off = (size_t)b * kDD + (size_t)(r0 + r) * kD + c0 + c4 * 4;
    *(u16x4*)(Abf + off) = a;
    *(u16x4*)(Y1 + off) = y;
  }
}

// upper-tri 128-tile map for 3x3 grid: (0,0),(0,1),(0,2),(1,1),(1,2),(2,2)
__device__ __forceinline__ void tile_mn(int bx, int& m0, int& n0) {
  int tm = bx < 3 ? 0 : (bx < 5 ? 1 : 2);
  int tn = bx < 3 ? bx : (bx < 5 ? bx - 2 : 2);
  m0 = tm * 128;
  n0 = tn * 128;
}

// ---- NS dispatch 1 (symmetric): z<64: U=Y*A;  z>=64: S=Y*Y. Upper tiles only.
__global__ __launch_bounds__(256) void k_ns_pair(const ushort* __restrict__ Y,
                                                 const ushort* __restrict__ A,
                                                 ushort* __restrict__ U,
                                                 ushort* __restrict__ S) {
  __shared__ ushort lds[16384];
  int z = blockIdx.z, b = z & 63, which = z >> 6;
  size_t boff = (size_t)b * kDD;
  int m0, n0;
  tile_mn(blockIdx.x, m0, n0);

  f32x4 acc[4][4];
#pragma unroll
  for (int i = 0; i < 4; ++i)
#pragma unroll
    for (int j = 0; j < 4; ++j) acc[i][j] = (f32x4){0.f, 0.f, 0.f, 0.f};

  const ushort* Bg = (which ? Y : A) + boff;
  ushort* Out = which ? S : U;
  mm_body(Y + boff, kD, Bg, kD, m0, n0, 12, lds, acc);

  stage_tile(lds, acc);
  __syncthreads();
  write_rowmajor(lds, Out, boff, m0, n0);
  if (m0 != n0) write_transposed(lds, Out, boff, m0, n0);
}

// ---- NS dispatch 2 (symmetric): Ynext = 1.5*Y - 0.5*U*S. Upper tiles only.
// Final iter: emit m2v (upper-tri packed, *tsc) directly, no Ynext write.
__global__ __launch_bounds__(256) void k_ns_upd(const ushort* __restrict__ U,
                                                const ushort* __restrict__ S,
                                                const ushort* __restrict__ Y,
                                                ushort* __restrict__ Yn,
                                                ushort* __restrict__ m2v,
                                                const float* __restrict__ tsc) {
  __shared__ ushort lds[16384];
  int b = blockIdx.z;
  size_t boff = (size_t)b * kDD;
  int m0, n0;
  tile_mn(blockIdx.x, m0, n0);
  int tid = threadIdx.x;
  int lane = tid & 63, wid = tid >> 6;
  int wr = wid >> 1, wc = wid & 1;
  int l15 = lane & 15, kq = lane >> 4;

  f32x4 acc[4][4];
#pragma unroll
  for (int i = 0; i < 4; ++i)
#pragma unroll
    for (int j = 0; j < 4; ++j) acc[i][j] = (f32x4){0.f, 0.f, 0.f, 0.f};

  mm_body(U + boff, kD, S + boff, kD, m0, n0, 12, lds, acc);

  if (m2v) {
    float scale = tsc[b];
#pragma unroll
    for (int i = 0; i < 4; ++i)
#pragma unroll
      for (int j = 0; j < 4; ++j) {
        int row0 = m0 + wr * 64 + i * 16 + kq * 4;
        int gcol = n0 + wc * 64 + j * 16 + l15;
#pragma unroll
        for (int v = 0; v < 4; ++v) {
          int grow = row0 + v;
          if (grow <= gcol) {
            float f = 1.5f * bf2f(Y[boff + (size_t)grow * kD + gcol]) - 0.5f * acc[i][j][v];
            int t = (grow * (769 - grow)) / 2 + (gcol - grow);
            m2v[(size_t)b * kTRI + t] = f2bf(f * scale);
          }
        }
      }
    return;
  }

  // f = 1.5Y - 0.5*acc into acc, then stage + dual write
#pragma unroll
  for (int i = 0; i < 4; ++i)
#pragma unroll
    for (int j = 0; j < 4; ++j) {
      int row0 = wr * 64 + i * 16 + kq * 4;
      int col = wc * 64 + j * 16 + l15;
#pragma unroll
      for (int v = 0; v < 4; ++v)
        acc[i][j][v] = 1.5f * bf2f(Y[boff + (size_t)(m0 + row0 + v) * kD + n0 + col]) -
                       0.5f * acc[i][j][v];
    }
  stage_tile(lds, acc);
  __syncthreads();
  write_rowmajor(lds, Yn, boff, m0, n0);
  if (m0 != n0) write_transposed(lds, Yn, boff, m0, n0);
}

// ---- big skinny GEMM, LDS-free streaming MFMA ----
__global__ __launch_bounds__(256) void k_skinny_stream(const ushort* __restrict__ A,
                                                       const float* __restrict__ W,
                                                       float* __restrict__ C,
                                                       int steps) {
  int tid = threadIdx.x;
  int lane = tid & 63, w = tid >> 6;
  int l15 = lane & 15, kq = lane >> 4;
  int n0 = blockIdx.x * 64;
  int col = n0 + w * 16 + l15;
  int k0 = blockIdx.y * steps * 32;

  f32x4 acc[4];
#pragma unroll
  for (int i = 0; i < 4; ++i) acc[i] = (f32x4){0.f, 0.f, 0.f, 0.f};

  float wv[8];
  {
    int kk = k0 + kq * 8;
#pragma unroll
    for (int s = 0; s < 8; ++s) wv[s] = W[(size_t)(kk + s) * 1024 + col];
  }
  for (int t = 0; t < steps; ++t) {
    float nv[8];
    if (t + 1 < steps) {
      int kk = k0 + (t + 1) * 32 + kq * 8;
#pragma unroll
      for (int s = 0; s < 8; ++s) nv[s] = W[(size_t)(kk + s) * 1024 + col];
    } else {
#pragma unroll
      for (int s = 0; s < 8; ++s) nv[s] = 0.f;
    }
    s16x8 bf;
    ushort* bp = (ushort*)&bf;
#pragma unroll
    for (int s = 0; s < 8; ++s) bp[s] = f2bf(wv[s]);
    int kk = k0 + t * 32 + kq * 8;
#pragma unroll
    for (int i = 0; i < 4; ++i) {
      s16x8 af = *(const s16x8*)(A + (size_t)(i * 16 + l15) * kTRI + kk);
      acc[i] = __builtin_amdgcn_mfma_f32_16x16x32_bf16(af, bf, acc[i], 0, 0, 0);
    }
#pragma unroll
    for (int s = 0; s < 8; ++s) wv[s] = nv[s];
  }

#pragma unroll
  for (int i = 0; i < 4; ++i) {
#pragma unroll
    for (int v = 0; v < 4; ++v) {
      int m = i * 16 + kq * 4 + v;
      atomicAdd(&C[(size_t)m * 1024 + col], acc[i][v]);
    }
  }
}

// skinny GEMM, M=64, double-buffered fp32 (sketch path hidden GEMM)
__global__ __launch_bounds__(256) void k_skinny2(const float* __restrict__ A, int lda,
                                                 const float* __restrict__ Bm, int ldb,
                                                 float* __restrict__ C, int ldc,
                                                 int ktiles) {
  __shared__ float As[2][16][68];
  __shared__ float Bs[2][16][68];
  int n0 = blockIdx.x * 64;
  int kt0 = blockIdx.y * ktiles * 16;
  int tid = threadIdx.x, tx = tid & 15, ty = tid >> 4;
  int ar = tid >> 2, aq = tid & 3;
  int bk = tid >> 4, bq = tid & 15;
  float4 apre = *(const float4*)&A[(size_t)ar * lda + kt0 + aq * 4];
  float4 bpre = *(const float4*)&Bm[(size_t)(kt0 + bk) * ldb + n0 + bq * 4];
  As[0][aq * 4 + 0][ar] = apre.x;
  As[0][aq * 4 + 1][ar] = apre.y;
  As[0][aq * 4 + 2][ar] = apre.z;
  As[0][aq * 4 + 3][ar] = apre.w;
  *(float4*)&Bs[0][bk][bq * 4] = bpre;
  __syncthreads();
  float acc[4][4] = {};
  for (int t = 0; t < ktiles; ++t) {
    int cur = t & 1;
    if (t + 1 < ktiles) {
      int kt = kt0 + (t + 1) * 16;
      apre = *(const float4*)&A[(size_t)ar * lda + kt + aq * 4];
      bpre = *(const float4*)&Bm[(size_t)(kt + bk) * ldb + n0 + bq * 4];
    }
#pragma unroll
    for (int k = 0; k < 16; ++k) {
      float a[4], bb[4];
#pragma unroll
      for (int i = 0; i < 4; ++i) a[i] = As[cur][k][ty * 4 + i];
#pragma unroll
      for (int j = 0; j < 4; ++j) bb[j] = Bs[cur][k][tx * 4 + j];
#pragma unroll
      for (int i = 0; i < 4; ++i)
#pragma unroll
        for (int j = 0; j < 4; ++j) acc[i][j] += a[i] * bb[j];
    }
    __syncthreads();
    if (t + 1 < ktiles) {
      int nxt = cur ^ 1;
      As[nxt][aq * 4 + 0][ar] = apre.x;
      As[nxt][aq * 4 + 1][ar] = apre.y;
      As[nxt][aq * 4 + 2][ar] = apre.z;
      As[nxt][aq * 4 + 3][ar] = apre.w;
      *(float4*)&Bs[nxt][bk][bq * 4] = bpre;
    }
    __syncthreads();
  }
  for (int i = 0; i < 4; ++i)
    for (int j = 0; j < 4; ++j)
      atomicAdd(&C[(size_t)(ty * 4 + i) * ldc + n0 + tx * 4 + j], acc[i][j]);
}

// ---- fused final MLP (both paths): bias+BN+GELU on A-load, then GEMM + bias2.
__global__ __launch_bounds__(256) void k_out(
    const float* __restrict__ h1, const float* __restrict__ h3,
    const float* __restrict__ b12, const float* __restrict__ g2,
    const float* __restrict__ be2, const float* __restrict__ rm2,
    const float* __restrict__ rv2,
    const float* __restrict__ b13, const float* __restrict__ g3,
    const float* __restrict__ be3, const float* __restrict__ rm3,
    const float* __restrict__ rv3,
    const float* __restrict__ w2, const float* __restrict__ w3,
    const float* __restrict__ bo2, const float* __restrict__ bo3,
    float* __restrict__ out) {
  __shared__ float As[16][68];
  __shared__ float Bs[16][68];
  int path = blockIdx.z;
  const float* A  = path ? h3 : h1;
  const float* b1 = path ? b13 : b12;
  const float* ga = path ? g3 : g2;
  const float* be = path ? be3 : be2;
  const float* rm = path ? rm3 : rm2;
  const float* rv = path ? rv3 : rv2;
  const float* W  = path ? w3 : w2;
  const float* bo = path ? bo3 : bo2;
  float* C = out + path * 512;

  int n0 = blockIdx.x * 64;
  int kt0 = blockIdx.y * 64;  // 4 k-tiles of 16
  int tid = threadIdx.x, tx = tid & 15, ty = tid >> 4;
  int ar = tid >> 2, aq = tid & 3;
  int bk = tid >> 4, bq = tid & 15;
  float acc[4][4] = {};
  for (int t = 0; t < 4; ++t) {
    int kt = kt0 + t * 16;
    float4 a = *(const float4*)&A[(size_t)ar * 1024 + kt + aq * 4];
    float4 vb = *(const float4*)&b1[kt + aq * 4];
    float4 vr = *(const float4*)&rm[kt + aq * 4];
    float4 vv = *(const float4*)&rv[kt + aq * 4];
    float4 vg = *(const float4*)&ga[kt + aq * 4];
    float4 ve = *(const float4*)&be[kt + aq * 4];
    const float* ap = (const float*)&a;
    const float* bp = (const float*)&vb;
    const float* rp = (const float*)&vr;
    const float* vp = (const float*)&vv;
    const float* gp = (const float*)&vg;
    const float* ep = (const float*)&ve;
#pragma unroll
    for (int e = 0; e < 4; ++e) {
      float xn = (ap[e] + bp[e] - rp[e]) * rsqrtf(vp[e] + kBNEPS) * gp[e] + ep[e];
      As[aq * 4 + e][ar] = xn * 0.5f * (1.0f + erff(xn * 0.70710678118654752f));
    }
    float4 bv = *(const float4*)&W[(size_t)(kt + bk) * 512 + n0 + bq * 4];
    *(float4*)&Bs[bk][bq * 4] = bv;
    __syncthreads();
#pragma unroll
    for (int k = 0; k < 16; ++k) {
      float av[4], bb[4];
#pragma unroll
      for (int i = 0; i < 4; ++i) av[i] = As[k][ty * 4 + i];
#pragma unroll
      for (int j = 0; j < 4; ++j) bb[j] = Bs[k][tx * 4 + j];
#pragma unroll
      for (int i = 0; i < 4; ++i)
#pragma unroll
        for (int j = 0; j < 4; ++j) acc[i][j] += av[i] * bb[j];
    }
    __syncthreads();
  }
  for (int i = 0; i < 4; ++i)
    for (int j = 0; j < 4; ++j) {
      int col = n0 + tx * 4 + j;
      float add = (blockIdx.y == 0) ? bo[col] : 0.f;
      atomicAdd(&C[(size_t)(ty * 4 + i) * 1024 + col], acc[i][j] + add);
    }
}

__global__ void k_sketch(const float* __restrict__ wc, const int* __restrict__ h1,
                         const int* __restrict__ h2, const int* __restrict__ h3,
                         const float* __restrict__ s1, const float* __restrict__ s2,
                         const float* __restrict__ s3, float* __restrict__ sk) {
  __shared__ float L1[kS];
  __shared__ float L2[kS];
  __shared__ float L3[kS];
  int b = blockIdx.x;
  for (int i = threadIdx.x; i < kS; i += blockDim.x) {
    L1[i] = 0.f;
    L2[i] = 0.f;
    L3[i] = 0.f;
  }
  __syncthreads();
  for (int d = threadIdx.x; d < kD; d += blockDim.x) {
    float w = wc[b * kD + d];
    atomicAdd(&L1[h1[d]], w * s1[d]);
    atomicAdd(&L2[h2[d]], w * s2[d]);
    atomicAdd(&L3[h3[d]], w * s3[d]);
  }
  __syncthreads();
  for (int i = threadIdx.x; i < kS; i += blockDim.x)
    sk[(size_t)b * kS + i] = L1[i] * L2[i] * L3[i];
}

}  // namespace

extern "C" void kernel_launch(void* const* d_in, const int* in_sizes, int n_in,
                              void* d_out, int out_size, void* d_ws, size_t ws_size,
                              hipStream_t stream) {
  (void)in_sizes; (void)n_in; (void)out_size; (void)ws_size;
  const float* tokens = (const float*)d_in[0];
  const float* graph  = (const float*)d_in[1];
  const int*   hash1  = (const int*)d_in[2];
  const int*   hash2  = (const int*)d_in[3];
  const int*   hash3  = (const int*)d_in[4];
  const float* sign1  = (const float*)d_in[5];
  const float* sign2  = (const float*)d_in[6];
  const float* sign3  = (const float*)d_in[7];
  const float* w1_2   = (const float*)d_in[8];
  const float* b1_2   = (const float*)d_in[9];
  const float* gamma2 = (const float*)d_in[10];
  const float* beta2  = (const float*)d_in[11];
  const float* rm2    = (const float*)d_in[12];
  const float* rv2    = (const float*)d_in[13];
  const float* w2_2   = (const float*)d_in[14];
  const float* b2_2   = (const float*)d_in[15];
  const float* w1_3   = (const float*)d_in[16];
  const float* b1_3   = (const float*)d_in[17];
  const float* gamma3 = (const float*)d_in[18];
  const float* beta3  = (const float*)d_in[19];
  const float* rm3    = (const float*)d_in[20];
  const float* rv3    = (const float*)d_in[21];
  const float* w2_3   = (const float*)d_in[22];
  const float* b2_3   = (const float*)d_in[23];
  float* outp = (float*)d_out;

  char* cp = (char*)d_ws;
  auto takeB = [&](size_t bytes) {
    char* q = cp;
    cp += (bytes + 255) & ~(size_t)255;
    return q;
  };
  float* isq  = (float*)takeB((size_t)kB * kN * 4);
  float* rsb  = (float*)takeB((size_t)kB * kN * 4);
  float* trw  = (float*)takeB(256);
  float* tr2  = (float*)takeB(256);
  float* tsc  = (float*)takeB(256);
  float* wc   = (float*)takeB((size_t)kB * kD * 4);
  ushort* xct = (ushort*)takeB((size_t)kB * kD * kNP * 2);
  ushort* wbf = (ushort*)takeB((size_t)kB * kNP * kNP * 2);
  ushort* wxt = (ushort*)takeB((size_t)kB * kD * kNP * 2);
  float* M2   = (float*)takeB((size_t)kB * kDD * 4);
  ushort* Abf = (ushort*)takeB((size_t)kB * kDD * 2);
  ushort* Ya  = (ushort*)takeB((size_t)kB * kDD * 2);
  ushort* Yb2 = (ushort*)takeB((size_t)kB * kDD * 2);
  ushort* m2v = (ushort*)takeB((size_t)kB * kTRI * 2);
  float* h1b  = (float*)takeB((size_t)kB * 1024 * 4);
  float* h3b  = (float*)takeB((size_t)kB * 1024 * 4);
  float* sk   = (float*)takeB((size_t)kB * kS * 4);
  // after k_init_sym, M2 fp32 region is dead -> reuse as two bf16 buffers
  ushort* Ubuf = (ushort*)M2;
  ushort* Sbuf = (ushort*)M2 + (size_t)kB * kDD;

  // stats + zero-init
  hipLaunchKernelGGL(k_deg, dim3(kN, kB), dim3(64), 0, stream,
                     graph, isq, trw, tr2, h1b, h3b, outp);
  hipLaunchKernelGGL(k_rowsum_w, dim3(kN, kB), dim3(64), 0, stream,
                     graph, isq, rsb, trw, wbf);
  hipLaunchKernelGGL(k_mu_xct, dim3(6, kB), dim3(256), 0, stream,
                     tokens, rsb, trw, wc, xct);

  // third path front (independent of NS)
  hipLaunchKernelGGL(k_sketch, dim3(kB), dim3(256), 0, stream,
                     wc, hash1, hash2, hash3, sign1, sign2, sign3, sk);
  hipLaunchKernelGGL(k_skinny2, dim3(16, 32), dim3(256), 0, stream,
                     sk, kS, w1_3, 1024, h3b, 1024, 8);  // 32*8*16 = 4096

  // moment path: WXT = XcT @ W^T, M2 = XcT @ WX (+trace)
  hipLaunchKernelGGL(k_gemm_bf, dim3(2, 3, kB), dim3(256), 0, stream,
                     xct, kNP, kD * kNP, wbf, kNP, kNP * kNP,
                     (void*)wxt, kNP, kD * kNP, 8, 0, (float*)nullptr);
  hipLaunchKernelGGL(k_gemm_bf, dim3(3, 3, kB), dim3(256), 0, stream,
                     xct, kNP, kD * kNP, wxt, kNP, kD * kNP,
                     (void*)M2, kD, kDD, 8, 1, tr2);
  hipLaunchKernelGGL(k_init_sym, dim3(6, 6, kB), dim3(256), 0, stream,
                     M2, tr2, Abf, Ya, tsc);

  // Newton-Schulz (symmetric): per iter {U=Y*A & S=Y*Y}; Ynext = 1.5Y - 0.5*U*S
  ushort* Yc = Ya;
  ushort* Yn = Yb2;
  for (int it = 0; it < 4; ++it) {
    hipLaunchKernelGGL(k_ns_pair, dim3(6, 1, 128), dim3(256), 0, stream,
                       Yc, Abf, Ubuf, Sbuf);
    if (it < 3) {
      hipLaunchKernelGGL(k_ns_upd, dim3(6, 1, kB), dim3(256), 0, stream,
                         Ubuf, Sbuf, Yc, Yn, (ushort*)nullptr, (const float*)nullptr);
    } else {
      hipLaunchKernelGGL(k_ns_upd, dim3(6, 1, kB), dim3(256), 0, stream,
                         Ubuf, Sbuf, Yc, (ushort*)nullptr, m2v, tsc);
    }
    ushort* t1 = Yc; Yc = Yn; Yn = t1;
  }

  // second path big GEMM (h1b zeroed in k_deg; bias folded into k_out)
  hipLaunchKernelGGL(k_skinny_stream, dim3(16, 110), dim3(256), 0, stream,
                     m2v, w1_2, h1b, 21);  // 110*21*32 = 73920

  // fused final MLP for both paths
  hipLaunchKernelGGL(k_out, dim3(8, 16, 2), dim3(256), 0, stream,
                     h1b, h3b,
                     b1_2, gamma2, beta2, rm2, rv2,
                     b1_3, gamma3, beta3, rm3, rv3,
                     w2_2, w2_3, b2_2, b2_3, outp);
}